// Round 1
// baseline (3025.491 us; speedup 1.0000x reference)
//
#include <hip/hip_runtime.h>

#define BN 4
#define NP 4096
#define RV 32
#define VX (RV*RV*RV)

// ---------- bf16 helpers (bit-level, avoids API ambiguity) ----------
__device__ __forceinline__ float bf2f(unsigned short u){
  union{unsigned u;float f;}v; v.u=((unsigned)u)<<16; return v.f; }
__device__ __forceinline__ unsigned short f2bf(float f){
  union{float f;unsigned u;}v; v.f=f; unsigned r=v.u + 0x7fffu + ((v.u>>16)&1u);
  return (unsigned short)(r>>16); }
__device__ __forceinline__ float2 bfp2f2(unsigned p){
  union{unsigned u;float f;}a,b; a.u=p<<16; b.u=p&0xffff0000u;
  float2 r; r.x=a.f; r.y=b.f; return r; }

// ---------- 1. per-batch coord stats: mean(3) + max norm ----------
__global__ void stats_kernel(const float* __restrict__ coords, float* __restrict__ stats)
{
  __shared__ float red[256];
  __shared__ float mean[3];
  const int b = blockIdx.x;
  const int tid = threadIdx.x;
  float s0=0.f,s1=0.f,s2=0.f;
  for (int n = tid; n < NP; n += 256) {
    s0 += coords[((size_t)(b*3)+0)*NP + n];
    s1 += coords[((size_t)(b*3)+1)*NP + n];
    s2 += coords[((size_t)(b*3)+2)*NP + n];
  }
  float sv[3] = {s0,s1,s2};
  for (int ax = 0; ax < 3; ax++) {
    __syncthreads();
    red[tid] = sv[ax];
    __syncthreads();
    for (int st = 128; st > 0; st >>= 1) {
      if (tid < st) red[tid] += red[tid + st];
      __syncthreads();
    }
    if (tid == 0) mean[ax] = red[0] * (1.f / NP);
  }
  __syncthreads();
  float mx = 0.f;
  for (int n = tid; n < NP; n += 256) {
    float d0 = coords[((size_t)(b*3)+0)*NP + n] - mean[0];
    float d1 = coords[((size_t)(b*3)+1)*NP + n] - mean[1];
    float d2 = coords[((size_t)(b*3)+2)*NP + n] - mean[2];
    mx = fmaxf(mx, sqrtf(d0*d0 + d1*d1 + d2*d2));
  }
  __syncthreads();
  red[tid] = mx;
  __syncthreads();
  for (int st = 128; st > 0; st >>= 1) {
    if (tid < st) red[tid] = fmaxf(red[tid], red[tid + st]);
    __syncthreads();
  }
  if (tid == 0) {
    stats[b*4+0] = mean[0]; stats[b*4+1] = mean[1];
    stats[b*4+2] = mean[2]; stats[b*4+3] = red[0];
  }
}

// ---------- 2. voxelize scatter-sum (+nc store, +count) ----------
__global__ void scatter_kernel(const float* __restrict__ features,
                               const float* __restrict__ coords,
                               const float* __restrict__ stats,
                               float* __restrict__ nc,
                               float* __restrict__ sums, float* __restrict__ cnt)
{
  int t = blockIdx.x*256 + threadIdx.x;   // B*N*4 threads
  int part = t & 3;
  int p = t >> 2;
  int b = p >> 12;
  int n = p & 4095;
  float m0 = stats[b*4+0], m1 = stats[b*4+1], m2 = stats[b*4+2], mx = stats[b*4+3];
  float inv = 1.f / (2.f * mx);
  float c0 = (coords[((size_t)(b*3)+0)*NP + n] - m0) * inv + 0.5f;
  float c1 = (coords[((size_t)(b*3)+1)*NP + n] - m1) * inv + 0.5f;
  float c2 = (coords[((size_t)(b*3)+2)*NP + n] - m2) * inv + 0.5f;
  float g0 = fminf(fmaxf(c0 * 32.f, 0.f), 31.f);
  float g1 = fminf(fmaxf(c1 * 32.f, 0.f), 31.f);
  float g2 = fminf(fmaxf(c2 * 32.f, 0.f), 31.f);
  int v0 = (int)rintf(g0), v1 = (int)rintf(g1), v2 = (int)rintf(g2);
  int idx = (v0*32 + v1)*32 + v2 + b*VX;
  if (part == 0) {
    nc[((size_t)(b*3)+0)*NP + n] = g0;
    nc[((size_t)(b*3)+1)*NP + n] = g1;
    nc[((size_t)(b*3)+2)*NP + n] = g2;
    atomicAdd(&cnt[idx], 1.f);
  }
  const float* fp = features + (size_t)(b*64)*NP + n;
  float* sp = sums + (size_t)idx*64;
  for (int i = part*16; i < part*16+16; i++)
    atomicAdd(&sp[i], fp[(size_t)i*NP]);
}

// ---------- 3. scatter-mean finalize ----------
__global__ void finalize_kernel(float* __restrict__ g, const float* __restrict__ cnt)
{
  int i = blockIdx.x*256 + threadIdx.x;   // B*VX*64
  g[i] = g[i] / fmaxf(cnt[i >> 6], 1.f);
}

// ---------- 4. 3x3x3 SAME conv + bias + relu. layout (B, vox, 64) ----------
__global__ __launch_bounds__(256) void conv_kernel(
    const float* __restrict__ gin, const float* __restrict__ wt,
    const float* __restrict__ bias, float* __restrict__ gout)
{
  __shared__ float ws_s[64*65];
  const int tid = threadIdx.x;
  const int blk = blockIdx.x;                 // B*32*16
  const int yp = blk & 15, z = (blk >> 4) & 31, b = blk >> 9;
  const int o = tid & 63, g = tid >> 6;
  const int yl = g >> 1, xh = (g & 1) * 16;
  const int y = yp*2 + yl;
  float acc[16];
  #pragma unroll
  for (int v = 0; v < 16; v++) acc[v] = 0.f;
  for (int kd = 0; kd < 3; kd++) {
    int zz = z + kd - 1;
    if (zz < 0 || zz >= 32) continue;         // block-uniform -> barrier safe
    for (int kh = 0; kh < 3; kh++) {
      int yy = y + kh - 1;
      bool yok = (yy >= 0 && yy < 32);
      for (int kw = 0; kw < 3; kw++) {
        int tap = kd*9 + kh*3 + kw;
        __syncthreads();
        for (int e = tid; e < 4096; e += 256) {
          int oo = e >> 6, ii = e & 63;
          ws_s[ii*65 + oo] = wt[(oo*64 + ii)*27 + tap];
        }
        __syncthreads();
        if (yok) {
          const float* base = gin + ((size_t)(b*VX) + (zz*32 + yy)*32) * 64;
          for (int i4 = 0; i4 < 16; i4++) {
            float w0 = ws_s[(i4*4+0)*65 + o];
            float w1 = ws_s[(i4*4+1)*65 + o];
            float w2 = ws_s[(i4*4+2)*65 + o];
            float w3 = ws_s[(i4*4+3)*65 + o];
            #pragma unroll
            for (int v = 0; v < 16; v++) {
              int xx = xh + v + kw - 1;
              if (xx < 0 || xx >= 32) continue;
              const float4 in4 = *(const float4*)(base + xx*64 + i4*4);
              acc[v] += in4.x*w0 + in4.y*w1 + in4.z*w2 + in4.w*w3;
            }
          }
        }
      }
    }
  }
  const float bb = bias[o];
  #pragma unroll
  for (int v = 0; v < 16; v++)
    gout[((size_t)(b*VX) + (z*32 + y)*32 + xh + v)*64 + o] = fmaxf(acc[v] + bb, 0.f);
}

// ---------- 5. windowed transformer encoder (in-place on grid1) ----------
__global__ __launch_bounds__(256) void encoder_kernel(
    float* __restrict__ grid,
    const float* __restrict__ ln1_g, const float* __restrict__ ln1_b,
    const float* __restrict__ qkv_w, const float* __restrict__ qkv_b,
    const float* __restrict__ proj_w, const float* __restrict__ proj_b,
    const float* __restrict__ ln2_g, const float* __restrict__ ln2_b,
    const float* __restrict__ w1, const float* __restrict__ b1,
    const float* __restrict__ w2, const float* __restrict__ b2,
    float* __restrict__ se_sum)
{
  __shared__ float t_s[64*65];               // residual stream, fp32
  __shared__ unsigned short h_s[64*66];      // LN out, bf16, TRANSPOSED [c][tok]
  __shared__ unsigned short big[4*64*66];    // q,k,v,proj_w bf16; later mlp hid
  __shared__ float mean_s[64], rstd_s[64];
  __shared__ float sered[256];
  unsigned short* q_s  = big;
  unsigned short* k_s  = big + 4224;
  unsigned short* v_s  = big + 8448;
  unsigned short* pw_s = big + 12672;
  unsigned short* hid  = big;                // [m][66], 256*66 = 16896 = |big|

  const int tid = threadIdx.x;
  const int win = blockIdx.x;                // 2048
  const int b = win >> 9, w = win & 511;
  const int zb = w >> 6, yb = (w >> 3) & 7, xb = w & 7;
  const size_t gb = (size_t)b * VX * 64;

  // load window tokens
  for (int e = tid; e < 4096; e += 256) {
    int tok = e >> 6, c = e & 63;
    int zl = tok >> 4, yl = (tok >> 2) & 3, xl = tok & 3;
    int vox = ((zb*4+zl)*32 + (yb*4+yl))*32 + (xb*4+xl);
    t_s[tok*65 + c] = grid[gb + (size_t)vox*64 + c];
  }
  __syncthreads();
  // LN1 stats (4 lanes per token)
  {
    int i = tid >> 2, part = tid & 3;
    float sum = 0.f, sq = 0.f;
    for (int c = part; c < 64; c += 4) { float x = t_s[i*65+c]; sum += x; sq += x*x; }
    sum += __shfl_xor(sum, 1); sq += __shfl_xor(sq, 1);
    sum += __shfl_xor(sum, 2); sq += __shfl_xor(sq, 2);
    if (part == 0) {
      float m = sum * (1.f/64.f);
      float var = sq * (1.f/64.f) - m*m;
      mean_s[i] = m; rstd_s[i] = rsqrtf(var + 1e-5f);
    }
  }
  __syncthreads();
  // h (transposed, bf16) + stage proj_w (bf16)
  for (int e = tid; e < 4096; e += 256) {
    int tok = e & 63, c = e >> 6;
    float h = (t_s[tok*65+c] - mean_s[tok]) * rstd_s[tok] * ln1_g[c] + ln1_b[c];
    h_s[c*66 + tok] = f2bf(h);
    pw_s[(e>>6)*66 + (e&63)] = f2bf(proj_w[e]);
  }
  __syncthreads();
  // qkv: 768 work items = 192 d x 4 token-quarters
  for (int item = 0; item < 3; item++) {
    int wk = tid + item*256;
    int d = wk % 192, quarter = wk / 192;
    int t0 = quarter * 16;
    float acc[16];
    #pragma unroll
    for (int t = 0; t < 16; t++) acc[t] = 0.f;
    for (int c = 0; c < 64; c++) {
      float wv = qkv_w[d*64 + c];
      const unsigned* hp = (const unsigned*)(h_s + c*66 + t0);
      #pragma unroll
      for (int t2 = 0; t2 < 8; t2++) {
        float2 hf = bfp2f2(hp[t2]);
        acc[2*t2]   += hf.x * wv;
        acc[2*t2+1] += hf.y * wv;
      }
    }
    float bb = qkv_b[d];
    unsigned short* dst; int dd; float sc;
    if (d < 64)       { dst = q_s; dd = d;       sc = 0.25f; }  // fold 1/sqrt(16)
    else if (d < 128) { dst = k_s; dd = d - 64;  sc = 1.f; }
    else              { dst = v_s; dd = d - 128; sc = 1.f; }
    #pragma unroll
    for (int t = 0; t < 16; t++)
      dst[(t0+t)*66 + dd] = f2bf((acc[t] + bb) * sc);
  }
  __syncthreads();
  // attention, 4 heads of 16; scores in regs (16/thread); fused proj residual
  {
    int i = tid >> 2, jg = tid & 3;
    for (int h = 0; h < 4; h++) {
      int hb = h * 16;
      float qv[16];
      #pragma unroll
      for (int d = 0; d < 16; d++) qv[d] = bf2f(q_s[i*66 + hb + d]);
      float p[16]; float mx = -1e30f;
      #pragma unroll
      for (int jj = 0; jj < 16; jj++) {
        int j = jg*16 + jj;
        float s = 0.f;
        #pragma unroll
        for (int d = 0; d < 16; d++) s += qv[d] * bf2f(k_s[j*66 + hb + d]);
        p[jj] = s; mx = fmaxf(mx, s);
      }
      mx = fmaxf(mx, __shfl_xor(mx, 1));
      mx = fmaxf(mx, __shfl_xor(mx, 2));
      float sum = 0.f;
      #pragma unroll
      for (int jj = 0; jj < 16; jj++) { p[jj] = __expf(p[jj]-mx); sum += p[jj]; }
      sum += __shfl_xor(sum, 1);
      sum += __shfl_xor(sum, 2);
      float po[16];
      #pragma unroll
      for (int d = 0; d < 16; d++) po[d] = 0.f;
      #pragma unroll
      for (int jj = 0; jj < 16; jj++) {
        int j = jg*16 + jj; float pv = p[jj];
        #pragma unroll
        for (int d = 0; d < 16; d++) po[d] += pv * bf2f(v_s[j*66 + hb + d]);
      }
      float invs = 1.f / sum;
      #pragma unroll
      for (int d = 0; d < 16; d++) {
        po[d] += __shfl_xor(po[d], 1);
        po[d] += __shfl_xor(po[d], 2);
        po[d] *= invs;
      }
      #pragma unroll
      for (int cc = 0; cc < 16; cc++) {
        int c = jg*16 + cc;
        float a = 0.f;
        #pragma unroll
        for (int d = 0; d < 16; d++) a += po[d] * bf2f(pw_s[c*66 + hb + d]);
        if (h == 0) a += proj_b[c];
        t_s[i*65 + c] += a;
      }
    }
  }
  __syncthreads();
  // LN2
  {
    int i = tid >> 2, part = tid & 3;
    float sum = 0.f, sq = 0.f;
    for (int c = part; c < 64; c += 4) { float x = t_s[i*65+c]; sum += x; sq += x*x; }
    sum += __shfl_xor(sum, 1); sq += __shfl_xor(sq, 1);
    sum += __shfl_xor(sum, 2); sq += __shfl_xor(sq, 2);
    if (part == 0) {
      float m = sum * (1.f/64.f);
      float var = sq * (1.f/64.f) - m*m;
      mean_s[i] = m; rstd_s[i] = rsqrtf(var + 1e-5f);
    }
  }
  __syncthreads();
  for (int e = tid; e < 4096; e += 256) {
    int tok = e & 63, c = e >> 6;
    float h = (t_s[tok*65+c] - mean_s[tok]) * rstd_s[tok] * ln2_g[c] + ln2_b[c];
    h_s[c*66 + tok] = f2bf(h);
  }
  __syncthreads();
  // MLP w1 + gelu -> hid (bf16, overlays q/k/v/pw)
  for (int item = 0; item < 4; item++) {
    int wk = tid + item*256;
    int m = wk & 255, quarter = wk >> 8;
    int t0 = quarter * 16;
    float acc[16];
    #pragma unroll
    for (int t = 0; t < 16; t++) acc[t] = 0.f;
    for (int c = 0; c < 64; c++) {
      float wv = w1[m*64 + c];
      const unsigned* hp = (const unsigned*)(h_s + c*66 + t0);
      #pragma unroll
      for (int t2 = 0; t2 < 8; t2++) {
        float2 hf = bfp2f2(hp[t2]);
        acc[2*t2]   += hf.x * wv;
        acc[2*t2+1] += hf.y * wv;
      }
    }
    float bb = b1[m];
    #pragma unroll
    for (int t = 0; t < 16; t++) {
      float x = acc[t] + bb;
      float gl = 0.5f * x * (1.f + tanhf(0.7978845608f*(x + 0.044715f*x*x*x)));
      hid[m*66 + t0 + t] = f2bf(gl);
    }
  }
  __syncthreads();
  // MLP w2 + residual
  {
    int c = tid & 63, quarter = tid >> 6;
    int t0 = quarter * 16;
    float acc[16];
    #pragma unroll
    for (int t = 0; t < 16; t++) acc[t] = 0.f;
    for (int k = 0; k < 256; k++) {
      float wv = w2[c*256 + k];
      const unsigned* hp = (const unsigned*)(hid + k*66 + t0);
      #pragma unroll
      for (int t2 = 0; t2 < 8; t2++) {
        float2 hf = bfp2f2(hp[t2]);
        acc[2*t2]   += hf.x * wv;
        acc[2*t2+1] += hf.y * wv;
      }
    }
    float bb = b2[c];
    #pragma unroll
    for (int t = 0; t < 16; t++)
      t_s[(t0+t)*65 + c] += acc[t] + bb;
  }
  __syncthreads();
  // write back + SE partial sums
  for (int e = tid; e < 4096; e += 256) {
    int tok = e >> 6, c = e & 63;
    int zl = tok >> 4, yl = (tok >> 2) & 3, xl = tok & 3;
    int vox = ((zb*4+zl)*32 + (yb*4+yl))*32 + (xb*4+xl);
    grid[gb + (size_t)vox*64 + c] = t_s[tok*65 + c];
  }
  {
    int c = tid & 63, quarter = tid >> 6;
    float ps = 0.f;
    #pragma unroll
    for (int t = 0; t < 16; t++) ps += t_s[(quarter*16+t)*65 + c];
    sered[quarter*64 + c] = ps;
  }
  __syncthreads();
  if (tid < 64)
    atomicAdd(&se_sum[b*64 + tid],
              sered[tid] + sered[64+tid] + sered[128+tid] + sered[192+tid]);
}

// ---------- 6. SE squeeze-excite scale ----------
__global__ void se_kernel(const float* __restrict__ se_sum, const float* __restrict__ w1,
                          const float* __restrict__ w2, float* __restrict__ scale)
{
  __shared__ float mean_s[256];
  __shared__ float z1[32];
  int tid = threadIdx.x;
  mean_s[tid] = se_sum[tid] * (1.f / VX);
  __syncthreads();
  if (tid < 32) {
    int bb = tid >> 3, j = tid & 7;
    float a = 0.f;
    for (int c = 0; c < 64; c++) a += mean_s[bb*64 + c] * w1[j*64 + c];
    z1[tid] = fmaxf(a, 0.f);
  }
  __syncthreads();
  int b = tid >> 6, c = tid & 63;
  float a = 0.f;
  for (int j = 0; j < 8; j++) a += z1[b*8 + j] * w2[c*8 + j];
  scale[tid] = 1.f / (1.f + __expf(-a));
}

// ---------- 7. point branch: x=relu(Wf+b); q,k,v projections ----------
__global__ __launch_bounds__(256) void point_in_kernel(
    const float* __restrict__ features,
    const float* __restrict__ pt_in_w, const float* __restrict__ pt_in_b,
    const float* __restrict__ q_w, const float* __restrict__ k_w,
    const float* __restrict__ v_w,
    float* __restrict__ x_t, float* __restrict__ q_t,
    float* __restrict__ k_t, float* __restrict__ v_t)
{
  __shared__ float f_s[64*65];
  __shared__ float x_s[64*65];
  const int tid = threadIdx.x;
  const int blk = blockIdx.x;            // B*64
  const int b = blk >> 6;
  const int n0 = (blk & 63) * 64;
  for (int e = tid; e < 4096; e += 256) {
    int i = e >> 6, nl = e & 63;
    f_s[nl*65 + i] = features[((size_t)(b*64 + i))*NP + n0 + nl];
  }
  __syncthreads();
  const int c = tid & 63, g = tid >> 6;
  const int t0 = g * 16;
  {
    float acc[16];
    #pragma unroll
    for (int t = 0; t < 16; t++) acc[t] = 0.f;
    for (int i = 0; i < 64; i++) {
      float wv = pt_in_w[c*64 + i];
      #pragma unroll
      for (int t = 0; t < 16; t++) acc[t] += f_s[(t0+t)*65 + i] * wv;
    }
    float bb = pt_in_b[c];
    #pragma unroll
    for (int t = 0; t < 16; t++) {
      float x = fmaxf(acc[t] + bb, 0.f);
      x_s[(t0+t)*65 + c] = x;
      x_t[((size_t)(b*NP) + n0 + t0 + t)*64 + c] = x;
    }
  }
  __syncthreads();
  {
    float acc[16];
    #pragma unroll
    for (int t = 0; t < 16; t++) acc[t] = 0.f;
    for (int k = 0; k < 64; k++) {
      float wv = v_w[c*64 + k];
      #pragma unroll
      for (int t = 0; t < 16; t++) acc[t] += x_s[(t0+t)*65 + k] * wv;
    }
    #pragma unroll
    for (int t = 0; t < 16; t++)
      v_t[((size_t)(b*NP) + n0 + t0 + t)*64 + c] = acc[t];
  }
  if (tid < 128) {
    int d = tid & 15, which = (tid >> 4) & 1, g2 = tid >> 5;
    int t0b = g2 * 16;
    const float* wp = which ? k_w : q_w;
    float scl = which ? 1.f : 0.25f;       // fold 1/sqrt(16) into q
    float acc[16];
    #pragma unroll
    for (int t = 0; t < 16; t++) acc[t] = 0.f;
    for (int cc = 0; cc < 64; cc++) {
      float wv = wp[d*64 + cc];
      #pragma unroll
      for (int t = 0; t < 16; t++) acc[t] += x_s[(t0b+t)*65 + cc] * wv;
    }
    float* dst = which ? k_t : q_t;
    #pragma unroll
    for (int t = 0; t < 16; t++)
      dst[((size_t)(b*NP) + n0 + t0b + t)*16 + d] = acc[t] * scl;
  }
}

// ---------- 8. point attention (flash-style, 64 rows/block) ----------
__global__ __launch_bounds__(256) void point_attn_kernel(
    const float* __restrict__ q_t, const float* __restrict__ k_t,
    const float* __restrict__ v_t, float* __restrict__ o_t)
{
  __shared__ float q_s[64*17];
  __shared__ float k_s[64*17];
  __shared__ float v_s[64*68];
  __shared__ float s_s[64*68];
  __shared__ float rmax[64], rsum[64], ralpha[64];
  const int tid = threadIdx.x;
  const int blk = blockIdx.x;            // B*64
  const int b = blk >> 6;
  const int n0 = (blk & 63) * 64;

  for (int e = tid; e < 1024; e += 256) {
    int r = e >> 4, d = e & 15;
    q_s[r*17 + d] = q_t[((size_t)(b*NP) + n0 + r)*16 + d];
  }
  if (tid < 64) { rmax[tid] = -1e30f; rsum[tid] = 0.f; }
  const int cg = (tid & 15) * 4;
  const int rg = (tid >> 4) * 4;
  float acc[4][4];
  #pragma unroll
  for (int r = 0; r < 4; r++)
    #pragma unroll
    for (int c = 0; c < 4; c++) acc[r][c] = 0.f;
  __syncthreads();

  for (int m0 = 0; m0 < NP; m0 += 64) {
    for (int e = tid; e < 1024; e += 256) {
      int j = e >> 4, d = e & 15;
      k_s[j*17 + d] = k_t[((size_t)(b*NP) + m0 + j)*16 + d];
    }
    for (int e = tid; e < 4096; e += 256) {
      int j = e >> 6, c = e & 63;
      v_s[j*68 + c] = v_t[((size_t)(b*NP) + m0 + j)*64 + c];
    }
    __syncthreads();
    {
      int i = tid >> 2, jg = tid & 3;
      float qv[16];
      #pragma unroll
      for (int d = 0; d < 16; d++) qv[d] = q_s[i*17 + d];
      float sc[16]; float mloc = -1e30f;
      #pragma unroll
      for (int jj = 0; jj < 16; jj++) {
        int j = jg*16 + jj;
        float s = 0.f;
        #pragma unroll
        for (int d = 0; d < 16; d++) s += qv[d] * k_s[j*17 + d];
        sc[jj] = s; mloc = fmaxf(mloc, s);
      }
      mloc = fmaxf(mloc, __shfl_xor(mloc, 1));
      mloc = fmaxf(mloc, __shfl_xor(mloc, 2));
      float mold = rmax[i];
      float mnew = fmaxf(mold, mloc);
      float psum = 0.f;
      #pragma unroll
      for (int jj = 0; jj < 16; jj++) {
        float p = __expf(sc[jj] - mnew);
        s_s[i*68 + jg*16 + jj] = p;
        psum += p;
      }
      psum += __shfl_xor(psum, 1);
      psum += __shfl_xor(psum, 2);
      if (jg == 0) {
        ralpha[i] = __expf(mold - mnew);
        rmax[i] = mnew;
        rsum[i] = rsum[i]*ralpha[i] + psum;
      }
    }
    __syncthreads();
    {
      float al[4];
      #pragma unroll
      for (int r = 0; r < 4; r++) al[r] = ralpha[rg + r];
      #pragma unroll
      for (int r = 0; r < 4; r++)
        #pragma unroll
        for (int c = 0; c < 4; c++) acc[r][c] *= al[r];
      for (int j4 = 0; j4 < 16; j4++) {
        float4 sv[4];
        #pragma unroll
        for (int r = 0; r < 4; r++)
          sv[r] = *(const float4*)&s_s[(rg+r)*68 + j4*4];
        #pragma unroll
        for (int jj = 0; jj < 4; jj++) {
          float4 vv = *(const float4*)&v_s[(j4*4+jj)*68 + cg];
          #pragma unroll
          for (int r = 0; r < 4; r++) {
            float p = (jj==0)?sv[r].x:(jj==1)?sv[r].y:(jj==2)?sv[r].z:sv[r].w;
            acc[r][0] += p*vv.x; acc[r][1] += p*vv.y;
            acc[r][2] += p*vv.z; acc[r][3] += p*vv.w;
          }
        }
      }
    }
    __syncthreads();
  }
  #pragma unroll
  for (int r = 0; r < 4; r++) {
    float inv = 1.f / rsum[rg + r];
    float4 o4;
    o4.x = acc[r][0]*inv; o4.y = acc[r][1]*inv;
    o4.z = acc[r][2]*inv; o4.w = acc[r][3]*inv;
    *(float4*)&o_t[((size_t)(b*NP) + n0 + rg + r)*64 + cg] = o4;
  }
}

// ---------- 9. devox + offset transform + fuse + transpose-store ----------
__global__ __launch_bounds__(256) void fuse_kernel(
    const float* __restrict__ x_t, const float* __restrict__ o_t,
    const float* __restrict__ trans_w, const float* __restrict__ trans_b,
    const float* __restrict__ grid, const float* __restrict__ se_scale,
    const float* __restrict__ nc, float* __restrict__ out)
{
  __shared__ float tw_s[64*65];
  __shared__ float d_s[64*65];
  __shared__ float r_s[64*65];
  const int tid = threadIdx.x;
  const int blk = blockIdx.x;            // B*64
  const int b = blk >> 6;
  const int n0 = (blk & 63) * 64;
  for (int e = tid; e < 4096; e += 256) {
    int c = e >> 6, k = e & 63;
    tw_s[c*65 + k] = trans_w[e];
  }
  for (int e = tid; e < 4096; e += 256) {
    int nl = e >> 6, c = e & 63;
    size_t idx = ((size_t)(b*NP) + n0 + nl)*64 + c;
    d_s[nl*65 + c] = x_t[idx] - o_t[idx];
  }
  __syncthreads();
  const int cl = tid & 63, g = tid >> 6;
  const float ses = se_scale[b*64 + cl];
  const float tb = trans_b[cl];
  for (int t = 0; t < 16; t++) {
    int nl = g*16 + t;
    int n = n0 + nl;
    float off = 0.f;
    for (int k = 0; k < 64; k++) off += tw_s[cl*65 + k] * d_s[nl*65 + k];
    off = fmaxf(off + tb, 0.f);
    float ncx = nc[((size_t)(b*3)+0)*NP + n];
    float ncy = nc[((size_t)(b*3)+1)*NP + n];
    float ncz = nc[((size_t)(b*3)+2)*NP + n];
    float fx0 = floorf(ncx), fy0 = floorf(ncy), fz0 = floorf(ncz);
    int x0 = (int)fx0, y0 = (int)fy0, z0 = (int)fz0;
    float fx = ncx - fx0, fy = ncy - fy0, fz = ncz - fz0;
    float wx[2] = {1.f-fx, fx}, wy[2] = {1.f-fy, fy}, wz[2] = {1.f-fz, fz};
    float vf = 0.f;
    #pragma unroll
    for (int cor = 0; cor < 8; cor++) {
      int dx = cor >> 2, dy = (cor >> 1) & 1, dz = cor & 1;
      int xi = min(x0+dx, 31), yi = min(y0+dy, 31), zi = min(z0+dz, 31);
      float wgt = wx[dx]*wy[dy]*wz[dz];
      vf += wgt * grid[((size_t)(b*VX) + (xi*32+yi)*32 + zi)*64 + cl];
    }
    vf *= ses;
    float xval = x_t[((size_t)(b*NP) + n)*64 + cl];
    r_s[cl*65 + nl] = xval + off + vf;
  }
  __syncthreads();
  for (int e = tid; e < 4096; e += 256) {
    int c = e >> 6, nl = e & 63;
    out[((size_t)(b*64) + c)*NP + n0 + nl] = r_s[c*65 + nl];
  }
}

extern "C" void kernel_launch(void* const* d_in, const int* in_sizes, int n_in,
                              void* d_out, int out_size, void* d_ws, size_t ws_size,
                              hipStream_t stream)
{
  const float* features = (const float*)d_in[0];
  const float* coords   = (const float*)d_in[1];
  const float* conv_w   = (const float*)d_in[2];
  const float* conv_b   = (const float*)d_in[3];
  const float* ln1_g    = (const float*)d_in[4];
  const float* ln1_b    = (const float*)d_in[5];
  const float* qkv_w    = (const float*)d_in[6];
  const float* qkv_b    = (const float*)d_in[7];
  const float* proj_w   = (const float*)d_in[8];
  const float* proj_b   = (const float*)d_in[9];
  const float* ln2_g    = (const float*)d_in[10];
  const float* ln2_b    = (const float*)d_in[11];
  const float* mlp_w1   = (const float*)d_in[12];
  const float* mlp_b1   = (const float*)d_in[13];
  const float* mlp_w2   = (const float*)d_in[14];
  const float* mlp_b2   = (const float*)d_in[15];
  const float* se_w1    = (const float*)d_in[16];
  const float* se_w2    = (const float*)d_in[17];
  const float* pt_in_w  = (const float*)d_in[18];
  const float* pt_in_b  = (const float*)d_in[19];
  const float* q_w      = (const float*)d_in[20];
  const float* k_w      = (const float*)d_in[21];
  const float* v_w      = (const float*)d_in[22];
  const float* v_trans_w= (const float*)d_in[23];
  const float* v_trans_b= (const float*)d_in[24];

  char* ws = (char*)d_ws;
  float* stats    = (float*)(ws + 0);
  float* se_sum   = (float*)(ws + 256);
  float* se_scale = (float*)(ws + 1280);
  float* nc       = (float*)(ws + 4096);                 // 196608 B
  float* cnt      = (float*)(ws + 200704);               // 524288 B (zeroed)
  float* grid0    = (float*)(ws + 724992);               // 33.5 MB (zeroed)
  float* grid1    = (float*)(ws + 34279424);             // 33.5 MB
  // point-branch buffers reuse grid0 region (free after conv)
  float* x_t = (float*)(ws + 724992);
  float* q_t = (float*)(ws + 724992 + 4194304);
  float* k_t = (float*)(ws + 724992 + 5242880);
  float* v_t = (float*)(ws + 724992 + 6291456);
  float* o_t = (float*)(ws + 724992 + 10485760);

  hipMemsetAsync(se_sum, 0, 1024, stream);
  hipMemsetAsync(cnt, 0, 524288 + 33554432, stream);     // cnt + grid0 contiguous

  stats_kernel<<<BN, 256, 0, stream>>>(coords, stats);
  scatter_kernel<<<256, 256, 0, stream>>>(features, coords, stats, nc, grid0, cnt);
  finalize_kernel<<<32768, 256, 0, stream>>>(grid0, cnt);
  conv_kernel<<<2048, 256, 0, stream>>>(grid0, conv_w, conv_b, grid1);
  encoder_kernel<<<2048, 256, 0, stream>>>(grid1, ln1_g, ln1_b, qkv_w, qkv_b,
      proj_w, proj_b, ln2_g, ln2_b, mlp_w1, mlp_b1, mlp_w2, mlp_b2, se_sum);
  se_kernel<<<1, 256, 0, stream>>>(se_sum, se_w1, se_w2, se_scale);
  point_in_kernel<<<256, 256, 0, stream>>>(features, pt_in_w, pt_in_b, q_w, k_w, v_w,
      x_t, q_t, k_t, v_t);
  point_attn_kernel<<<256, 256, 0, stream>>>(q_t, k_t, v_t, o_t);
  fuse_kernel<<<256, 256, 0, stream>>>(x_t, o_t, v_trans_w, v_trans_b, grid1,
      se_scale, nc, (float*)d_out);
  hipMemcpyAsync((char*)d_out + (size_t)BN*64*NP*4, coords, (size_t)BN*3*NP*4,
                 hipMemcpyDeviceToDevice, stream);
}

// Round 2
// 1233.174 us; speedup vs baseline: 2.4534x; 2.4534x over previous
//
#include <hip/hip_runtime.h>

#define BN 4
#define NP 4096
#define RV 32
#define VX (RV*RV*RV)

typedef __attribute__((ext_vector_type(8))) short bf16x8;
typedef __attribute__((ext_vector_type(4))) float f32x4;

// ---------- bf16 helpers (bit-level) ----------
__device__ __forceinline__ float bf2f(unsigned short u){
  union{unsigned u;float f;}v; v.u=((unsigned)u)<<16; return v.f; }
__device__ __forceinline__ unsigned short f2bf(float f){
  union{float f;unsigned u;}v; v.f=f; unsigned r=v.u + 0x7fffu + ((v.u>>16)&1u);
  return (unsigned short)(r>>16); }
__device__ __forceinline__ float2 bfp2f2(unsigned p){
  union{unsigned u;float f;}a,b; a.u=p<<16; b.u=p&0xffff0000u;
  float2 r; r.x=a.f; r.y=b.f; return r; }
__device__ __forceinline__ unsigned pack2bf(float a, float b){
  return (unsigned)f2bf(a) | ((unsigned)f2bf(b) << 16); }

union ABu { uint4 u; bf16x8 v; };

// ---------- 1. per-batch coord stats ----------
__global__ void stats_kernel(const float* __restrict__ coords, float* __restrict__ stats)
{
  __shared__ float red[256];
  __shared__ float mean[3];
  const int b = blockIdx.x;
  const int tid = threadIdx.x;
  float s0=0.f,s1=0.f,s2=0.f;
  for (int n = tid; n < NP; n += 256) {
    s0 += coords[((size_t)(b*3)+0)*NP + n];
    s1 += coords[((size_t)(b*3)+1)*NP + n];
    s2 += coords[((size_t)(b*3)+2)*NP + n];
  }
  float sv[3] = {s0,s1,s2};
  for (int ax = 0; ax < 3; ax++) {
    __syncthreads();
    red[tid] = sv[ax];
    __syncthreads();
    for (int st = 128; st > 0; st >>= 1) {
      if (tid < st) red[tid] += red[tid + st];
      __syncthreads();
    }
    if (tid == 0) mean[ax] = red[0] * (1.f / NP);
  }
  __syncthreads();
  float mx = 0.f;
  for (int n = tid; n < NP; n += 256) {
    float d0 = coords[((size_t)(b*3)+0)*NP + n] - mean[0];
    float d1 = coords[((size_t)(b*3)+1)*NP + n] - mean[1];
    float d2 = coords[((size_t)(b*3)+2)*NP + n] - mean[2];
    mx = fmaxf(mx, sqrtf(d0*d0 + d1*d1 + d2*d2));
  }
  __syncthreads();
  red[tid] = mx;
  __syncthreads();
  for (int st = 128; st > 0; st >>= 1) {
    if (tid < st) red[tid] = fmaxf(red[tid], red[tid + st]);
    __syncthreads();
  }
  if (tid == 0) {
    stats[b*4+0] = mean[0]; stats[b*4+1] = mean[1];
    stats[b*4+2] = mean[2]; stats[b*4+3] = red[0];
  }
}

// ---------- 2. voxelize scatter-sum ----------
__global__ void scatter_kernel(const float* __restrict__ features,
                               const float* __restrict__ coords,
                               const float* __restrict__ stats,
                               float* __restrict__ nc,
                               float* __restrict__ sums, float* __restrict__ cnt)
{
  int t = blockIdx.x*256 + threadIdx.x;   // B*N*4 threads
  int part = t & 3;
  int p = t >> 2;
  int b = p >> 12;
  int n = p & 4095;
  float m0 = stats[b*4+0], m1 = stats[b*4+1], m2 = stats[b*4+2], mx = stats[b*4+3];
  float inv = 1.f / (2.f * mx);
  float c0 = (coords[((size_t)(b*3)+0)*NP + n] - m0) * inv + 0.5f;
  float c1 = (coords[((size_t)(b*3)+1)*NP + n] - m1) * inv + 0.5f;
  float c2 = (coords[((size_t)(b*3)+2)*NP + n] - m2) * inv + 0.5f;
  float g0 = fminf(fmaxf(c0 * 32.f, 0.f), 31.f);
  float g1 = fminf(fmaxf(c1 * 32.f, 0.f), 31.f);
  float g2 = fminf(fmaxf(c2 * 32.f, 0.f), 31.f);
  int v0 = (int)rintf(g0), v1 = (int)rintf(g1), v2 = (int)rintf(g2);
  int idx = (v0*32 + v1)*32 + v2 + b*VX;
  if (part == 0) {
    nc[((size_t)(b*3)+0)*NP + n] = g0;
    nc[((size_t)(b*3)+1)*NP + n] = g1;
    nc[((size_t)(b*3)+2)*NP + n] = g2;
    atomicAdd(&cnt[idx], 1.f);
  }
  const float* fp = features + (size_t)(b*64)*NP + n;
  float* sp = sums + (size_t)idx*64;
  for (int i = part*16; i < part*16+16; i++)
    atomicAdd(&sp[i], fp[(size_t)i*NP]);
}

// ---------- 3. weight prep: (O,I,27) fp32 -> [tap][o][c16^swz] bf16x8 ----------
__global__ void wprep_kernel(const float* __restrict__ wt, unsigned short* __restrict__ wpre)
{
  int t = blockIdx.x*256 + threadIdx.x;  // 27*64*8 = 13824
  if (t >= 27*64*8) return;
  int c16 = t & 7, o = (t >> 3) & 63, tap = t >> 9;
  size_t dst = ((size_t)(tap*64 + o)*8 + (c16 ^ (o & 7))) * 8;
  #pragma unroll
  for (int j = 0; j < 8; j++) {
    int i = c16*8 + j;
    wpre[dst + j] = f2bf(wt[(o*64 + i)*27 + tap]);
  }
}

// ---------- 4. 3x3x3 conv via MFMA implicit GEMM ----------
// block: 256 thr = 4 waves; tile M=128 (4 y rows x 32 x) x N=64; z fixed.
__global__ __launch_bounds__(256) void conv_mfma_kernel(
    const float* __restrict__ sums, const float* __restrict__ cnt,
    const unsigned short* __restrict__ wpre,
    const float* __restrict__ bias, float* __restrict__ gout)
{
  __shared__ uint4 plane[6*34*8];   // [yl][sx][c16p]  25.5 KB
  __shared__ uint4 wsm[3*64*8];     // [kw][o][c16p]   24 KB
  const int tid = threadIdx.x;
  const int blk = blockIdx.x;       // B*32*8
  const int yq = blk & 7, z = (blk >> 3) & 31, b = blk >> 8;
  const int y0 = yq * 4;
  const int w  = tid >> 6;          // wave = y row
  const int lm = tid & 15;
  const int kg = (tid >> 4) & 3;

  f32x4 acc[2][4];
  #pragma unroll
  for (int mt = 0; mt < 2; mt++)
    #pragma unroll
    for (int nt = 0; nt < 4; nt++)
      #pragma unroll
      for (int r = 0; r < 4; r++) acc[mt][nt][r] = 0.f;

  float bv[4];
  #pragma unroll
  for (int nt = 0; nt < 4; nt++) bv[nt] = bias[nt*16 + lm];

  for (int kd = 0; kd < 3; kd++) {
    const int zz = z + kd - 1;
    if (zz < 0 || zz >= 32) continue;           // block-uniform
    __syncthreads();
    // stage z-plane: fp32 sums / cnt -> bf16, swizzled
    for (int e = tid; e < 6*34*8; e += 256) {
      int c16 = e & 7;
      int sx  = (e >> 3) % 34;
      int yl  = e / (34*8);
      int yy = y0 - 1 + yl, x = sx - 1;
      uint4 val = make_uint4(0u,0u,0u,0u);
      if (yy >= 0 && yy < 32 && x >= 0 && x < 32) {
        size_t vox = (size_t)(b*VX) + (zz*32 + yy)*32 + x;
        float rc = 1.f / fmaxf(cnt[vox], 1.f);
        const float* src = sums + vox*64 + c16*8;
        float4 f0 = *(const float4*)(src);
        float4 f1 = *(const float4*)(src + 4);
        val.x = pack2bf(f0.x*rc, f0.y*rc);
        val.y = pack2bf(f0.z*rc, f0.w*rc);
        val.z = pack2bf(f1.x*rc, f1.y*rc);
        val.w = pack2bf(f1.z*rc, f1.w*rc);
      }
      plane[(yl*34 + sx)*8 + (c16 ^ (sx & 7))] = val;
    }
    for (int kh = 0; kh < 3; kh++) {
      __syncthreads();
      const uint4* wsrc = (const uint4*)wpre + (size_t)((kd*3 + kh)*3)*512;
      for (int e = tid; e < 1536; e += 256) wsm[e] = wsrc[e];
      __syncthreads();
      const int yi = w + kh;
      #pragma unroll
      for (int kw = 0; kw < 3; kw++) {
        const int sxa = lm + kw, sxb = sxa + 16;
        const int swz = sxa & 7;
        #pragma unroll
        for (int ch = 0; ch < 2; ch++) {
          const int cb = ch*4 + kg;
          ABu a0, a1, w0, w1, w2, w3;
          a0.u = plane[(yi*34 + sxa)*8 + (cb ^ swz)];
          a1.u = plane[(yi*34 + sxb)*8 + (cb ^ swz)];
          const int wsz = cb ^ (lm & 7);
          w0.u = wsm[(kw*64 +      lm)*8 + wsz];
          w1.u = wsm[(kw*64 + 16 + lm)*8 + wsz];
          w2.u = wsm[(kw*64 + 32 + lm)*8 + wsz];
          w3.u = wsm[(kw*64 + 48 + lm)*8 + wsz];
          acc[0][0] = __builtin_amdgcn_mfma_f32_16x16x32_bf16(a0.v, w0.v, acc[0][0], 0,0,0);
          acc[1][0] = __builtin_amdgcn_mfma_f32_16x16x32_bf16(a1.v, w0.v, acc[1][0], 0,0,0);
          acc[0][1] = __builtin_amdgcn_mfma_f32_16x16x32_bf16(a0.v, w1.v, acc[0][1], 0,0,0);
          acc[1][1] = __builtin_amdgcn_mfma_f32_16x16x32_bf16(a1.v, w1.v, acc[1][1], 0,0,0);
          acc[0][2] = __builtin_amdgcn_mfma_f32_16x16x32_bf16(a0.v, w2.v, acc[0][2], 0,0,0);
          acc[1][2] = __builtin_amdgcn_mfma_f32_16x16x32_bf16(a1.v, w2.v, acc[1][2], 0,0,0);
          acc[0][3] = __builtin_amdgcn_mfma_f32_16x16x32_bf16(a0.v, w3.v, acc[0][3], 0,0,0);
          acc[1][3] = __builtin_amdgcn_mfma_f32_16x16x32_bf16(a1.v, w3.v, acc[1][3], 0,0,0);
        }
      }
    }
  }
  // epilogue: bias + relu; C/D: col=lane&15, row=(lane>>4)*4+reg
  const int y = y0 + w;
  #pragma unroll
  for (int mt = 0; mt < 2; mt++) {
    #pragma unroll
    for (int r = 0; r < 4; r++) {
      const int x = mt*16 + kg*4 + r;
      float* dst = gout + ((size_t)(b*VX) + (z*32 + y)*32 + x)*64 + lm;
      #pragma unroll
      for (int nt = 0; nt < 4; nt++)
        dst[nt*16] = fmaxf(acc[mt][nt][r] + bv[nt], 0.f);
    }
  }
}

// ---------- 5. windowed transformer encoder (in-place on grid1) ----------
__global__ __launch_bounds__(256) void encoder_kernel(
    float* __restrict__ grid,
    const float* __restrict__ ln1_g, const float* __restrict__ ln1_b,
    const float* __restrict__ qkv_w, const float* __restrict__ qkv_b,
    const float* __restrict__ proj_w, const float* __restrict__ proj_b,
    const float* __restrict__ ln2_g, const float* __restrict__ ln2_b,
    const float* __restrict__ w1, const float* __restrict__ b1,
    const float* __restrict__ w2, const float* __restrict__ b2,
    float* __restrict__ se_sum)
{
  __shared__ float t_s[64*65];
  __shared__ unsigned short h_s[64*66];
  __shared__ unsigned short big[4*64*66];
  __shared__ float mean_s[64], rstd_s[64];
  __shared__ float sered[256];
  unsigned short* q_s  = big;
  unsigned short* k_s  = big + 4224;
  unsigned short* v_s  = big + 8448;
  unsigned short* pw_s = big + 12672;
  unsigned short* hid  = big;

  const int tid = threadIdx.x;
  const int win = blockIdx.x;
  const int b = win >> 9, w = win & 511;
  const int zb = w >> 6, yb = (w >> 3) & 7, xb = w & 7;
  const size_t gb = (size_t)b * VX * 64;

  for (int e = tid; e < 4096; e += 256) {
    int tok = e >> 6, c = e & 63;
    int zl = tok >> 4, yl = (tok >> 2) & 3, xl = tok & 3;
    int vox = ((zb*4+zl)*32 + (yb*4+yl))*32 + (xb*4+xl);
    t_s[tok*65 + c] = grid[gb + (size_t)vox*64 + c];
  }
  __syncthreads();
  {
    int i = tid >> 2, part = tid & 3;
    float sum = 0.f, sq = 0.f;
    for (int c = part; c < 64; c += 4) { float x = t_s[i*65+c]; sum += x; sq += x*x; }
    sum += __shfl_xor(sum, 1); sq += __shfl_xor(sq, 1);
    sum += __shfl_xor(sum, 2); sq += __shfl_xor(sq, 2);
    if (part == 0) {
      float m = sum * (1.f/64.f);
      float var = sq * (1.f/64.f) - m*m;
      mean_s[i] = m; rstd_s[i] = rsqrtf(var + 1e-5f);
    }
  }
  __syncthreads();
  for (int e = tid; e < 4096; e += 256) {
    int tok = e & 63, c = e >> 6;
    float h = (t_s[tok*65+c] - mean_s[tok]) * rstd_s[tok] * ln1_g[c] + ln1_b[c];
    h_s[c*66 + tok] = f2bf(h);
    pw_s[(e>>6)*66 + (e&63)] = f2bf(proj_w[e]);
  }
  __syncthreads();
  for (int item = 0; item < 3; item++) {
    int wk = tid + item*256;
    int d = wk % 192, quarter = wk / 192;
    int t0 = quarter * 16;
    float acc[16];
    #pragma unroll
    for (int t = 0; t < 16; t++) acc[t] = 0.f;
    for (int c = 0; c < 64; c++) {
      float wv = qkv_w[d*64 + c];
      const unsigned* hp = (const unsigned*)(h_s + c*66 + t0);
      #pragma unroll
      for (int t2 = 0; t2 < 8; t2++) {
        float2 hf = bfp2f2(hp[t2]);
        acc[2*t2]   += hf.x * wv;
        acc[2*t2+1] += hf.y * wv;
      }
    }
    float bb = qkv_b[d];
    unsigned short* dst; int dd; float sc;
    if (d < 64)       { dst = q_s; dd = d;       sc = 0.25f; }
    else if (d < 128) { dst = k_s; dd = d - 64;  sc = 1.f; }
    else              { dst = v_s; dd = d - 128; sc = 1.f; }
    #pragma unroll
    for (int t = 0; t < 16; t++)
      dst[(t0+t)*66 + dd] = f2bf((acc[t] + bb) * sc);
  }
  __syncthreads();
  {
    int i = tid >> 2, jg = tid & 3;
    for (int h = 0; h < 4; h++) {
      int hb = h * 16;
      float qv[16];
      #pragma unroll
      for (int d = 0; d < 16; d++) qv[d] = bf2f(q_s[i*66 + hb + d]);
      float p[16]; float mx = -1e30f;
      #pragma unroll
      for (int jj = 0; jj < 16; jj++) {
        int j = jg*16 + jj;
        float s = 0.f;
        #pragma unroll
        for (int d = 0; d < 16; d++) s += qv[d] * bf2f(k_s[j*66 + hb + d]);
        p[jj] = s; mx = fmaxf(mx, s);
      }
      mx = fmaxf(mx, __shfl_xor(mx, 1));
      mx = fmaxf(mx, __shfl_xor(mx, 2));
      float sum = 0.f;
      #pragma unroll
      for (int jj = 0; jj < 16; jj++) { p[jj] = __expf(p[jj]-mx); sum += p[jj]; }
      sum += __shfl_xor(sum, 1);
      sum += __shfl_xor(sum, 2);
      float po[16];
      #pragma unroll
      for (int d = 0; d < 16; d++) po[d] = 0.f;
      #pragma unroll
      for (int jj = 0; jj < 16; jj++) {
        int j = jg*16 + jj; float pv = p[jj];
        #pragma unroll
        for (int d = 0; d < 16; d++) po[d] += pv * bf2f(v_s[j*66 + hb + d]);
      }
      float invs = 1.f / sum;
      #pragma unroll
      for (int d = 0; d < 16; d++) {
        po[d] += __shfl_xor(po[d], 1);
        po[d] += __shfl_xor(po[d], 2);
        po[d] *= invs;
      }
      #pragma unroll
      for (int cc = 0; cc < 16; cc++) {
        int c = jg*16 + cc;
        float a = 0.f;
        #pragma unroll
        for (int d = 0; d < 16; d++) a += po[d] * bf2f(pw_s[c*66 + hb + d]);
        if (h == 0) a += proj_b[c];
        t_s[i*65 + c] += a;
      }
    }
  }
  __syncthreads();
  {
    int i = tid >> 2, part = tid & 3;
    float sum = 0.f, sq = 0.f;
    for (int c = part; c < 64; c += 4) { float x = t_s[i*65+c]; sum += x; sq += x*x; }
    sum += __shfl_xor(sum, 1); sq += __shfl_xor(sq, 1);
    sum += __shfl_xor(sum, 2); sq += __shfl_xor(sq, 2);
    if (part == 0) {
      float m = sum * (1.f/64.f);
      float var = sq * (1.f/64.f) - m*m;
      mean_s[i] = m; rstd_s[i] = rsqrtf(var + 1e-5f);
    }
  }
  __syncthreads();
  for (int e = tid; e < 4096; e += 256) {
    int tok = e & 63, c = e >> 6;
    float h = (t_s[tok*65+c] - mean_s[tok]) * rstd_s[tok] * ln2_g[c] + ln2_b[c];
    h_s[c*66 + tok] = f2bf(h);
  }
  __syncthreads();
  for (int item = 0; item < 4; item++) {
    int wk = tid + item*256;
    int m = wk & 255, quarter = wk >> 8;
    int t0 = quarter * 16;
    float acc[16];
    #pragma unroll
    for (int t = 0; t < 16; t++) acc[t] = 0.f;
    for (int c = 0; c < 64; c++) {
      float wv = w1[m*64 + c];
      const unsigned* hp = (const unsigned*)(h_s + c*66 + t0);
      #pragma unroll
      for (int t2 = 0; t2 < 8; t2++) {
        float2 hf = bfp2f2(hp[t2]);
        acc[2*t2]   += hf.x * wv;
        acc[2*t2+1] += hf.y * wv;
      }
    }
    float bb = b1[m];
    #pragma unroll
    for (int t = 0; t < 16; t++) {
      float x = acc[t] + bb;
      float gl = 0.5f * x * (1.f + tanhf(0.7978845608f*(x + 0.044715f*x*x*x)));
      hid[m*66 + t0 + t] = f2bf(gl);
    }
  }
  __syncthreads();
  {
    int c = tid & 63, quarter = tid >> 6;
    int t0 = quarter * 16;
    float acc[16];
    #pragma unroll
    for (int t = 0; t < 16; t++) acc[t] = 0.f;
    for (int k = 0; k < 256; k++) {
      float wv = w2[c*256 + k];
      const unsigned* hp = (const unsigned*)(hid + k*66 + t0);
      #pragma unroll
      for (int t2 = 0; t2 < 8; t2++) {
        float2 hf = bfp2f2(hp[t2]);
        acc[2*t2]   += hf.x * wv;
        acc[2*t2+1] += hf.y * wv;
      }
    }
    float bb = b2[c];
    #pragma unroll
    for (int t = 0; t < 16; t++)
      t_s[(t0+t)*65 + c] += acc[t] + bb;
  }
  __syncthreads();
  for (int e = tid; e < 4096; e += 256) {
    int tok = e >> 6, c = e & 63;
    int zl = tok >> 4, yl = (tok >> 2) & 3, xl = tok & 3;
    int vox = ((zb*4+zl)*32 + (yb*4+yl))*32 + (xb*4+xl);
    grid[gb + (size_t)vox*64 + c] = t_s[tok*65 + c];
  }
  {
    int c = tid & 63, quarter = tid >> 6;
    float ps = 0.f;
    #pragma unroll
    for (int t = 0; t < 16; t++) ps += t_s[(quarter*16+t)*65 + c];
    sered[quarter*64 + c] = ps;
  }
  __syncthreads();
  if (tid < 64)
    atomicAdd(&se_sum[b*64 + tid],
              sered[tid] + sered[64+tid] + sered[128+tid] + sered[192+tid]);
}

// ---------- 6. SE squeeze-excite scale ----------
__global__ void se_kernel(const float* __restrict__ se_sum, const float* __restrict__ w1,
                          const float* __restrict__ w2, float* __restrict__ scale)
{
  __shared__ float mean_s[256];
  __shared__ float z1[32];
  int tid = threadIdx.x;
  mean_s[tid] = se_sum[tid] * (1.f / VX);
  __syncthreads();
  if (tid < 32) {
    int bb = tid >> 3, j = tid & 7;
    float a = 0.f;
    for (int c = 0; c < 64; c++) a += mean_s[bb*64 + c] * w1[j*64 + c];
    z1[tid] = fmaxf(a, 0.f);
  }
  __syncthreads();
  int b = tid >> 6, c = tid & 63;
  float a = 0.f;
  for (int j = 0; j < 8; j++) a += z1[b*8 + j] * w2[c*8 + j];
  scale[tid] = 1.f / (1.f + __expf(-a));
}

// ---------- 7. point branch: x=relu(Wf+b); q,k,v projections ----------
__global__ __launch_bounds__(256) void point_in_kernel(
    const float* __restrict__ features,
    const float* __restrict__ pt_in_w, const float* __restrict__ pt_in_b,
    const float* __restrict__ q_w, const float* __restrict__ k_w,
    const float* __restrict__ v_w,
    float* __restrict__ x_t, float* __restrict__ q_t,
    float* __restrict__ k_t, float* __restrict__ v_t)
{
  __shared__ float f_s[64*65];
  __shared__ float x_s[64*65];
  const int tid = threadIdx.x;
  const int blk = blockIdx.x;
  const int b = blk >> 6;
  const int n0 = (blk & 63) * 64;
  for (int e = tid; e < 4096; e += 256) {
    int i = e >> 6, nl = e & 63;
    f_s[nl*65 + i] = features[((size_t)(b*64 + i))*NP + n0 + nl];
  }
  __syncthreads();
  const int c = tid & 63, g = tid >> 6;
  const int t0 = g * 16;
  {
    float acc[16];
    #pragma unroll
    for (int t = 0; t < 16; t++) acc[t] = 0.f;
    for (int i = 0; i < 64; i++) {
      float wv = pt_in_w[c*64 + i];
      #pragma unroll
      for (int t = 0; t < 16; t++) acc[t] += f_s[(t0+t)*65 + i] * wv;
    }
    float bb = pt_in_b[c];
    #pragma unroll
    for (int t = 0; t < 16; t++) {
      float x = fmaxf(acc[t] + bb, 0.f);
      x_s[(t0+t)*65 + c] = x;
      x_t[((size_t)(b*NP) + n0 + t0 + t)*64 + c] = x;
    }
  }
  __syncthreads();
  {
    float acc[16];
    #pragma unroll
    for (int t = 0; t < 16; t++) acc[t] = 0.f;
    for (int k = 0; k < 64; k++) {
      float wv = v_w[c*64 + k];
      #pragma unroll
      for (int t = 0; t < 16; t++) acc[t] += x_s[(t0+t)*65 + k] * wv;
    }
    #pragma unroll
    for (int t = 0; t < 16; t++)
      v_t[((size_t)(b*NP) + n0 + t0 + t)*64 + c] = acc[t];
  }
  if (tid < 128) {
    int d = tid & 15, which = (tid >> 4) & 1, g2 = tid >> 5;
    int t0b = g2 * 16;
    const float* wp = which ? k_w : q_w;
    float scl = which ? 1.f : 0.25f;
    float acc[16];
    #pragma unroll
    for (int t = 0; t < 16; t++) acc[t] = 0.f;
    for (int cc = 0; cc < 64; cc++) {
      float wv = wp[d*64 + cc];
      #pragma unroll
      for (int t = 0; t < 16; t++) acc[t] += x_s[(t0b+t)*65 + cc] * wv;
    }
    float* dst = which ? k_t : q_t;
    #pragma unroll
    for (int t = 0; t < 16; t++)
      dst[((size_t)(b*NP) + n0 + t0b + t)*16 + d] = acc[t] * scl;
  }
}

// ---------- 8. point attention (flash-style, 64 rows/block) ----------
__global__ __launch_bounds__(256) void point_attn_kernel(
    const float* __restrict__ q_t, const float* __restrict__ k_t,
    const float* __restrict__ v_t, float* __restrict__ o_t)
{
  __shared__ float q_s[64*17];
  __shared__ float k_s[64*17];
  __shared__ float v_s[64*68];
  __shared__ float s_s[64*68];
  __shared__ float rmax[64], rsum[64], ralpha[64];
  const int tid = threadIdx.x;
  const int blk = blockIdx.x;
  const int b = blk >> 6;
  const int n0 = (blk & 63) * 64;

  for (int e = tid; e < 1024; e += 256) {
    int r = e >> 4, d = e & 15;
    q_s[r*17 + d] = q_t[((size_t)(b*NP) + n0 + r)*16 + d];
  }
  if (tid < 64) { rmax[tid] = -1e30f; rsum[tid] = 0.f; }
  const int cg = (tid & 15) * 4;
  const int rg = (tid >> 4) * 4;
  float acc[4][4];
  #pragma unroll
  for (int r = 0; r < 4; r++)
    #pragma unroll
    for (int c = 0; c < 4; c++) acc[r][c] = 0.f;
  __syncthreads();

  for (int m0 = 0; m0 < NP; m0 += 64) {
    for (int e = tid; e < 1024; e += 256) {
      int j = e >> 4, d = e & 15;
      k_s[j*17 + d] = k_t[((size_t)(b*NP) + m0 + j)*16 + d];
    }
    for (int e = tid; e < 4096; e += 256) {
      int j = e >> 6, c = e & 63;
      v_s[j*68 + c] = v_t[((size_t)(b*NP) + m0 + j)*64 + c];
    }
    __syncthreads();
    {
      int i = tid >> 2, jg = tid & 3;
      float qv[16];
      #pragma unroll
      for (int d = 0; d < 16; d++) qv[d] = q_s[i*17 + d];
      float sc[16]; float mloc = -1e30f;
      #pragma unroll
      for (int jj = 0; jj < 16; jj++) {
        int j = jg*16 + jj;
        float s = 0.f;
        #pragma unroll
        for (int d = 0; d < 16; d++) s += qv[d] * k_s[j*17 + d];
        sc[jj] = s; mloc = fmaxf(mloc, s);
      }
      mloc = fmaxf(mloc, __shfl_xor(mloc, 1));
      mloc = fmaxf(mloc, __shfl_xor(mloc, 2));
      float mold = rmax[i];
      float mnew = fmaxf(mold, mloc);
      float psum = 0.f;
      #pragma unroll
      for (int jj = 0; jj < 16; jj++) {
        float p = __expf(sc[jj] - mnew);
        s_s[i*68 + jg*16 + jj] = p;
        psum += p;
      }
      psum += __shfl_xor(psum, 1);
      psum += __shfl_xor(psum, 2);
      if (jg == 0) {
        ralpha[i] = __expf(mold - mnew);
        rmax[i] = mnew;
        rsum[i] = rsum[i]*ralpha[i] + psum;
      }
    }
    __syncthreads();
    {
      float al[4];
      #pragma unroll
      for (int r = 0; r < 4; r++) al[r] = ralpha[rg + r];
      #pragma unroll
      for (int r = 0; r < 4; r++)
        #pragma unroll
        for (int c = 0; c < 4; c++) acc[r][c] *= al[r];
      for (int j4 = 0; j4 < 16; j4++) {
        float4 sv[4];
        #pragma unroll
        for (int r = 0; r < 4; r++)
          sv[r] = *(const float4*)&s_s[(rg+r)*68 + j4*4];
        #pragma unroll
        for (int jj = 0; jj < 4; jj++) {
          float4 vv = *(const float4*)&v_s[(j4*4+jj)*68 + cg];
          #pragma unroll
          for (int r = 0; r < 4; r++) {
            float p = (jj==0)?sv[r].x:(jj==1)?sv[r].y:(jj==2)?sv[r].z:sv[r].w;
            acc[r][0] += p*vv.x; acc[r][1] += p*vv.y;
            acc[r][2] += p*vv.z; acc[r][3] += p*vv.w;
          }
        }
      }
    }
    __syncthreads();
  }
  #pragma unroll
  for (int r = 0; r < 4; r++) {
    float inv = 1.f / rsum[rg + r];
    float4 o4;
    o4.x = acc[r][0]*inv; o4.y = acc[r][1]*inv;
    o4.z = acc[r][2]*inv; o4.w = acc[r][3]*inv;
    *(float4*)&o_t[((size_t)(b*NP) + n0 + rg + r)*64 + cg] = o4;
  }
}

// ---------- 9. devox + offset transform + fuse + transpose-store ----------
__global__ __launch_bounds__(256) void fuse_kernel(
    const float* __restrict__ x_t, const float* __restrict__ o_t,
    const float* __restrict__ trans_w, const float* __restrict__ trans_b,
    const float* __restrict__ grid, const float* __restrict__ se_scale,
    const float* __restrict__ nc, float* __restrict__ out)
{
  __shared__ float tw_s[64*65];
  __shared__ float d_s[64*65];
  __shared__ float r_s[64*65];
  const int tid = threadIdx.x;
  const int blk = blockIdx.x;
  const int b = blk >> 6;
  const int n0 = (blk & 63) * 64;
  for (int e = tid; e < 4096; e += 256) {
    int c = e >> 6, k = e & 63;
    tw_s[c*65 + k] = trans_w[e];
  }
  for (int e = tid; e < 4096; e += 256) {
    int nl = e >> 6, c = e & 63;
    size_t idx = ((size_t)(b*NP) + n0 + nl)*64 + c;
    d_s[nl*65 + c] = x_t[idx] - o_t[idx];
  }
  __syncthreads();
  const int cl = tid & 63, g = tid >> 6;
  const float ses = se_scale[b*64 + cl];
  const float tb = trans_b[cl];
  for (int t = 0; t < 16; t++) {
    int nl = g*16 + t;
    int n = n0 + nl;
    float off = 0.f;
    for (int k = 0; k < 64; k++) off += tw_s[cl*65 + k] * d_s[nl*65 + k];
    off = fmaxf(off + tb, 0.f);
    float ncx = nc[((size_t)(b*3)+0)*NP + n];
    float ncy = nc[((size_t)(b*3)+1)*NP + n];
    float ncz = nc[((size_t)(b*3)+2)*NP + n];
    float fx0 = floorf(ncx), fy0 = floorf(ncy), fz0 = floorf(ncz);
    int x0 = (int)fx0, y0 = (int)fy0, z0 = (int)fz0;
    float fx = ncx - fx0, fy = ncy - fy0, fz = ncz - fz0;
    float wx[2] = {1.f-fx, fx}, wy[2] = {1.f-fy, fy}, wz[2] = {1.f-fz, fz};
    float vf = 0.f;
    #pragma unroll
    for (int cor = 0; cor < 8; cor++) {
      int dx = cor >> 2, dy = (cor >> 1) & 1, dz = cor & 1;
      int xi = min(x0+dx, 31), yi = min(y0+dy, 31), zi = min(z0+dz, 31);
      float wgt = wx[dx]*wy[dy]*wz[dz];
      vf += wgt * grid[((size_t)(b*VX) + (xi*32+yi)*32 + zi)*64 + cl];
    }
    vf *= ses;
    float xval = x_t[((size_t)(b*NP) + n)*64 + cl];
    r_s[cl*65 + nl] = xval + off + vf;
  }
  __syncthreads();
  for (int e = tid; e < 4096; e += 256) {
    int c = e >> 6, nl = e & 63;
    out[((size_t)(b*64) + c)*NP + n0 + nl] = r_s[c*65 + nl];
  }
}

extern "C" void kernel_launch(void* const* d_in, const int* in_sizes, int n_in,
                              void* d_out, int out_size, void* d_ws, size_t ws_size,
                              hipStream_t stream)
{
  const float* features = (const float*)d_in[0];
  const float* coords   = (const float*)d_in[1];
  const float* conv_w   = (const float*)d_in[2];
  const float* conv_b   = (const float*)d_in[3];
  const float* ln1_g    = (const float*)d_in[4];
  const float* ln1_b    = (const float*)d_in[5];
  const float* qkv_w    = (const float*)d_in[6];
  const float* qkv_b    = (const float*)d_in[7];
  const float* proj_w   = (const float*)d_in[8];
  const float* proj_b   = (const float*)d_in[9];
  const float* ln2_g    = (const float*)d_in[10];
  const float* ln2_b    = (const float*)d_in[11];
  const float* mlp_w1   = (const float*)d_in[12];
  const float* mlp_b1   = (const float*)d_in[13];
  const float* mlp_w2   = (const float*)d_in[14];
  const float* mlp_b2   = (const float*)d_in[15];
  const float* se_w1    = (const float*)d_in[16];
  const float* se_w2    = (const float*)d_in[17];
  const float* pt_in_w  = (const float*)d_in[18];
  const float* pt_in_b  = (const float*)d_in[19];
  const float* q_w      = (const float*)d_in[20];
  const float* k_w      = (const float*)d_in[21];
  const float* v_w      = (const float*)d_in[22];
  const float* v_trans_w= (const float*)d_in[23];
  const float* v_trans_b= (const float*)d_in[24];

  char* ws = (char*)d_ws;
  float* stats    = (float*)(ws + 0);
  float* se_sum   = (float*)(ws + 256);
  float* se_scale = (float*)(ws + 1280);
  float* nc       = (float*)(ws + 4096);                 // 196608 B
  float* cnt      = (float*)(ws + 200704);               // 524288 B (zeroed)
  float* grid0    = (float*)(ws + 724992);               // 33.5 MB sums (zeroed)
  float* grid1    = (float*)(ws + 34279424);             // 33.5 MB conv/encoder out
  // point-branch buffers reuse grid0 region (dead after conv)
  float* x_t = (float*)(ws + 724992);
  float* q_t = (float*)(ws + 724992 + 4194304);
  float* k_t = (float*)(ws + 724992 + 5242880);
  float* v_t = (float*)(ws + 724992 + 6291456);
  float* o_t = (float*)(ws + 724992 + 10485760);
  // packed bf16 conv weights live in d_out (dead until fuse_kernel writes it)
  unsigned short* wpre = (unsigned short*)d_out;         // 221184 B << out bytes

  hipMemsetAsync(se_sum, 0, 1024, stream);
  hipMemsetAsync(cnt, 0, 524288 + 33554432, stream);     // cnt + grid0 contiguous

  wprep_kernel<<<54, 256, 0, stream>>>(conv_w, wpre);
  stats_kernel<<<BN, 256, 0, stream>>>(coords, stats);
  scatter_kernel<<<256, 256, 0, stream>>>(features, coords, stats, nc, grid0, cnt);
  conv_mfma_kernel<<<1024, 256, 0, stream>>>(grid0, cnt, wpre, conv_b, grid1);
  encoder_kernel<<<2048, 256, 0, stream>>>(grid1, ln1_g, ln1_b, qkv_w, qkv_b,
      proj_w, proj_b, ln2_g, ln2_b, mlp_w1, mlp_b1, mlp_w2, mlp_b2, se_sum);
  se_kernel<<<1, 256, 0, stream>>>(se_sum, se_w1, se_w2, se_scale);
  point_in_kernel<<<256, 256, 0, stream>>>(features, pt_in_w, pt_in_b, q_w, k_w, v_w,
      x_t, q_t, k_t, v_t);
  point_attn_kernel<<<256, 256, 0, stream>>>(q_t, k_t, v_t, o_t);
  fuse_kernel<<<256, 256, 0, stream>>>(x_t, o_t, v_trans_w, v_trans_b, grid1,
      se_scale, nc, (float*)d_out);
  hipMemcpyAsync((char*)d_out + (size_t)BN*64*NP*4, coords, (size_t)BN*3*NP*4,
                 hipMemcpyDeviceToDevice, stream);
}

// Round 3
// 475.800 us; speedup vs baseline: 6.3587x; 2.5918x over previous
//
#include <hip/hip_runtime.h>

#define BN 4
#define NP 4096
#define RV 32
#define VX (RV*RV*RV)

typedef __attribute__((ext_vector_type(8))) short bf16x8;
typedef __attribute__((ext_vector_type(4))) float f32x4;

// ---------- bf16 helpers (bit-level) ----------
__device__ __forceinline__ float bf2f(unsigned short u){
  union{unsigned u;float f;}v; v.u=((unsigned)u)<<16; return v.f; }
__device__ __forceinline__ unsigned short f2bf(float f){
  union{float f;unsigned u;}v; v.f=f; unsigned r=v.u + 0x7fffu + ((v.u>>16)&1u);
  return (unsigned short)(r>>16); }
__device__ __forceinline__ unsigned pack2bf(float a, float b){
  return (unsigned)f2bf(a) | ((unsigned)f2bf(b) << 16); }

union ABu { uint4 u; bf16x8 v; };

// ---------- 1. per-batch coord stats ----------
__global__ void stats_kernel(const float* __restrict__ coords, float* __restrict__ stats)
{
  __shared__ float red[256];
  __shared__ float mean[3];
  const int b = blockIdx.x;
  const int tid = threadIdx.x;
  float s0=0.f,s1=0.f,s2=0.f;
  for (int n = tid; n < NP; n += 256) {
    s0 += coords[((size_t)(b*3)+0)*NP + n];
    s1 += coords[((size_t)(b*3)+1)*NP + n];
    s2 += coords[((size_t)(b*3)+2)*NP + n];
  }
  float sv[3] = {s0,s1,s2};
  for (int ax = 0; ax < 3; ax++) {
    __syncthreads();
    red[tid] = sv[ax];
    __syncthreads();
    for (int st = 128; st > 0; st >>= 1) {
      if (tid < st) red[tid] += red[tid + st];
      __syncthreads();
    }
    if (tid == 0) mean[ax] = red[0] * (1.f / NP);
  }
  __syncthreads();
  float mx = 0.f;
  for (int n = tid; n < NP; n += 256) {
    float d0 = coords[((size_t)(b*3)+0)*NP + n] - mean[0];
    float d1 = coords[((size_t)(b*3)+1)*NP + n] - mean[1];
    float d2 = coords[((size_t)(b*3)+2)*NP + n] - mean[2];
    mx = fmaxf(mx, sqrtf(d0*d0 + d1*d1 + d2*d2));
  }
  __syncthreads();
  red[tid] = mx;
  __syncthreads();
  for (int st = 128; st > 0; st >>= 1) {
    if (tid < st) red[tid] = fmaxf(red[tid], red[tid + st]);
    __syncthreads();
  }
  if (tid == 0) {
    stats[b*4+0] = mean[0]; stats[b*4+1] = mean[1];
    stats[b*4+2] = mean[2]; stats[b*4+3] = red[0];
  }
}

// ---------- 2. voxelize scatter-sum ----------
__global__ void scatter_kernel(const float* __restrict__ features,
                               const float* __restrict__ coords,
                               const float* __restrict__ stats,
                               float* __restrict__ nc,
                               float* __restrict__ sums, float* __restrict__ cnt)
{
  int t = blockIdx.x*256 + threadIdx.x;   // B*N*4 threads
  int part = t & 3;
  int p = t >> 2;
  int b = p >> 12;
  int n = p & 4095;
  float m0 = stats[b*4+0], m1 = stats[b*4+1], m2 = stats[b*4+2], mx = stats[b*4+3];
  float inv = 1.f / (2.f * mx);
  float c0 = (coords[((size_t)(b*3)+0)*NP + n] - m0) * inv + 0.5f;
  float c1 = (coords[((size_t)(b*3)+1)*NP + n] - m1) * inv + 0.5f;
  float c2 = (coords[((size_t)(b*3)+2)*NP + n] - m2) * inv + 0.5f;
  float g0 = fminf(fmaxf(c0 * 32.f, 0.f), 31.f);
  float g1 = fminf(fmaxf(c1 * 32.f, 0.f), 31.f);
  float g2 = fminf(fmaxf(c2 * 32.f, 0.f), 31.f);
  int v0 = (int)rintf(g0), v1 = (int)rintf(g1), v2 = (int)rintf(g2);
  int idx = (v0*32 + v1)*32 + v2 + b*VX;
  if (part == 0) {
    nc[((size_t)(b*3)+0)*NP + n] = g0;
    nc[((size_t)(b*3)+1)*NP + n] = g1;
    nc[((size_t)(b*3)+2)*NP + n] = g2;
    atomicAdd(&cnt[idx], 1.f);
  }
  const float* fp = features + (size_t)(b*64)*NP + n;
  float* sp = sums + (size_t)idx*64;
  for (int i = part*16; i < part*16+16; i++)
    atomicAdd(&sp[i], fp[(size_t)i*NP]);
}

// ---------- 3a. conv weight prep ----------
__global__ void wprep_kernel(const float* __restrict__ wt, unsigned short* __restrict__ wpre)
{
  int t = blockIdx.x*256 + threadIdx.x;  // 27*64*8 = 13824
  if (t >= 27*64*8) return;
  int c16 = t & 7, o = (t >> 3) & 63, tap = t >> 9;
  size_t dst = ((size_t)(tap*64 + o)*8 + (c16 ^ (o & 7))) * 8;
  #pragma unroll
  for (int j = 0; j < 8; j++) {
    int i = c16*8 + j;
    wpre[dst + j] = f2bf(wt[(o*64 + i)*27 + tap]);
  }
}

// ---------- 3b. encoder weight prep: fp32 -> bf16 flat ----------
__global__ void eprep_kernel(const float* __restrict__ qkv_w, const float* __restrict__ proj_w,
                             const float* __restrict__ w1, const float* __restrict__ w2,
                             unsigned short* __restrict__ dst)
{
  int t = blockIdx.x*256 + threadIdx.x;   // 49152
  float v;
  if (t < 12288)      v = qkv_w[t];
  else if (t < 16384) v = proj_w[t-12288];
  else if (t < 32768) v = w1[t-16384];
  else                v = w2[t-32768];
  dst[t] = f2bf(v);
}

// ---------- 4. 3x3x3 conv via MFMA implicit GEMM ----------
__global__ __launch_bounds__(256) void conv_mfma_kernel(
    const float* __restrict__ sums, const float* __restrict__ cnt,
    const unsigned short* __restrict__ wpre,
    const float* __restrict__ bias, float* __restrict__ gout)
{
  __shared__ uint4 plane[6*34*8];
  __shared__ uint4 wsm[3*64*8];
  const int tid = threadIdx.x;
  const int blk = blockIdx.x;       // B*32*8
  const int yq = blk & 7, z = (blk >> 3) & 31, b = blk >> 8;
  const int y0 = yq * 4;
  const int w  = tid >> 6;
  const int lm = tid & 15;
  const int kg = (tid >> 4) & 3;

  f32x4 acc[2][4];
  #pragma unroll
  for (int mt = 0; mt < 2; mt++)
    #pragma unroll
    for (int nt = 0; nt < 4; nt++)
      #pragma unroll
      for (int r = 0; r < 4; r++) acc[mt][nt][r] = 0.f;

  float bv[4];
  #pragma unroll
  for (int nt = 0; nt < 4; nt++) bv[nt] = bias[nt*16 + lm];

  for (int kd = 0; kd < 3; kd++) {
    const int zz = z + kd - 1;
    if (zz < 0 || zz >= 32) continue;
    __syncthreads();
    for (int e = tid; e < 6*34*8; e += 256) {
      int c16 = e & 7;
      int sx  = (e >> 3) % 34;
      int yl  = e / (34*8);
      int yy = y0 - 1 + yl, x = sx - 1;
      uint4 val = make_uint4(0u,0u,0u,0u);
      if (yy >= 0 && yy < 32 && x >= 0 && x < 32) {
        size_t vox = (size_t)(b*VX) + (zz*32 + yy)*32 + x;
        float rc = 1.f / fmaxf(cnt[vox], 1.f);
        const float* src = sums + vox*64 + c16*8;
        float4 f0 = *(const float4*)(src);
        float4 f1 = *(const float4*)(src + 4);
        val.x = pack2bf(f0.x*rc, f0.y*rc);
        val.y = pack2bf(f0.z*rc, f0.w*rc);
        val.z = pack2bf(f1.x*rc, f1.y*rc);
        val.w = pack2bf(f1.z*rc, f1.w*rc);
      }
      plane[(yl*34 + sx)*8 + (c16 ^ (sx & 7))] = val;
    }
    for (int kh = 0; kh < 3; kh++) {
      __syncthreads();
      const uint4* wsrc = (const uint4*)wpre + (size_t)((kd*3 + kh)*3)*512;
      for (int e = tid; e < 1536; e += 256) wsm[e] = wsrc[e];
      __syncthreads();
      const int yi = w + kh;
      #pragma unroll
      for (int kw = 0; kw < 3; kw++) {
        const int sxa = lm + kw, sxb = sxa + 16;
        const int swz = sxa & 7;
        #pragma unroll
        for (int ch = 0; ch < 2; ch++) {
          const int cb = ch*4 + kg;
          ABu a0, a1, w0, w1, w2, w3;
          a0.u = plane[(yi*34 + sxa)*8 + (cb ^ swz)];
          a1.u = plane[(yi*34 + sxb)*8 + (cb ^ swz)];
          const int wsz = cb ^ (lm & 7);
          w0.u = wsm[(kw*64 +      lm)*8 + wsz];
          w1.u = wsm[(kw*64 + 16 + lm)*8 + wsz];
          w2.u = wsm[(kw*64 + 32 + lm)*8 + wsz];
          w3.u = wsm[(kw*64 + 48 + lm)*8 + wsz];
          acc[0][0] = __builtin_amdgcn_mfma_f32_16x16x32_bf16(a0.v, w0.v, acc[0][0], 0,0,0);
          acc[1][0] = __builtin_amdgcn_mfma_f32_16x16x32_bf16(a1.v, w0.v, acc[1][0], 0,0,0);
          acc[0][1] = __builtin_amdgcn_mfma_f32_16x16x32_bf16(a0.v, w1.v, acc[0][1], 0,0,0);
          acc[1][1] = __builtin_amdgcn_mfma_f32_16x16x32_bf16(a1.v, w1.v, acc[1][1], 0,0,0);
          acc[0][2] = __builtin_amdgcn_mfma_f32_16x16x32_bf16(a0.v, w2.v, acc[0][2], 0,0,0);
          acc[1][2] = __builtin_amdgcn_mfma_f32_16x16x32_bf16(a1.v, w2.v, acc[1][2], 0,0,0);
          acc[0][3] = __builtin_amdgcn_mfma_f32_16x16x32_bf16(a0.v, w3.v, acc[0][3], 0,0,0);
          acc[1][3] = __builtin_amdgcn_mfma_f32_16x16x32_bf16(a1.v, w3.v, acc[1][3], 0,0,0);
        }
      }
    }
  }
  const int y = y0 + w;
  #pragma unroll
  for (int mt = 0; mt < 2; mt++) {
    #pragma unroll
    for (int r = 0; r < 4; r++) {
      const int x = mt*16 + kg*4 + r;
      float* dst = gout + ((size_t)(b*VX) + (z*32 + y)*32 + x)*64 + lm;
      #pragma unroll
      for (int nt = 0; nt < 4; nt++)
        dst[nt*16] = fmaxf(acc[mt][nt][r] + bv[nt], 0.f);
    }
  }
}

// ---------- 5. windowed transformer encoder — full MFMA ----------
// transposed-compute scheme: for X@W^T compute W@X^T (A=W [out][in], B=X [tok][in]),
// D tile = [out][tok]: lane holds 4 consecutive out for one tok -> b64 packed store
// into [tok][out] layout, which is again a valid B operand.
__global__ __launch_bounds__(256) void encoder_kernel(
    float* __restrict__ grid,
    const float* __restrict__ ln1_g, const float* __restrict__ ln1_b,
    const float* __restrict__ qkv_b, const float* __restrict__ proj_b,
    const float* __restrict__ ln2_g, const float* __restrict__ ln2_b,
    const float* __restrict__ b1, const float* __restrict__ b2,
    const unsigned short* __restrict__ encw,
    float* __restrict__ se_sum)
{
  __shared__ float t_s[64*65];                 // residual fp32 [tok][65]
  __shared__ unsigned short aT[64*72];         // h/h2 bf16 [tok][72]; p_s overlay
  __shared__ unsigned short qk[4*64*72];       // q,k,v,o | hid overlay
  __shared__ float mean_s[64], rstd_s[64];
  __shared__ float sered[256];
  unsigned short* q_s = qk;
  unsigned short* k_s = qk + 4608;
  unsigned short* v_s = qk + 9216;             // [dim][tok]
  unsigned short* o_s = qk + 13824;            // [tok][dim]
  unsigned short* hid = qk;                    // [tok][264]
  unsigned short* p_s = aT;                    // [tok_i][72]

  const unsigned short* wqb = encw;            // [192][64]
  const unsigned short* wpb = encw + 12288;    // [64][64]
  const unsigned short* w1b = encw + 16384;    // [256][64]
  const unsigned short* w2b = encw + 32768;    // [64][256]

  const int tid = threadIdx.x;
  const int w = tid >> 6;
  const int lane = tid & 63;
  const int cl = lane & 15;
  const int quad = lane >> 4;
  const int win = blockIdx.x;
  const int b = win >> 9, wn = win & 511;
  const int zb = wn >> 6, yb = (wn >> 3) & 7, xb = wn & 7;
  const size_t gb = (size_t)b * VX * 64;

  // load window
  for (int e = tid; e < 4096; e += 256) {
    int tok = e >> 6, c = e & 63;
    int zl = tok >> 4, yl = (tok >> 2) & 3, xl = tok & 3;
    int vox = ((zb*4+zl)*32 + (yb*4+yl))*32 + (xb*4+xl);
    t_s[tok*65 + c] = grid[gb + (size_t)vox*64 + c];
  }
  __syncthreads();
  // LN1 stats
  {
    int i = tid >> 2, part = tid & 3;
    float sum = 0.f, sq = 0.f;
    for (int c = part; c < 64; c += 4) { float x = t_s[i*65+c]; sum += x; sq += x*x; }
    sum += __shfl_xor(sum, 1); sq += __shfl_xor(sq, 1);
    sum += __shfl_xor(sum, 2); sq += __shfl_xor(sq, 2);
    if (part == 0) {
      float m = sum * (1.f/64.f);
      float var = sq * (1.f/64.f) - m*m;
      mean_s[i] = m; rstd_s[i] = rsqrtf(var + 1e-5f);
    }
  }
  __syncthreads();
  for (int e = tid; e < 4096; e += 256) {
    int tok = e >> 6, c = e & 63;
    float h = (t_s[tok*65+c] - mean_s[tok]) * rstd_s[tok] * ln1_g[c] + ln1_b[c];
    aT[tok*72 + c] = f2bf(h);
  }
  __syncthreads();
  // qkv: qkv^T = W(192x64) @ h^T. wave w: dim-tiles 3w..3w+2
  {
    #pragma unroll
    for (int ci = 0; ci < 3; ci++) {
      const int d0 = 48*w + ci*16;
      ABu a0, a1;
      a0.u = *(const uint4*)(wqb + (d0 + cl)*64 + quad*8);
      a1.u = *(const uint4*)(wqb + (d0 + cl)*64 + 32 + quad*8);
      float4 bias4 = *(const float4*)(qkv_b + d0 + quad*4);
      #pragma unroll
      for (int tt = 0; tt < 4; tt++) {
        ABu h0, h1;
        h0.u = *(const uint4*)(aT + (tt*16 + cl)*72 + quad*8);
        h1.u = *(const uint4*)(aT + (tt*16 + cl)*72 + 32 + quad*8);
        f32x4 d = {0.f,0.f,0.f,0.f};
        d = __builtin_amdgcn_mfma_f32_16x16x32_bf16(a0.v, h0.v, d, 0,0,0);
        d = __builtin_amdgcn_mfma_f32_16x16x32_bf16(a1.v, h1.v, d, 0,0,0);
        if (d0 < 64) {          // q (fold 1/sqrt(16))
          unsigned lo = pack2bf((d[0]+bias4.x)*0.25f, (d[1]+bias4.y)*0.25f);
          unsigned hi = pack2bf((d[2]+bias4.z)*0.25f, (d[3]+bias4.w)*0.25f);
          *(uint2*)(q_s + (tt*16+cl)*72 + d0 + quad*4) = make_uint2(lo, hi);
        } else if (d0 < 128) {  // k
          unsigned lo = pack2bf(d[0]+bias4.x, d[1]+bias4.y);
          unsigned hi = pack2bf(d[2]+bias4.z, d[3]+bias4.w);
          *(uint2*)(k_s + (tt*16+cl)*72 + (d0-64) + quad*4) = make_uint2(lo, hi);
        } else {                // v -> [dim][tok]
          const float* bp = (const float*)&bias4;
          #pragma unroll
          for (int r = 0; r < 4; r++)
            v_s[((d0-128) + quad*4 + r)*72 + tt*16 + cl] = f2bf(d[r] + bp[r]);
        }
      }
    }
  }
  __syncthreads();
  // attention: 4 heads, all wave-local (wave w owns tok_i rows w*16..w*16+15)
  {
    const uint4 z4 = make_uint4(0u,0u,0u,0u);
    #pragma unroll
    for (int h = 0; h < 4; h++) {
      const int hb = h*16;
      ABu bq;
      if (quad < 2) bq.u = *(const uint4*)(q_s + (w*16 + cl)*72 + hb + quad*8);
      else bq.u = z4;
      float sc[4][4];
      #pragma unroll
      for (int tj = 0; tj < 4; tj++) {
        ABu ak;
        if (quad < 2) ak.u = *(const uint4*)(k_s + (tj*16 + cl)*72 + hb + quad*8);
        else ak.u = z4;
        f32x4 d = {0.f,0.f,0.f,0.f};
        d = __builtin_amdgcn_mfma_f32_16x16x32_bf16(ak.v, bq.v, d, 0,0,0);
        #pragma unroll
        for (int r = 0; r < 4; r++) sc[tj][r] = d[r];
      }
      float mx = -1e30f;
      #pragma unroll
      for (int tj = 0; tj < 4; tj++)
        #pragma unroll
        for (int r = 0; r < 4; r++) mx = fmaxf(mx, sc[tj][r]);
      mx = fmaxf(mx, __shfl_xor(mx, 16));
      mx = fmaxf(mx, __shfl_xor(mx, 32));
      float psum = 0.f;
      #pragma unroll
      for (int tj = 0; tj < 4; tj++) {
        float p0 = __expf(sc[tj][0]-mx), p1 = __expf(sc[tj][1]-mx);
        float p2 = __expf(sc[tj][2]-mx), p3 = __expf(sc[tj][3]-mx);
        psum += p0+p1+p2+p3;
        *(uint2*)(p_s + (w*16+cl)*72 + tj*16 + quad*4) =
            make_uint2(pack2bf(p0,p1), pack2bf(p2,p3));
      }
      psum += __shfl_xor(psum, 16);
      psum += __shfl_xor(psum, 32);
      float inv = 1.f / psum;
      f32x4 oacc = {0.f,0.f,0.f,0.f};
      #pragma unroll
      for (int kk = 0; kk < 2; kk++) {
        ABu av, bp;
        av.u = *(const uint4*)(v_s + (hb + cl)*72 + kk*32 + quad*8);
        bp.u = *(const uint4*)(p_s + (w*16 + cl)*72 + kk*32 + quad*8);
        oacc = __builtin_amdgcn_mfma_f32_16x16x32_bf16(av.v, bp.v, oacc, 0,0,0);
      }
      *(uint2*)(o_s + (w*16+cl)*72 + hb + quad*4) =
          make_uint2(pack2bf(oacc[0]*inv, oacc[1]*inv), pack2bf(oacc[2]*inv, oacc[3]*inv));
    }
  }
  __syncthreads();
  // proj: out^T = proj_w @ O^T; wave w: out-cols c0=w*16; += into t_s
  {
    const int c0 = w*16;
    ABu a0, a1;
    a0.u = *(const uint4*)(wpb + (c0 + cl)*64 + quad*8);
    a1.u = *(const uint4*)(wpb + (c0 + cl)*64 + 32 + quad*8);
    float4 pb4 = *(const float4*)(proj_b + c0 + quad*4);
    const float* pbp = (const float*)&pb4;
    #pragma unroll
    for (int tt = 0; tt < 4; tt++) {
      ABu o0, o1;
      o0.u = *(const uint4*)(o_s + (tt*16 + cl)*72 + quad*8);
      o1.u = *(const uint4*)(o_s + (tt*16 + cl)*72 + 32 + quad*8);
      f32x4 d = {0.f,0.f,0.f,0.f};
      d = __builtin_amdgcn_mfma_f32_16x16x32_bf16(a0.v, o0.v, d, 0,0,0);
      d = __builtin_amdgcn_mfma_f32_16x16x32_bf16(a1.v, o1.v, d, 0,0,0);
      #pragma unroll
      for (int r = 0; r < 4; r++)
        t_s[(tt*16+cl)*65 + c0 + quad*4 + r] += d[r] + pbp[r];
    }
  }
  __syncthreads();
  // LN2
  {
    int i = tid >> 2, part = tid & 3;
    float sum = 0.f, sq = 0.f;
    for (int c = part; c < 64; c += 4) { float x = t_s[i*65+c]; sum += x; sq += x*x; }
    sum += __shfl_xor(sum, 1); sq += __shfl_xor(sq, 1);
    sum += __shfl_xor(sum, 2); sq += __shfl_xor(sq, 2);
    if (part == 0) {
      float m = sum * (1.f/64.f);
      float var = sq * (1.f/64.f) - m*m;
      mean_s[i] = m; rstd_s[i] = rsqrtf(var + 1e-5f);
    }
  }
  __syncthreads();
  for (int e = tid; e < 4096; e += 256) {
    int tok = e >> 6, c = e & 63;
    float h = (t_s[tok*65+c] - mean_s[tok]) * rstd_s[tok] * ln2_g[c] + ln2_b[c];
    aT[tok*72 + c] = f2bf(h);
  }
  __syncthreads();
  // MLP1: hid^T = w1(256x64) @ h2^T; wave w: hid dims 64w..64w+63; gelu; -> hid[tok][264]
  {
    const int m0w = w*64;
    ABu hb0[4], hb1[4];
    #pragma unroll
    for (int tt = 0; tt < 4; tt++) {
      hb0[tt].u = *(const uint4*)(aT + (tt*16 + cl)*72 + quad*8);
      hb1[tt].u = *(const uint4*)(aT + (tt*16 + cl)*72 + 32 + quad*8);
    }
    f32x4 acc1[4][4];
    #pragma unroll
    for (int mt = 0; mt < 4; mt++) {
      ABu a0, a1;
      a0.u = *(const uint4*)(w1b + (m0w + mt*16 + cl)*64 + quad*8);
      a1.u = *(const uint4*)(w1b + (m0w + mt*16 + cl)*64 + 32 + quad*8);
      #pragma unroll
      for (int tt = 0; tt < 4; tt++) {
        f32x4 d = {0.f,0.f,0.f,0.f};
        d = __builtin_amdgcn_mfma_f32_16x16x32_bf16(a0.v, hb0[tt].v, d, 0,0,0);
        d = __builtin_amdgcn_mfma_f32_16x16x32_bf16(a1.v, hb1[tt].v, d, 0,0,0);
        acc1[mt][tt] = d;
      }
    }
    __syncthreads();   // all o_s/q/k/v reads done block-wide before hid overlay write
    #pragma unroll
    for (int mt = 0; mt < 4; mt++) {
      float4 b14 = *(const float4*)(b1 + m0w + mt*16 + quad*4);
      const float* bp = (const float*)&b14;
      #pragma unroll
      for (int tt = 0; tt < 4; tt++) {
        float g[4];
        #pragma unroll
        for (int r = 0; r < 4; r++) {
          float x = acc1[mt][tt][r] + bp[r];
          float u = 1.5957691f * (x + 0.044715f*x*x*x);
          g[r] = x / (1.f + __expf(-u));
        }
        *(uint2*)(hid + (tt*16+cl)*264 + m0w + mt*16 + quad*4) =
            make_uint2(pack2bf(g[0],g[1]), pack2bf(g[2],g[3]));
      }
    }
  }
  __syncthreads();
  // MLP2: out^T = w2(64x256) @ hid^T; wave w: out-cols c0=w*16; += into t_s
  {
    const int c0 = w*16;
    f32x4 acc2[4];
    #pragma unroll
    for (int tt = 0; tt < 4; tt++)
      #pragma unroll
      for (int r = 0; r < 4; r++) acc2[tt][r] = 0.f;
    #pragma unroll
    for (int kk = 0; kk < 8; kk++) {
      ABu a;
      a.u = *(const uint4*)(w2b + (c0 + cl)*256 + kk*32 + quad*8);
      #pragma unroll
      for (int tt = 0; tt < 4; tt++) {
        ABu bh;
        bh.u = *(const uint4*)(hid + (tt*16 + cl)*264 + kk*32 + quad*8);
        acc2[tt] = __builtin_amdgcn_mfma_f32_16x16x32_bf16(a.v, bh.v, acc2[tt], 0,0,0);
      }
    }
    float4 b24 = *(const float4*)(b2 + c0 + quad*4);
    const float* bp = (const float*)&b24;
    #pragma unroll
    for (int tt = 0; tt < 4; tt++)
      #pragma unroll
      for (int r = 0; r < 4; r++)
        t_s[(tt*16+cl)*65 + c0 + quad*4 + r] += acc2[tt][r] + bp[r];
  }
  __syncthreads();
  // writeback + SE partials
  for (int e = tid; e < 4096; e += 256) {
    int tok = e >> 6, c = e & 63;
    int zl = tok >> 4, yl = (tok >> 2) & 3, xl = tok & 3;
    int vox = ((zb*4+zl)*32 + (yb*4+yl))*32 + (xb*4+xl);
    grid[gb + (size_t)vox*64 + c] = t_s[tok*65 + c];
  }
  {
    int c = tid & 63, quarter = tid >> 6;
    float ps = 0.f;
    #pragma unroll
    for (int t = 0; t < 16; t++) ps += t_s[(quarter*16+t)*65 + c];
    sered[quarter*64 + c] = ps;
  }
  __syncthreads();
  if (tid < 64)
    atomicAdd(&se_sum[b*64 + tid],
              sered[tid] + sered[64+tid] + sered[128+tid] + sered[192+tid]);
}

// ---------- 6. SE squeeze-excite scale ----------
__global__ void se_kernel(const float* __restrict__ se_sum, const float* __restrict__ w1,
                          const float* __restrict__ w2, float* __restrict__ scale)
{
  __shared__ float mean_s[256];
  __shared__ float z1[32];
  int tid = threadIdx.x;
  mean_s[tid] = se_sum[tid] * (1.f / VX);
  __syncthreads();
  if (tid < 32) {
    int bb = tid >> 3, j = tid & 7;
    float a = 0.f;
    for (int c = 0; c < 64; c++) a += mean_s[bb*64 + c] * w1[j*64 + c];
    z1[tid] = fmaxf(a, 0.f);
  }
  __syncthreads();
  int b = tid >> 6, c = tid & 63;
  float a = 0.f;
  for (int j = 0; j < 8; j++) a += z1[b*8 + j] * w2[c*8 + j];
  scale[tid] = 1.f / (1.f + __expf(-a));
}

// ---------- 7. point branch input: x, q/k bf16, v transposed bf16 ----------
__global__ __launch_bounds__(256) void point_in_kernel(
    const float* __restrict__ features,
    const float* __restrict__ pt_in_w, const float* __restrict__ pt_in_b,
    const float* __restrict__ q_w, const float* __restrict__ k_w,
    const float* __restrict__ v_w,
    float* __restrict__ x_t, unsigned short* __restrict__ q_bf,
    unsigned short* __restrict__ k_bf, unsigned short* __restrict__ v_tt)
{
  __shared__ float f_s[64*65];
  __shared__ float x_s[64*65];
  const int tid = threadIdx.x;
  const int blk = blockIdx.x;
  const int b = blk >> 6;
  const int n0 = (blk & 63) * 64;
  for (int e = tid; e < 4096; e += 256) {
    int i = e >> 6, nl = e & 63;
    f_s[nl*65 + i] = features[((size_t)(b*64 + i))*NP + n0 + nl];
  }
  __syncthreads();
  const int c = tid & 63, g = tid >> 6;
  const int t0 = g * 16;
  {
    float acc[16];
    #pragma unroll
    for (int t = 0; t < 16; t++) acc[t] = 0.f;
    for (int i = 0; i < 64; i++) {
      float wv = pt_in_w[c*64 + i];
      #pragma unroll
      for (int t = 0; t < 16; t++) acc[t] += f_s[(t0+t)*65 + i] * wv;
    }
    float bb = pt_in_b[c];
    #pragma unroll
    for (int t = 0; t < 16; t++) {
      float x = fmaxf(acc[t] + bb, 0.f);
      x_s[(t0+t)*65 + c] = x;
      x_t[((size_t)(b*NP) + n0 + t0 + t)*64 + c] = x;
    }
  }
  __syncthreads();
  {
    float acc[16];
    #pragma unroll
    for (int t = 0; t < 16; t++) acc[t] = 0.f;
    for (int k = 0; k < 64; k++) {
      float wv = v_w[c*64 + k];
      #pragma unroll
      for (int t = 0; t < 16; t++) acc[t] += x_s[(t0+t)*65 + k] * wv;
    }
    #pragma unroll
    for (int t = 0; t < 16; t++)
      v_tt[((size_t)(b*64) + c)*NP + n0 + t0 + t] = f2bf(acc[t]);
  }
  if (tid < 128) {
    int d = tid & 15, which = (tid >> 4) & 1, g2 = tid >> 5;
    int t0b = g2 * 16;
    const float* wp = which ? k_w : q_w;
    float scl = which ? 1.f : 0.25f;
    float acc[16];
    #pragma unroll
    for (int t = 0; t < 16; t++) acc[t] = 0.f;
    for (int cc = 0; cc < 64; cc++) {
      float wv = wp[d*64 + cc];
      #pragma unroll
      for (int t = 0; t < 16; t++) acc[t] += x_s[(t0b+t)*65 + cc] * wv;
    }
    unsigned short* dst = which ? k_bf : q_bf;
    #pragma unroll
    for (int t = 0; t < 16; t++)
      dst[((size_t)(b*NP) + n0 + t0b + t)*16 + d] = f2bf(acc[t] * scl);
  }
}

// ---------- 8. point attention — MFMA flash, online softmax in registers ----------
__global__ __launch_bounds__(256) void point_attn_kernel(
    const unsigned short* __restrict__ q_bf, const unsigned short* __restrict__ k_bf,
    const unsigned short* __restrict__ v_tt, float* __restrict__ o_t)
{
  __shared__ unsigned short q_s[64*24];
  __shared__ unsigned short k_sh[2][64*24];
  __shared__ unsigned short v_sh[2][64*72];
  __shared__ unsigned short p_s[64*72];
  const int tid = threadIdx.x;
  const int b = blockIdx.x >> 6;
  const int n0 = (blockIdx.x & 63) * 64;
  const int w = tid >> 6;
  const int lane = tid & 63;
  const int cl = lane & 15;
  const int quad = lane >> 4;
  const uint4 z4 = make_uint4(0u,0u,0u,0u);

  const unsigned* qbu = (const unsigned*)q_bf;
  const unsigned* kbu = (const unsigned*)k_bf;
  const unsigned* vtu = (const unsigned*)v_tt;
  unsigned* q_su = (unsigned*)q_s;

  // stage Q and tile 0
  {
    unsigned* kd = (unsigned*)k_sh[0];
    unsigned* vd = (unsigned*)v_sh[0];
    for (int e = tid; e < 512; e += 256) {
      int tok = e >> 3, du = e & 7;
      q_su[tok*12 + du] = qbu[((size_t)(b*NP) + n0 + tok)*8 + du];
      kd[tok*12 + du]   = kbu[((size_t)(b*NP) + tok)*8 + du];
    }
    for (int e = tid; e < 2048; e += 256) {
      int cc = e >> 5, tu = e & 31;
      vd[cc*36 + tu] = vtu[((size_t)(b*64) + cc)*2048 + tu];
    }
  }
  float m_run = -1e30f, l_run = 0.f;
  f32x4 acc[4];
  #pragma unroll
  for (int ct = 0; ct < 4; ct++)
    #pragma unroll
    for (int r = 0; r < 4; r++) acc[ct][r] = 0.f;
  __syncthreads();

  ABu bq;
  if (quad < 2) bq.u = *(const uint4*)(q_s + (w*16 + cl)*24 + quad*8);
  else bq.u = z4;

  for (int t = 0; t < 64; t++) {
    const int cur = t & 1;
    unsigned pk[2], pv[8];
    if (t+1 < 64) {
      const int m1 = (t+1)*64;
      #pragma unroll
      for (int i = 0; i < 2; i++) {
        int e = tid + i*256;
        pk[i] = kbu[((size_t)(b*NP) + m1 + (e>>3))*8 + (e&7)];
      }
      #pragma unroll
      for (int i = 0; i < 8; i++) {
        int e = tid + i*256;
        pv[i] = vtu[((size_t)(b*64) + (e>>5))*2048 + (m1>>1) + (e&31)];
      }
    }
    const unsigned short* ks = k_sh[cur];
    const unsigned short* vs = v_sh[cur];
    // S^T = K @ Q^T
    float sc[4][4];
    #pragma unroll
    for (int tj = 0; tj < 4; tj++) {
      ABu ak;
      if (quad < 2) ak.u = *(const uint4*)(ks + (tj*16 + cl)*24 + quad*8);
      else ak.u = z4;
      f32x4 d = {0.f,0.f,0.f,0.f};
      d = __builtin_amdgcn_mfma_f32_16x16x32_bf16(ak.v, bq.v, d, 0,0,0);
      #pragma unroll
      for (int r = 0; r < 4; r++) sc[tj][r] = d[r];
    }
    float tmax = -1e30f;
    #pragma unroll
    for (int tj = 0; tj < 4; tj++)
      #pragma unroll
      for (int r = 0; r < 4; r++) tmax = fmaxf(tmax, sc[tj][r]);
    tmax = fmaxf(tmax, __shfl_xor(tmax, 16));
    tmax = fmaxf(tmax, __shfl_xor(tmax, 32));
    float mnew = fmaxf(m_run, tmax);
    float alpha = __expf(m_run - mnew);
    float psum = 0.f;
    #pragma unroll
    for (int tj = 0; tj < 4; tj++) {
      float p0 = __expf(sc[tj][0]-mnew), p1 = __expf(sc[tj][1]-mnew);
      float p2 = __expf(sc[tj][2]-mnew), p3 = __expf(sc[tj][3]-mnew);
      psum += p0+p1+p2+p3;
      *(uint2*)(p_s + (w*16+cl)*72 + tj*16 + quad*4) =
          make_uint2(pack2bf(p0,p1), pack2bf(p2,p3));
    }
    psum += __shfl_xor(psum, 16);
    psum += __shfl_xor(psum, 32);
    l_run = l_run*alpha + psum;
    m_run = mnew;
    #pragma unroll
    for (int ct = 0; ct < 4; ct++)
      #pragma unroll
      for (int r = 0; r < 4; r++) acc[ct][r] *= alpha;
    // O^T += V^T @ P^T
    #pragma unroll
    for (int kk = 0; kk < 2; kk++) {
      ABu bp;
      bp.u = *(const uint4*)(p_s + (w*16 + cl)*72 + kk*32 + quad*8);
      #pragma unroll
      for (int ct = 0; ct < 4; ct++) {
        ABu av;
        av.u = *(const uint4*)(vs + (ct*16 + cl)*72 + kk*32 + quad*8);
        acc[ct] = __builtin_amdgcn_mfma_f32_16x16x32_bf16(av.v, bp.v, acc[ct], 0,0,0);
      }
    }
    __syncthreads();
    if (t+1 < 64) {
      unsigned* kd = (unsigned*)k_sh[1-cur];
      unsigned* vd = (unsigned*)v_sh[1-cur];
      #pragma unroll
      for (int i = 0; i < 2; i++) {
        int e = tid + i*256;
        kd[(e>>3)*12 + (e&7)] = pk[i];
      }
      #pragma unroll
      for (int i = 0; i < 8; i++) {
        int e = tid + i*256;
        vd[(e>>5)*36 + (e&31)] = pv[i];
      }
    }
    __syncthreads();
  }
  const float inv = 1.f / l_run;
  const int tok = n0 + w*16 + cl;
  #pragma unroll
  for (int ct = 0; ct < 4; ct++) {
    float4 o4;
    o4.x = acc[ct][0]*inv; o4.y = acc[ct][1]*inv;
    o4.z = acc[ct][2]*inv; o4.w = acc[ct][3]*inv;
    *(float4*)&o_t[((size_t)(b*NP) + tok)*64 + ct*16 + quad*4] = o4;
  }
}

// ---------- 9. devox + offset transform + fuse + transpose-store ----------
__global__ __launch_bounds__(256) void fuse_kernel(
    const float* __restrict__ x_t, const float* __restrict__ o_t,
    const float* __restrict__ trans_w, const float* __restrict__ trans_b,
    const float* __restrict__ grid, const float* __restrict__ se_scale,
    const float* __restrict__ nc, float* __restrict__ out)
{
  __shared__ float tw_s[64*65];
  __shared__ float d_s[64*65];
  __shared__ float r_s[64*65];
  const int tid = threadIdx.x;
  const int blk = blockIdx.x;
  const int b = blk >> 6;
  const int n0 = (blk & 63) * 64;
  for (int e = tid; e < 4096; e += 256) {
    int c = e >> 6, k = e & 63;
    tw_s[c*65 + k] = trans_w[e];
  }
  for (int e = tid; e < 4096; e += 256) {
    int nl = e >> 6, c = e & 63;
    size_t idx = ((size_t)(b*NP) + n0 + nl)*64 + c;
    d_s[nl*65 + c] = x_t[idx] - o_t[idx];
  }
  __syncthreads();
  const int cl = tid & 63, g = tid >> 6;
  const float ses = se_scale[b*64 + cl];
  const float tb = trans_b[cl];
  for (int t = 0; t < 16; t++) {
    int nl = g*16 + t;
    int n = n0 + nl;
    float off = 0.f;
    for (int k = 0; k < 64; k++) off += tw_s[cl*65 + k] * d_s[nl*65 + k];
    off = fmaxf(off + tb, 0.f);
    float ncx = nc[((size_t)(b*3)+0)*NP + n];
    float ncy = nc[((size_t)(b*3)+1)*NP + n];
    float ncz = nc[((size_t)(b*3)+2)*NP + n];
    float fx0 = floorf(ncx), fy0 = floorf(ncy), fz0 = floorf(ncz);
    int x0 = (int)fx0, y0 = (int)fy0, z0 = (int)fz0;
    float fx = ncx - fx0, fy = ncy - fy0, fz = ncz - fz0;
    float wx[2] = {1.f-fx, fx}, wy[2] = {1.f-fy, fy}, wz[2] = {1.f-fz, fz};
    float vf = 0.f;
    #pragma unroll
    for (int cor = 0; cor < 8; cor++) {
      int dx = cor >> 2, dy = (cor >> 1) & 1, dz = cor & 1;
      int xi = min(x0+dx, 31), yi = min(y0+dy, 31), zi = min(z0+dz, 31);
      float wgt = wx[dx]*wy[dy]*wz[dz];
      vf += wgt * grid[((size_t)(b*VX) + (xi*32+yi)*32 + zi)*64 + cl];
    }
    vf *= ses;
    float xval = x_t[((size_t)(b*NP) + n)*64 + cl];
    r_s[cl*65 + nl] = xval + off + vf;
  }
  __syncthreads();
  for (int e = tid; e < 4096; e += 256) {
    int c = e >> 6, nl = e & 63;
    out[((size_t)(b*64) + c)*NP + n0 + nl] = r_s[c*65 + nl];
  }
}

extern "C" void kernel_launch(void* const* d_in, const int* in_sizes, int n_in,
                              void* d_out, int out_size, void* d_ws, size_t ws_size,
                              hipStream_t stream)
{
  const float* features = (const float*)d_in[0];
  const float* coords   = (const float*)d_in[1];
  const float* conv_w   = (const float*)d_in[2];
  const float* conv_b   = (const float*)d_in[3];
  const float* ln1_g    = (const float*)d_in[4];
  const float* ln1_b    = (const float*)d_in[5];
  const float* qkv_w    = (const float*)d_in[6];
  const float* qkv_b    = (const float*)d_in[7];
  const float* proj_w   = (const float*)d_in[8];
  const float* proj_b   = (const float*)d_in[9];
  const float* ln2_g    = (const float*)d_in[10];
  const float* ln2_b    = (const float*)d_in[11];
  const float* mlp_w1   = (const float*)d_in[12];
  const float* mlp_b1   = (const float*)d_in[13];
  const float* mlp_w2   = (const float*)d_in[14];
  const float* mlp_b2   = (const float*)d_in[15];
  const float* se_w1    = (const float*)d_in[16];
  const float* se_w2    = (const float*)d_in[17];
  const float* pt_in_w  = (const float*)d_in[18];
  const float* pt_in_b  = (const float*)d_in[19];
  const float* q_w      = (const float*)d_in[20];
  const float* k_w      = (const float*)d_in[21];
  const float* v_w      = (const float*)d_in[22];
  const float* v_trans_w= (const float*)d_in[23];
  const float* v_trans_b= (const float*)d_in[24];

  char* ws = (char*)d_ws;
  float* stats    = (float*)(ws + 0);
  float* se_sum   = (float*)(ws + 256);
  float* se_scale = (float*)(ws + 1280);
  float* nc       = (float*)(ws + 4096);
  float* cnt      = (float*)(ws + 200704);
  float* grid0    = (float*)(ws + 724992);               // sums (zeroed)
  float* grid1    = (float*)(ws + 34279424);
  // point-branch buffers reuse grid0 region (dead after conv)
  float* x_t = (float*)(ws + 724992);
  unsigned short* q_bf = (unsigned short*)(ws + 724992 + 4194304);
  unsigned short* k_bf = (unsigned short*)(ws + 724992 + 5242880);
  unsigned short* v_tt = (unsigned short*)(ws + 724992 + 6291456);
  float* o_t = (float*)(ws + 724992 + 10485760);
  // packed bf16 weights live in d_out (dead until fuse_kernel writes it)
  unsigned short* wpre = (unsigned short*)d_out;             // 221184 B
  unsigned short* encw = (unsigned short*)((char*)d_out + 221184);  // 98304 B

  hipMemsetAsync(se_sum, 0, 1024, stream);
  hipMemsetAsync(cnt, 0, 524288 + 33554432, stream);

  wprep_kernel<<<54, 256, 0, stream>>>(conv_w, wpre);
  eprep_kernel<<<192, 256, 0, stream>>>(qkv_w, proj_w, mlp_w1, mlp_w2, encw);
  stats_kernel<<<BN, 256, 0, stream>>>(coords, stats);
  scatter_kernel<<<256, 256, 0, stream>>>(features, coords, stats, nc, grid0, cnt);
  conv_mfma_kernel<<<1024, 256, 0, stream>>>(grid0, cnt, wpre, conv_b, grid1);
  encoder_kernel<<<2048, 256, 0, stream>>>(grid1, ln1_g, ln1_b, qkv_b, proj_b,
      ln2_g, ln2_b, mlp_b1, mlp_b2, encw, se_sum);
  se_kernel<<<1, 256, 0, stream>>>(se_sum, se_w1, se_w2, se_scale);
  point_in_kernel<<<256, 256, 0, stream>>>(features, pt_in_w, pt_in_b, q_w, k_w, v_w,
      x_t, q_bf, k_bf, v_tt);
  point_attn_kernel<<<256, 256, 0, stream>>>(q_bf, k_bf, v_tt, o_t);
  fuse_kernel<<<256, 256, 0, stream>>>(x_t, o_t, v_trans_w, v_trans_b, grid1,
      se_scale, nc, (float*)d_out);
  hipMemcpyAsync((char*)d_out + (size_t)BN*64*NP*4, coords, (size_t)BN*3*NP*4,
                 hipMemcpyDeviceToDevice, stream);
}

// Round 4
// 428.685 us; speedup vs baseline: 7.0576x; 1.1099x over previous
//
#include <hip/hip_runtime.h>

#define BN 4
#define NP 4096
#define RV 32
#define VX (RV*RV*RV)

typedef __attribute__((ext_vector_type(8))) short bf16x8;
typedef __attribute__((ext_vector_type(4))) float f32x4;

// ---------- bf16 helpers (bit-level) ----------
__device__ __forceinline__ float bf2f(unsigned short u){
  union{unsigned u;float f;}v; v.u=((unsigned)u)<<16; return v.f; }
__device__ __forceinline__ unsigned short f2bf(float f){
  union{float f;unsigned u;}v; v.f=f; unsigned r=v.u + 0x7fffu + ((v.u>>16)&1u);
  return (unsigned short)(r>>16); }
__device__ __forceinline__ float2 bfp2f2(unsigned p){
  union{unsigned u;float f;}a,b; a.u=p<<16; b.u=p&0xffff0000u;
  float2 r; r.x=a.f; r.y=b.f; return r; }
__device__ __forceinline__ unsigned pack2bf(float a, float b){
  return (unsigned)f2bf(a) | ((unsigned)f2bf(b) << 16); }

union ABu { uint4 u; bf16x8 v; };

// ---------- 1. per-batch coord stats ----------
__global__ void stats_kernel(const float* __restrict__ coords, float* __restrict__ stats)
{
  __shared__ float red[256];
  __shared__ float mean[3];
  const int b = blockIdx.x;
  const int tid = threadIdx.x;
  float s0=0.f,s1=0.f,s2=0.f;
  for (int n = tid; n < NP; n += 256) {
    s0 += coords[((size_t)(b*3)+0)*NP + n];
    s1 += coords[((size_t)(b*3)+1)*NP + n];
    s2 += coords[((size_t)(b*3)+2)*NP + n];
  }
  float sv[3] = {s0,s1,s2};
  for (int ax = 0; ax < 3; ax++) {
    __syncthreads();
    red[tid] = sv[ax];
    __syncthreads();
    for (int st = 128; st > 0; st >>= 1) {
      if (tid < st) red[tid] += red[tid + st];
      __syncthreads();
    }
    if (tid == 0) mean[ax] = red[0] * (1.f / NP);
  }
  __syncthreads();
  float mx = 0.f;
  for (int n = tid; n < NP; n += 256) {
    float d0 = coords[((size_t)(b*3)+0)*NP + n] - mean[0];
    float d1 = coords[((size_t)(b*3)+1)*NP + n] - mean[1];
    float d2 = coords[((size_t)(b*3)+2)*NP + n] - mean[2];
    mx = fmaxf(mx, sqrtf(d0*d0 + d1*d1 + d2*d2));
  }
  __syncthreads();
  red[tid] = mx;
  __syncthreads();
  for (int st = 128; st > 0; st >>= 1) {
    if (tid < st) red[tid] = fmaxf(red[tid], red[tid + st]);
    __syncthreads();
  }
  if (tid == 0) {
    stats[b*4+0] = mean[0]; stats[b*4+1] = mean[1];
    stats[b*4+2] = mean[2]; stats[b*4+3] = red[0];
  }
}

// ---------- 2. voxelize scatter-sum ----------
__global__ void scatter_kernel(const float* __restrict__ features,
                               const float* __restrict__ coords,
                               const float* __restrict__ stats,
                               float* __restrict__ nc,
                               float* __restrict__ sums, float* __restrict__ cnt)
{
  int t = blockIdx.x*256 + threadIdx.x;   // B*N*4 threads
  int part = t & 3;
  int p = t >> 2;
  int b = p >> 12;
  int n = p & 4095;
  float m0 = stats[b*4+0], m1 = stats[b*4+1], m2 = stats[b*4+2], mx = stats[b*4+3];
  float inv = 1.f / (2.f * mx);
  float c0 = (coords[((size_t)(b*3)+0)*NP + n] - m0) * inv + 0.5f;
  float c1 = (coords[((size_t)(b*3)+1)*NP + n] - m1) * inv + 0.5f;
  float c2 = (coords[((size_t)(b*3)+2)*NP + n] - m2) * inv + 0.5f;
  float g0 = fminf(fmaxf(c0 * 32.f, 0.f), 31.f);
  float g1 = fminf(fmaxf(c1 * 32.f, 0.f), 31.f);
  float g2 = fminf(fmaxf(c2 * 32.f, 0.f), 31.f);
  int v0 = (int)rintf(g0), v1 = (int)rintf(g1), v2 = (int)rintf(g2);
  int idx = (v0*32 + v1)*32 + v2 + b*VX;
  if (part == 0) {
    nc[((size_t)(b*3)+0)*NP + n] = g0;
    nc[((size_t)(b*3)+1)*NP + n] = g1;
    nc[((size_t)(b*3)+2)*NP + n] = g2;
    atomicAdd(&cnt[idx], 1.f);
  }
  const float* fp = features + (size_t)(b*64)*NP + n;
  float* sp = sums + (size_t)idx*64;
  for (int i = part*16; i < part*16+16; i++)
    atomicAdd(&sp[i], fp[(size_t)i*NP]);
}

// ---------- 3a. conv weight prep ----------
__global__ void wprep_kernel(const float* __restrict__ wt, unsigned short* __restrict__ wpre)
{
  int t = blockIdx.x*256 + threadIdx.x;  // 27*64*8 = 13824
  if (t >= 27*64*8) return;
  int c16 = t & 7, o = (t >> 3) & 63, tap = t >> 9;
  size_t dst = ((size_t)(tap*64 + o)*8 + (c16 ^ (o & 7))) * 8;
  #pragma unroll
  for (int j = 0; j < 8; j++) {
    int i = c16*8 + j;
    wpre[dst + j] = f2bf(wt[(o*64 + i)*27 + tap]);
  }
}

// ---------- 3b. encoder weight prep ----------
__global__ void eprep_kernel(const float* __restrict__ qkv_w, const float* __restrict__ proj_w,
                             const float* __restrict__ w1, const float* __restrict__ w2,
                             unsigned short* __restrict__ dst)
{
  int t = blockIdx.x*256 + threadIdx.x;   // 49152
  float v;
  if (t < 12288)      v = qkv_w[t];
  else if (t < 16384) v = proj_w[t-12288];
  else if (t < 32768) v = w1[t-16384];
  else                v = w2[t-32768];
  dst[t] = f2bf(v);
}

// ---------- 4. 3x3x3 conv via MFMA implicit GEMM (bf16 output) ----------
__global__ __launch_bounds__(256) void conv_mfma_kernel(
    const float* __restrict__ sums, const float* __restrict__ cnt,
    const unsigned short* __restrict__ wpre,
    const float* __restrict__ bias, unsigned short* __restrict__ gout)
{
  __shared__ uint4 plane[6*34*8];
  __shared__ uint4 wsm[3*64*8];
  const int tid = threadIdx.x;
  const int blk = blockIdx.x;       // B*32*8
  const int yq = blk & 7, z = (blk >> 3) & 31, b = blk >> 8;
  const int y0 = yq * 4;
  const int w  = tid >> 6;
  const int lm = tid & 15;
  const int kg = (tid >> 4) & 3;

  f32x4 acc[2][4];
  #pragma unroll
  for (int mt = 0; mt < 2; mt++)
    #pragma unroll
    for (int nt = 0; nt < 4; nt++)
      #pragma unroll
      for (int r = 0; r < 4; r++) acc[mt][nt][r] = 0.f;

  float bv[4];
  #pragma unroll
  for (int nt = 0; nt < 4; nt++) bv[nt] = bias[nt*16 + lm];

  for (int kd = 0; kd < 3; kd++) {
    const int zz = z + kd - 1;
    if (zz < 0 || zz >= 32) continue;
    __syncthreads();
    for (int e = tid; e < 6*34*8; e += 256) {
      int c16 = e & 7;
      int sx  = (e >> 3) % 34;
      int yl  = e / (34*8);
      int yy = y0 - 1 + yl, x = sx - 1;
      uint4 val = make_uint4(0u,0u,0u,0u);
      if (yy >= 0 && yy < 32 && x >= 0 && x < 32) {
        size_t vox = (size_t)(b*VX) + (zz*32 + yy)*32 + x;
        float rc = 1.f / fmaxf(cnt[vox], 1.f);
        const float* src = sums + vox*64 + c16*8;
        float4 f0 = *(const float4*)(src);
        float4 f1 = *(const float4*)(src + 4);
        val.x = pack2bf(f0.x*rc, f0.y*rc);
        val.y = pack2bf(f0.z*rc, f0.w*rc);
        val.z = pack2bf(f1.x*rc, f1.y*rc);
        val.w = pack2bf(f1.z*rc, f1.w*rc);
      }
      plane[(yl*34 + sx)*8 + (c16 ^ (sx & 7))] = val;
    }
    for (int kh = 0; kh < 3; kh++) {
      __syncthreads();
      const uint4* wsrc = (const uint4*)wpre + (size_t)((kd*3 + kh)*3)*512;
      for (int e = tid; e < 1536; e += 256) wsm[e] = wsrc[e];
      __syncthreads();
      const int yi = w + kh;
      #pragma unroll
      for (int kw = 0; kw < 3; kw++) {
        const int sxa = lm + kw, sxb = sxa + 16;
        const int swz = sxa & 7;
        #pragma unroll
        for (int ch = 0; ch < 2; ch++) {
          const int cb = ch*4 + kg;
          ABu a0, a1, w0, w1, w2, w3;
          a0.u = plane[(yi*34 + sxa)*8 + (cb ^ swz)];
          a1.u = plane[(yi*34 + sxb)*8 + (cb ^ swz)];
          const int wsz = cb ^ (lm & 7);
          w0.u = wsm[(kw*64 +      lm)*8 + wsz];
          w1.u = wsm[(kw*64 + 16 + lm)*8 + wsz];
          w2.u = wsm[(kw*64 + 32 + lm)*8 + wsz];
          w3.u = wsm[(kw*64 + 48 + lm)*8 + wsz];
          acc[0][0] = __builtin_amdgcn_mfma_f32_16x16x32_bf16(a0.v, w0.v, acc[0][0], 0,0,0);
          acc[1][0] = __builtin_amdgcn_mfma_f32_16x16x32_bf16(a1.v, w0.v, acc[1][0], 0,0,0);
          acc[0][1] = __builtin_amdgcn_mfma_f32_16x16x32_bf16(a0.v, w1.v, acc[0][1], 0,0,0);
          acc[1][1] = __builtin_amdgcn_mfma_f32_16x16x32_bf16(a1.v, w1.v, acc[1][1], 0,0,0);
          acc[0][2] = __builtin_amdgcn_mfma_f32_16x16x32_bf16(a0.v, w2.v, acc[0][2], 0,0,0);
          acc[1][2] = __builtin_amdgcn_mfma_f32_16x16x32_bf16(a1.v, w2.v, acc[1][2], 0,0,0);
          acc[0][3] = __builtin_amdgcn_mfma_f32_16x16x32_bf16(a0.v, w3.v, acc[0][3], 0,0,0);
          acc[1][3] = __builtin_amdgcn_mfma_f32_16x16x32_bf16(a1.v, w3.v, acc[1][3], 0,0,0);
        }
      }
    }
  }
  const int y = y0 + w;
  #pragma unroll
  for (int mt = 0; mt < 2; mt++) {
    #pragma unroll
    for (int r = 0; r < 4; r++) {
      const int x = mt*16 + kg*4 + r;
      unsigned short* dst = gout + ((size_t)(b*VX) + (z*32 + y)*32 + x)*64 + lm;
      #pragma unroll
      for (int nt = 0; nt < 4; nt++)
        dst[nt*16] = f2bf(fmaxf(acc[mt][nt][r] + bv[nt], 0.f));
    }
  }
}

// ---------- 5. windowed transformer encoder — MFMA, 47.6 KB LDS ----------
// regions (stride 72 ushort, 16B-aligned rows): t_b residual bf16; h_b = h/h2/p;
// q_b = q / mlp-hid-chunk; k_b = k / o-staging; v_b = v [dim][tok].
__global__ __launch_bounds__(256) void encoder_kernel(
    unsigned short* __restrict__ grid,
    const float* __restrict__ ln1_g, const float* __restrict__ ln1_b,
    const float* __restrict__ qkv_b, const float* __restrict__ proj_b,
    const float* __restrict__ ln2_g, const float* __restrict__ ln2_b,
    const float* __restrict__ b1, const float* __restrict__ b2,
    const unsigned short* __restrict__ encw,
    float* __restrict__ se_sum)
{
  __shared__ unsigned short t_b[64*72];
  __shared__ unsigned short h_b[64*72];
  __shared__ unsigned short q_b[64*72];
  __shared__ unsigned short k_b[64*72];
  __shared__ unsigned short v_b[64*72];
  __shared__ float mean_s[64], rstd_s[64];
  __shared__ float sered[256];

  const unsigned short* wqb = encw;            // [192][64]
  const unsigned short* wpb = encw + 12288;    // [64][64]
  const unsigned short* w1b = encw + 16384;    // [256][64]
  const unsigned short* w2b = encw + 32768;    // [64][256]

  const int tid = threadIdx.x;
  const int w = tid >> 6;
  const int lane = tid & 63;
  const int cl = lane & 15;
  const int quad = lane >> 4;
  const int win = blockIdx.x;
  const int b = win >> 9, wn = win & 511;
  const int zb = wn >> 6, yb = (wn >> 3) & 7, xb = wn & 7;
  const size_t gb = (size_t)b * VX * 64;

  // load window (bf16 direct copy)
  for (int e = tid; e < 1024; e += 256) {
    int tok = e >> 4, cg = e & 15;
    int zl = tok >> 4, yl = (tok >> 2) & 3, xl = tok & 3;
    int vox = ((zb*4+zl)*32 + (yb*4+yl))*32 + (xb*4+xl);
    *(uint2*)(t_b + tok*72 + cg*4) = *(const uint2*)(grid + gb + (size_t)vox*64 + cg*4);
  }
  __syncthreads();
  // LN1 stats
  {
    int i = tid >> 2, part = tid & 3;
    float sum = 0.f, sq = 0.f;
    for (int c = part; c < 64; c += 4) { float x = bf2f(t_b[i*72+c]); sum += x; sq += x*x; }
    sum += __shfl_xor(sum, 1); sq += __shfl_xor(sq, 1);
    sum += __shfl_xor(sum, 2); sq += __shfl_xor(sq, 2);
    if (part == 0) {
      float m = sum * (1.f/64.f);
      float var = sq * (1.f/64.f) - m*m;
      mean_s[i] = m; rstd_s[i] = rsqrtf(var + 1e-5f);
    }
  }
  __syncthreads();
  for (int e = tid; e < 4096; e += 256) {
    int tok = e >> 6, c = e & 63;
    float h = (bf2f(t_b[tok*72+c]) - mean_s[tok]) * rstd_s[tok] * ln1_g[c] + ln1_b[c];
    h_b[tok*72 + c] = f2bf(h);
  }
  __syncthreads();
  // qkv: qkv^T = W(192x64) @ h^T; wave w -> dim-tiles 48w..48w+47
  {
    #pragma unroll
    for (int ci = 0; ci < 3; ci++) {
      const int d0 = 48*w + ci*16;
      ABu a0, a1;
      a0.u = *(const uint4*)(wqb + (d0 + cl)*64 + quad*8);
      a1.u = *(const uint4*)(wqb + (d0 + cl)*64 + 32 + quad*8);
      float4 bias4 = *(const float4*)(qkv_b + d0 + quad*4);
      #pragma unroll
      for (int tt = 0; tt < 4; tt++) {
        ABu h0, h1;
        h0.u = *(const uint4*)(h_b + (tt*16 + cl)*72 + quad*8);
        h1.u = *(const uint4*)(h_b + (tt*16 + cl)*72 + 32 + quad*8);
        f32x4 d = {0.f,0.f,0.f,0.f};
        d = __builtin_amdgcn_mfma_f32_16x16x32_bf16(a0.v, h0.v, d, 0,0,0);
        d = __builtin_amdgcn_mfma_f32_16x16x32_bf16(a1.v, h1.v, d, 0,0,0);
        if (d0 < 64) {
          *(uint2*)(q_b + (tt*16+cl)*72 + d0 + quad*4) =
            make_uint2(pack2bf((d[0]+bias4.x)*0.25f, (d[1]+bias4.y)*0.25f),
                       pack2bf((d[2]+bias4.z)*0.25f, (d[3]+bias4.w)*0.25f));
        } else if (d0 < 128) {
          *(uint2*)(k_b + (tt*16+cl)*72 + (d0-64) + quad*4) =
            make_uint2(pack2bf(d[0]+bias4.x, d[1]+bias4.y),
                       pack2bf(d[2]+bias4.z, d[3]+bias4.w));
        } else {
          const float* bp = (const float*)&bias4;
          #pragma unroll
          for (int r = 0; r < 4; r++)
            v_b[((d0-128) + quad*4 + r)*72 + tt*16 + cl] = f2bf(d[r] + bp[r]);
        }
      }
    }
  }
  __syncthreads();
  // attention: wave w owns tok_i rows 16w..16w+15; p overlays h_b; o -> regs
  uint2 pk[4];
  {
    const uint4 z4 = make_uint4(0u,0u,0u,0u);
    #pragma unroll
    for (int h = 0; h < 4; h++) {
      const int hb = h*16;
      ABu bq;
      if (quad < 2) bq.u = *(const uint4*)(q_b + (w*16 + cl)*72 + hb + quad*8);
      else bq.u = z4;
      float sc[4][4];
      #pragma unroll
      for (int tj = 0; tj < 4; tj++) {
        ABu ak;
        if (quad < 2) ak.u = *(const uint4*)(k_b + (tj*16 + cl)*72 + hb + quad*8);
        else ak.u = z4;
        f32x4 d = {0.f,0.f,0.f,0.f};
        d = __builtin_amdgcn_mfma_f32_16x16x32_bf16(ak.v, bq.v, d, 0,0,0);
        #pragma unroll
        for (int r = 0; r < 4; r++) sc[tj][r] = d[r];
      }
      float mx = -1e30f;
      #pragma unroll
      for (int tj = 0; tj < 4; tj++)
        #pragma unroll
        for (int r = 0; r < 4; r++) mx = fmaxf(mx, sc[tj][r]);
      mx = fmaxf(mx, __shfl_xor(mx, 16));
      mx = fmaxf(mx, __shfl_xor(mx, 32));
      float psum = 0.f;
      #pragma unroll
      for (int tj = 0; tj < 4; tj++) {
        float p0 = __expf(sc[tj][0]-mx), p1 = __expf(sc[tj][1]-mx);
        float p2 = __expf(sc[tj][2]-mx), p3 = __expf(sc[tj][3]-mx);
        psum += p0+p1+p2+p3;
        *(uint2*)(h_b + (w*16+cl)*72 + tj*16 + quad*4) =
            make_uint2(pack2bf(p0,p1), pack2bf(p2,p3));
      }
      psum += __shfl_xor(psum, 16);
      psum += __shfl_xor(psum, 32);
      float inv = 1.f / psum;
      f32x4 oacc = {0.f,0.f,0.f,0.f};
      #pragma unroll
      for (int kk = 0; kk < 2; kk++) {
        ABu av, bp;
        av.u = *(const uint4*)(v_b + (hb + cl)*72 + kk*32 + quad*8);
        bp.u = *(const uint4*)(h_b + (w*16 + cl)*72 + kk*32 + quad*8);
        oacc = __builtin_amdgcn_mfma_f32_16x16x32_bf16(av.v, bp.v, oacc, 0,0,0);
      }
      pk[h] = make_uint2(pack2bf(oacc[0]*inv, oacc[1]*inv),
                         pack2bf(oacc[2]*inv, oacc[3]*inv));
    }
  }
  __syncthreads();
  // stage o into k_b [tok][72]
  #pragma unroll
  for (int h = 0; h < 4; h++)
    *(uint2*)(k_b + (w*16+cl)*72 + h*16 + quad*4) = pk[h];
  __syncthreads();
  // proj: out^T = proj_w @ o^T; wave w -> out-cols c0=16w; bf16 RMW into t_b
  {
    const int c0 = w*16;
    ABu a0, a1;
    a0.u = *(const uint4*)(wpb + (c0 + cl)*64 + quad*8);
    a1.u = *(const uint4*)(wpb + (c0 + cl)*64 + 32 + quad*8);
    float4 pb4 = *(const float4*)(proj_b + c0 + quad*4);
    #pragma unroll
    for (int tt = 0; tt < 4; tt++) {
      ABu o0, o1;
      o0.u = *(const uint4*)(k_b + (tt*16 + cl)*72 + quad*8);
      o1.u = *(const uint4*)(k_b + (tt*16 + cl)*72 + 32 + quad*8);
      f32x4 d = {0.f,0.f,0.f,0.f};
      d = __builtin_amdgcn_mfma_f32_16x16x32_bf16(a0.v, o0.v, d, 0,0,0);
      d = __builtin_amdgcn_mfma_f32_16x16x32_bf16(a1.v, o1.v, d, 0,0,0);
      uint2* tp = (uint2*)(t_b + (tt*16+cl)*72 + c0 + quad*4);
      uint2 told = *tp;
      float2 t01 = bfp2f2(told.x), t23 = bfp2f2(told.y);
      *tp = make_uint2(pack2bf(t01.x + d[0] + pb4.x, t01.y + d[1] + pb4.y),
                       pack2bf(t23.x + d[2] + pb4.z, t23.y + d[3] + pb4.w));
    }
  }
  __syncthreads();
  // LN2
  {
    int i = tid >> 2, part = tid & 3;
    float sum = 0.f, sq = 0.f;
    for (int c = part; c < 64; c += 4) { float x = bf2f(t_b[i*72+c]); sum += x; sq += x*x; }
    sum += __shfl_xor(sum, 1); sq += __shfl_xor(sq, 1);
    sum += __shfl_xor(sum, 2); sq += __shfl_xor(sq, 2);
    if (part == 0) {
      float m = sum * (1.f/64.f);
      float var = sq * (1.f/64.f) - m*m;
      mean_s[i] = m; rstd_s[i] = rsqrtf(var + 1e-5f);
    }
  }
  __syncthreads();
  for (int e = tid; e < 4096; e += 256) {
    int tok = e >> 6, c = e & 63;
    float h = (bf2f(t_b[tok*72+c]) - mean_s[tok]) * rstd_s[tok] * ln2_g[c] + ln2_b[c];
    h_b[tok*72 + c] = f2bf(h);
  }
  __syncthreads();
  // MLP chunked over 4 hid-groups of 64; hid chunk overlays q_b
  {
    const int c0 = w*16;
    ABu hb0[4], hb1[4];
    #pragma unroll
    for (int tt = 0; tt < 4; tt++) {
      hb0[tt].u = *(const uint4*)(h_b + (tt*16 + cl)*72 + quad*8);
      hb1[tt].u = *(const uint4*)(h_b + (tt*16 + cl)*72 + 32 + quad*8);
    }
    f32x4 acc2[4];
    #pragma unroll
    for (int tt = 0; tt < 4; tt++)
      #pragma unroll
      for (int r = 0; r < 4; r++) acc2[tt][r] = 0.f;
    for (int ch = 0; ch < 4; ch++) {
      const int m0 = ch*64 + w*16;
      ABu a0, a1;
      a0.u = *(const uint4*)(w1b + (m0 + cl)*64 + quad*8);
      a1.u = *(const uint4*)(w1b + (m0 + cl)*64 + 32 + quad*8);
      float4 b14 = *(const float4*)(b1 + m0 + quad*4);
      const float* bp = (const float*)&b14;
      #pragma unroll
      for (int tt = 0; tt < 4; tt++) {
        f32x4 d = {0.f,0.f,0.f,0.f};
        d = __builtin_amdgcn_mfma_f32_16x16x32_bf16(a0.v, hb0[tt].v, d, 0,0,0);
        d = __builtin_amdgcn_mfma_f32_16x16x32_bf16(a1.v, hb1[tt].v, d, 0,0,0);
        float g[4];
        #pragma unroll
        for (int r = 0; r < 4; r++) {
          float x = d[r] + bp[r];
          float u = 1.5957691f * (x + 0.044715f*x*x*x);
          g[r] = x / (1.f + __expf(-u));
        }
        *(uint2*)(q_b + (tt*16+cl)*72 + w*16 + quad*4) =
            make_uint2(pack2bf(g[0],g[1]), pack2bf(g[2],g[3]));
      }
      __syncthreads();
      ABu a20, a21;
      a20.u = *(const uint4*)(w2b + (c0 + cl)*256 + ch*64 + quad*8);
      a21.u = *(const uint4*)(w2b + (c0 + cl)*256 + ch*64 + 32 + quad*8);
      #pragma unroll
      for (int tt = 0; tt < 4; tt++) {
        ABu bh0, bh1;
        bh0.u = *(const uint4*)(q_b + (tt*16 + cl)*72 + quad*8);
        bh1.u = *(const uint4*)(q_b + (tt*16 + cl)*72 + 32 + quad*8);
        acc2[tt] = __builtin_amdgcn_mfma_f32_16x16x32_bf16(a20.v, bh0.v, acc2[tt], 0,0,0);
        acc2[tt] = __builtin_amdgcn_mfma_f32_16x16x32_bf16(a21.v, bh1.v, acc2[tt], 0,0,0);
      }
      __syncthreads();
    }
    float4 b24 = *(const float4*)(b2 + c0 + quad*4);
    #pragma unroll
    for (int tt = 0; tt < 4; tt++) {
      uint2* tp = (uint2*)(t_b + (tt*16+cl)*72 + c0 + quad*4);
      uint2 told = *tp;
      float2 t01 = bfp2f2(told.x), t23 = bfp2f2(told.y);
      *tp = make_uint2(pack2bf(t01.x + acc2[tt][0] + b24.x, t01.y + acc2[tt][1] + b24.y),
                       pack2bf(t23.x + acc2[tt][2] + b24.z, t23.y + acc2[tt][3] + b24.w));
    }
  }
  __syncthreads();
  // writeback + SE partials
  for (int e = tid; e < 1024; e += 256) {
    int tok = e >> 4, cg = e & 15;
    int zl = tok >> 4, yl = (tok >> 2) & 3, xl = tok & 3;
    int vox = ((zb*4+zl)*32 + (yb*4+yl))*32 + (xb*4+xl);
    *(uint2*)(grid + gb + (size_t)vox*64 + cg*4) = *(const uint2*)(t_b + tok*72 + cg*4);
  }
  {
    int c = tid & 63, quarter = tid >> 6;
    float ps = 0.f;
    #pragma unroll
    for (int t = 0; t < 16; t++) ps += bf2f(t_b[(quarter*16+t)*72 + c]);
    sered[quarter*64 + c] = ps;
  }
  __syncthreads();
  if (tid < 64)
    atomicAdd(&se_sum[b*64 + tid],
              sered[tid] + sered[64+tid] + sered[128+tid] + sered[192+tid]);
}

// ---------- 6. SE squeeze-excite scale ----------
__global__ void se_kernel(const float* __restrict__ se_sum, const float* __restrict__ w1,
                          const float* __restrict__ w2, float* __restrict__ scale)
{
  __shared__ float mean_s[256];
  __shared__ float z1[32];
  int tid = threadIdx.x;
  mean_s[tid] = se_sum[tid] * (1.f / VX);
  __syncthreads();
  if (tid < 32) {
    int bb = tid >> 3, j = tid & 7;
    float a = 0.f;
    for (int c = 0; c < 64; c++) a += mean_s[bb*64 + c] * w1[j*64 + c];
    z1[tid] = fmaxf(a, 0.f);
  }
  __syncthreads();
  int b = tid >> 6, c = tid & 63;
  float a = 0.f;
  for (int j = 0; j < 8; j++) a += z1[b*8 + j] * w2[c*8 + j];
  scale[tid] = 1.f / (1.f + __expf(-a));
}

// ---------- 7. point branch input ----------
__global__ __launch_bounds__(256) void point_in_kernel(
    const float* __restrict__ features,
    const float* __restrict__ pt_in_w, const float* __restrict__ pt_in_b,
    const float* __restrict__ q_w, const float* __restrict__ k_w,
    const float* __restrict__ v_w,
    float* __restrict__ x_t, unsigned short* __restrict__ q_bf,
    unsigned short* __restrict__ k_bf, unsigned short* __restrict__ v_tt)
{
  __shared__ float f_s[64*65];
  __shared__ float x_s[64*65];
  const int tid = threadIdx.x;
  const int blk = blockIdx.x;
  const int b = blk >> 6;
  const int n0 = (blk & 63) * 64;
  for (int e = tid; e < 4096; e += 256) {
    int i = e >> 6, nl = e & 63;
    f_s[nl*65 + i] = features[((size_t)(b*64 + i))*NP + n0 + nl];
  }
  __syncthreads();
  const int c = tid & 63, g = tid >> 6;
  const int t0 = g * 16;
  {
    float acc[16];
    #pragma unroll
    for (int t = 0; t < 16; t++) acc[t] = 0.f;
    for (int i = 0; i < 64; i++) {
      float wv = pt_in_w[c*64 + i];
      #pragma unroll
      for (int t = 0; t < 16; t++) acc[t] += f_s[(t0+t)*65 + i] * wv;
    }
    float bb = pt_in_b[c];
    #pragma unroll
    for (int t = 0; t < 16; t++) {
      float x = fmaxf(acc[t] + bb, 0.f);
      x_s[(t0+t)*65 + c] = x;
      x_t[((size_t)(b*NP) + n0 + t0 + t)*64 + c] = x;
    }
  }
  __syncthreads();
  {
    float acc[16];
    #pragma unroll
    for (int t = 0; t < 16; t++) acc[t] = 0.f;
    for (int k = 0; k < 64; k++) {
      float wv = v_w[c*64 + k];
      #pragma unroll
      for (int t = 0; t < 16; t++) acc[t] += x_s[(t0+t)*65 + k] * wv;
    }
    #pragma unroll
    for (int t = 0; t < 16; t++)
      v_tt[((size_t)(b*64) + c)*NP + n0 + t0 + t] = f2bf(acc[t]);
  }
  if (tid < 128) {
    int d = tid & 15, which = (tid >> 4) & 1, g2 = tid >> 5;
    int t0b = g2 * 16;
    const float* wp = which ? k_w : q_w;
    float scl = which ? 1.f : 0.25f;
    float acc[16];
    #pragma unroll
    for (int t = 0; t < 16; t++) acc[t] = 0.f;
    for (int cc = 0; cc < 64; cc++) {
      float wv = wp[d*64 + cc];
      #pragma unroll
      for (int t = 0; t < 16; t++) acc[t] += x_s[(t0b+t)*65 + cc] * wv;
    }
    unsigned short* dst = which ? k_bf : q_bf;
    #pragma unroll
    for (int t = 0; t < 16; t++)
      dst[((size_t)(b*NP) + n0 + t0b + t)*16 + d] = f2bf(acc[t] * scl);
  }
}

// ---------- 8. point attention — MFMA flash, 4-way KV split ----------
__global__ __launch_bounds__(256) void point_attn_kernel(
    const unsigned short* __restrict__ q_bf, const unsigned short* __restrict__ k_bf,
    const unsigned short* __restrict__ v_tt,
    float* __restrict__ opart, float2* __restrict__ mlbuf)
{
  __shared__ unsigned short q_s[64*24];
  __shared__ unsigned short k_sh[2][64*24];
  __shared__ unsigned short v_sh[2][64*72];
  __shared__ unsigned short p_s[64*72];
  const int tid = threadIdx.x;
  const int blk = blockIdx.x;      // B*64*4
  const int b = blk >> 8;
  const int nb = (blk >> 2) & 63;
  const int s = blk & 3;
  const int n0 = nb * 64;
  const int t_beg = s*16, t_end = s*16 + 16;
  const int w = tid >> 6;
  const int lane = tid & 63;
  const int cl = lane & 15;
  const int quad = lane >> 4;
  const uint4 z4 = make_uint4(0u,0u,0u,0u);

  const unsigned* qbu = (const unsigned*)q_bf;
  const unsigned* kbu = (const unsigned*)k_bf;
  const unsigned* vtu = (const unsigned*)v_tt;
  unsigned* q_su = (unsigned*)q_s;

  {
    unsigned* kd = (unsigned*)k_sh[0];
    unsigned* vd = (unsigned*)v_sh[0];
    for (int e = tid; e < 512; e += 256) {
      int tok = e >> 3, du = e & 7;
      q_su[tok*12 + du] = qbu[((size_t)(b*NP) + n0 + tok)*8 + du];
      kd[tok*12 + du]   = kbu[((size_t)(b*NP) + t_beg*64 + tok)*8 + du];
    }
    for (int e = tid; e < 2048; e += 256) {
      int cc = e >> 5, tu = e & 31;
      vd[cc*36 + tu] = vtu[((size_t)(b*64) + cc)*2048 + t_beg*32 + tu];
    }
  }
  float m_run = -1e30f, l_run = 0.f;
  f32x4 acc[4];
  #pragma unroll
  for (int ct = 0; ct < 4; ct++)
    #pragma unroll
    for (int r = 0; r < 4; r++) acc[ct][r] = 0.f;
  __syncthreads();

  ABu bq;
  if (quad < 2) bq.u = *(const uint4*)(q_s + (w*16 + cl)*24 + quad*8);
  else bq.u = z4;

  for (int t = t_beg; t < t_end; t++) {
    const int cur = t & 1;
    unsigned pk[2], pv[8];
    if (t+1 < t_end) {
      const int m1 = (t+1)*64;
      #pragma unroll
      for (int i = 0; i < 2; i++) {
        int e = tid + i*256;
        pk[i] = kbu[((size_t)(b*NP) + m1 + (e>>3))*8 + (e&7)];
      }
      #pragma unroll
      for (int i = 0; i < 8; i++) {
        int e = tid + i*256;
        pv[i] = vtu[((size_t)(b*64) + (e>>5))*2048 + (m1>>1) + (e&31)];
      }
    }
    const unsigned short* ks = k_sh[cur];
    const unsigned short* vs = v_sh[cur];
    float sc[4][4];
    #pragma unroll
    for (int tj = 0; tj < 4; tj++) {
      ABu ak;
      if (quad < 2) ak.u = *(const uint4*)(ks + (tj*16 + cl)*24 + quad*8);
      else ak.u = z4;
      f32x4 d = {0.f,0.f,0.f,0.f};
      d = __builtin_amdgcn_mfma_f32_16x16x32_bf16(ak.v, bq.v, d, 0,0,0);
      #pragma unroll
      for (int r = 0; r < 4; r++) sc[tj][r] = d[r];
    }
    float tmax = -1e30f;
    #pragma unroll
    for (int tj = 0; tj < 4; tj++)
      #pragma unroll
      for (int r = 0; r < 4; r++) tmax = fmaxf(tmax, sc[tj][r]);
    tmax = fmaxf(tmax, __shfl_xor(tmax, 16));
    tmax = fmaxf(tmax, __shfl_xor(tmax, 32));
    float mnew = fmaxf(m_run, tmax);
    float alpha = __expf(m_run - mnew);
    float psum = 0.f;
    #pragma unroll
    for (int tj = 0; tj < 4; tj++) {
      float p0 = __expf(sc[tj][0]-mnew), p1 = __expf(sc[tj][1]-mnew);
      float p2 = __expf(sc[tj][2]-mnew), p3 = __expf(sc[tj][3]-mnew);
      psum += p0+p1+p2+p3;
      *(uint2*)(p_s + (w*16+cl)*72 + tj*16 + quad*4) =
          make_uint2(pack2bf(p0,p1), pack2bf(p2,p3));
    }
    psum += __shfl_xor(psum, 16);
    psum += __shfl_xor(psum, 32);
    l_run = l_run*alpha + psum;
    m_run = mnew;
    #pragma unroll
    for (int ct = 0; ct < 4; ct++)
      #pragma unroll
      for (int r = 0; r < 4; r++) acc[ct][r] *= alpha;
    #pragma unroll
    for (int kk = 0; kk < 2; kk++) {
      ABu bp;
      bp.u = *(const uint4*)(p_s + (w*16 + cl)*72 + kk*32 + quad*8);
      #pragma unroll
      for (int ct = 0; ct < 4; ct++) {
        ABu av;
        av.u = *(const uint4*)(vs + (ct*16 + cl)*72 + kk*32 + quad*8);
        acc[ct] = __builtin_amdgcn_mfma_f32_16x16x32_bf16(av.v, bp.v, acc[ct], 0,0,0);
      }
    }
    __syncthreads();
    if (t+1 < t_end) {
      unsigned* kd = (unsigned*)k_sh[1-cur];
      unsigned* vd = (unsigned*)v_sh[1-cur];
      #pragma unroll
      for (int i = 0; i < 2; i++) {
        int e = tid + i*256;
        kd[(e>>3)*12 + (e&7)] = pk[i];
      }
      #pragma unroll
      for (int i = 0; i < 8; i++) {
        int e = tid + i*256;
        vd[(e>>5)*36 + (e&31)] = pv[i];
      }
    }
    __syncthreads();
  }
  const int tok = n0 + w*16 + cl;
  #pragma unroll
  for (int ct = 0; ct < 4; ct++) {
    float4 o4;
    o4.x = acc[ct][0]; o4.y = acc[ct][1]; o4.z = acc[ct][2]; o4.w = acc[ct][3];
    *(float4*)&opart[(((size_t)(s*BN + b))*NP + tok)*64 + ct*16 + quad*4] = o4;
  }
  if (quad == 0)
    mlbuf[(size_t)(s*BN + b)*NP + tok] = make_float2(m_run, l_run);
}

// ---------- 9. merge + devox + offset transform + fuse ----------
__global__ __launch_bounds__(256) void fuse_kernel(
    const float* __restrict__ x_t, const float* __restrict__ opart,
    const float2* __restrict__ mlbuf,
    const float* __restrict__ trans_w, const float* __restrict__ trans_b,
    const unsigned short* __restrict__ grid, const float* __restrict__ se_scale,
    const float* __restrict__ nc, float* __restrict__ out)
{
  __shared__ float tw_s[64*65];
  __shared__ float d_s[32*65];
  __shared__ float r_s[64*33];
  __shared__ float mw[32][6];     // w0..w3, invL
  const int tid = threadIdx.x;
  const int blk = blockIdx.x;     // B*128
  const int b = blk >> 7;
  const int n0 = (blk & 127) * 32;
  for (int e = tid; e < 4096; e += 256) {
    int c = e >> 6, k = e & 63;
    tw_s[c*65 + k] = trans_w[e];
  }
  if (tid < 32) {
    int nl = tid;
    float m[4], l[4];
    #pragma unroll
    for (int s = 0; s < 4; s++) {
      float2 v = mlbuf[(size_t)(s*BN + b)*NP + n0 + nl];
      m[s] = v.x; l[s] = v.y;
    }
    float M = fmaxf(fmaxf(m[0], m[1]), fmaxf(m[2], m[3]));
    float L = 0.f;
    #pragma unroll
    for (int s = 0; s < 4; s++) {
      float ws = __expf(m[s] - M);
      mw[nl][s] = ws;
      L += l[s] * ws;
    }
    mw[nl][4] = 1.f / L;
  }
  __syncthreads();
  for (int e = tid; e < 2048; e += 256) {
    int nl = e >> 6, c = e & 63;
    size_t pbase = ((size_t)(b*NP) + n0 + nl)*64 + c;
    const size_t sstr = (size_t)BN*NP*64;
    float o = opart[pbase]        * mw[nl][0] + opart[pbase +   sstr] * mw[nl][1]
            + opart[pbase+2*sstr] * mw[nl][2] + opart[pbase + 3*sstr] * mw[nl][3];
    o *= mw[nl][4];
    d_s[nl*65 + c] = x_t[pbase] - o;
  }
  __syncthreads();
  const int cl = tid & 63, g = tid >> 6;
  const float ses = se_scale[b*64 + cl];
  const float tb = trans_b[cl];
  for (int t = 0; t < 8; t++) {
    int nl = g*8 + t;
    int n = n0 + nl;
    float off = 0.f;
    for (int k = 0; k < 64; k++) off += tw_s[cl*65 + k] * d_s[nl*65 + k];
    off = fmaxf(off + tb, 0.f);
    float ncx = nc[((size_t)(b*3)+0)*NP + n];
    float ncy = nc[((size_t)(b*3)+1)*NP + n];
    float ncz = nc[((size_t)(b*3)+2)*NP + n];
    float fx0 = floorf(ncx), fy0 = floorf(ncy), fz0 = floorf(ncz);
    int x0 = (int)fx0, y0 = (int)fy0, z0 = (int)fz0;
    float fx = ncx - fx0, fy = ncy - fy0, fz = ncz - fz0;
    float wx[2] = {1.f-fx, fx}, wy[2] = {1.f-fy, fy}, wz[2] = {1.f-fz, fz};
    float vf = 0.f;
    #pragma unroll
    for (int cor = 0; cor < 8; cor++) {
      int dx = cor >> 2, dy = (cor >> 1) & 1, dz = cor & 1;
      int xi = min(x0+dx, 31), yi = min(y0+dy, 31), zi = min(z0+dz, 31);
      float wgt = wx[dx]*wy[dy]*wz[dz];
      vf += wgt * bf2f(grid[((size_t)(b*VX) + (xi*32+yi)*32 + zi)*64 + cl]);
    }
    vf *= ses;
    float xval = x_t[((size_t)(b*NP) + n)*64 + cl];
    r_s[cl*33 + nl] = xval + off + vf;
  }
  __syncthreads();
  for (int e = tid; e < 2048; e += 256) {
    int c = e >> 5, nl = e & 31;
    out[((size_t)(b*64) + c)*NP + n0 + nl] = r_s[c*33 + nl];
  }
}

extern "C" void kernel_launch(void* const* d_in, const int* in_sizes, int n_in,
                              void* d_out, int out_size, void* d_ws, size_t ws_size,
                              hipStream_t stream)
{
  const float* features = (const float*)d_in[0];
  const float* coords   = (const float*)d_in[1];
  const float* conv_w   = (const float*)d_in[2];
  const float* conv_b   = (const float*)d_in[3];
  const float* ln1_g    = (const float*)d_in[4];
  const float* ln1_b    = (const float*)d_in[5];
  const float* qkv_w    = (const float*)d_in[6];
  const float* qkv_b    = (const float*)d_in[7];
  const float* proj_w   = (const float*)d_in[8];
  const float* proj_b   = (const float*)d_in[9];
  const float* ln2_g    = (const float*)d_in[10];
  const float* ln2_b    = (const float*)d_in[11];
  const float* mlp_w1   = (const float*)d_in[12];
  const float* mlp_b1   = (const float*)d_in[13];
  const float* mlp_w2   = (const float*)d_in[14];
  const float* mlp_b2   = (const float*)d_in[15];
  const float* se_w1    = (const float*)d_in[16];
  const float* se_w2    = (const float*)d_in[17];
  const float* pt_in_w  = (const float*)d_in[18];
  const float* pt_in_b  = (const float*)d_in[19];
  const float* q_w      = (const float*)d_in[20];
  const float* k_w      = (const float*)d_in[21];
  const float* v_w      = (const float*)d_in[22];
  const float* v_trans_w= (const float*)d_in[23];
  const float* v_trans_b= (const float*)d_in[24];

  char* ws = (char*)d_ws;
  float* stats    = (float*)(ws + 0);
  float* se_sum   = (float*)(ws + 256);
  float* se_scale = (float*)(ws + 1280);
  float* nc       = (float*)(ws + 4096);
  float* cnt      = (float*)(ws + 200704);
  float* grid0    = (float*)(ws + 724992);               // fp32 sums (zeroed)
  unsigned short* grid1b = (unsigned short*)(ws + 34279424);  // bf16 grid
  // point-branch buffers reuse grid0 region (dead after conv)
  float* x_t = (float*)(ws + 724992);
  unsigned short* q_bf = (unsigned short*)(ws + 724992 + 4194304);
  unsigned short* k_bf = (unsigned short*)(ws + 724992 + 5242880);
  unsigned short* v_tt = (unsigned short*)(ws + 724992 + 6291456);
  float*  opart = (float*)(ws + 724992 + 10485760);      // 16 MB (4 splits)
  float2* mlbuf = (float2*)(ws + 724992 + 27787264);     // 512 KB
  // packed bf16 weights in d_out (dead until fuse writes it)
  unsigned short* wpre = (unsigned short*)d_out;
  unsigned short* encw = (unsigned short*)((char*)d_out + 221184);

  hipMemsetAsync(se_sum, 0, 1024, stream);
  hipMemsetAsync(cnt, 0, 524288 + 33554432, stream);

  wprep_kernel<<<54, 256, 0, stream>>>(conv_w, wpre);
  eprep_kernel<<<192, 256, 0, stream>>>(qkv_w, proj_w, mlp_w1, mlp_w2, encw);
  stats_kernel<<<BN, 256, 0, stream>>>(coords, stats);
  scatter_kernel<<<256, 256, 0, stream>>>(features, coords, stats, nc, grid0, cnt);
  conv_mfma_kernel<<<1024, 256, 0, stream>>>(grid0, cnt, wpre, conv_b, grid1b);
  encoder_kernel<<<2048, 256, 0, stream>>>(grid1b, ln1_g, ln1_b, qkv_b, proj_b,
      ln2_g, ln2_b, mlp_b1, mlp_b2, encw, se_sum);
  se_kernel<<<1, 256, 0, stream>>>(se_sum, se_w1, se_w2, se_scale);
  point_in_kernel<<<256, 256, 0, stream>>>(features, pt_in_w, pt_in_b, q_w, k_w, v_w,
      x_t, q_bf, k_bf, v_tt);
  point_attn_kernel<<<1024, 256, 0, stream>>>(q_bf, k_bf, v_tt, opart, mlbuf);
  fuse_kernel<<<512, 256, 0, stream>>>(x_t, opart, mlbuf, v_trans_w, v_trans_b,
      grid1b, se_scale, nc, (float*)d_out);
  hipMemcpyAsync((char*)d_out + (size_t)BN*64*NP*4, coords, (size_t)BN*3*NP*4,
                 hipMemcpyDeviceToDevice, stream);
}

// Round 5
// 398.323 us; speedup vs baseline: 7.5956x; 1.0762x over previous
//
#include <hip/hip_runtime.h>

#define BN 4
#define NP 4096
#define RV 32
#define VX (RV*RV*RV)

typedef __attribute__((ext_vector_type(8))) short bf16x8;
typedef __attribute__((ext_vector_type(4))) float f32x4;

// ---------- bf16 helpers (bit-level) ----------
__device__ __forceinline__ float bf2f(unsigned short u){
  union{unsigned u;float f;}v; v.u=((unsigned)u)<<16; return v.f; }
__device__ __forceinline__ unsigned short f2bf(float f){
  union{float f;unsigned u;}v; v.f=f; unsigned r=v.u + 0x7fffu + ((v.u>>16)&1u);
  return (unsigned short)(r>>16); }
__device__ __forceinline__ float2 bfp2f2(unsigned p){
  union{unsigned u;float f;}a,b; a.u=p<<16; b.u=p&0xffff0000u;
  float2 r; r.x=a.f; r.y=b.f; return r; }
__device__ __forceinline__ unsigned pack2bf(float a, float b){
  return (unsigned)f2bf(a) | ((unsigned)f2bf(b) << 16); }

union ABu { uint4 u; bf16x8 v; };

// ---------- 1. per-batch coord stats ----------
__global__ void stats_kernel(const float* __restrict__ coords, float* __restrict__ stats)
{
  __shared__ float red[256];
  __shared__ float mean[3];
  const int b = blockIdx.x;
  const int tid = threadIdx.x;
  float s0=0.f,s1=0.f,s2=0.f;
  for (int n = tid; n < NP; n += 256) {
    s0 += coords[((size_t)(b*3)+0)*NP + n];
    s1 += coords[((size_t)(b*3)+1)*NP + n];
    s2 += coords[((size_t)(b*3)+2)*NP + n];
  }
  float sv[3] = {s0,s1,s2};
  for (int ax = 0; ax < 3; ax++) {
    __syncthreads();
    red[tid] = sv[ax];
    __syncthreads();
    for (int st = 128; st > 0; st >>= 1) {
      if (tid < st) red[tid] += red[tid + st];
      __syncthreads();
    }
    if (tid == 0) mean[ax] = red[0] * (1.f / NP);
  }
  __syncthreads();
  float mx = 0.f;
  for (int n = tid; n < NP; n += 256) {
    float d0 = coords[((size_t)(b*3)+0)*NP + n] - mean[0];
    float d1 = coords[((size_t)(b*3)+1)*NP + n] - mean[1];
    float d2 = coords[((size_t)(b*3)+2)*NP + n] - mean[2];
    mx = fmaxf(mx, sqrtf(d0*d0 + d1*d1 + d2*d2));
  }
  __syncthreads();
  red[tid] = mx;
  __syncthreads();
  for (int st = 128; st > 0; st >>= 1) {
    if (tid < st) red[tid] = fmaxf(red[tid], red[tid + st]);
    __syncthreads();
  }
  if (tid == 0) {
    stats[b*4+0] = mean[0]; stats[b*4+1] = mean[1];
    stats[b*4+2] = mean[2]; stats[b*4+3] = red[0];
  }
}

// ---------- 2. voxelize scatter-sum ----------
__global__ void scatter_kernel(const float* __restrict__ features,
                               const float* __restrict__ coords,
                               const float* __restrict__ stats,
                               float* __restrict__ nc,
                               float* __restrict__ sums, float* __restrict__ cnt)
{
  int t = blockIdx.x*256 + threadIdx.x;   // B*N*4 threads
  int part = t & 3;
  int p = t >> 2;
  int b = p >> 12;
  int n = p & 4095;
  float m0 = stats[b*4+0], m1 = stats[b*4+1], m2 = stats[b*4+2], mx = stats[b*4+3];
  float inv = 1.f / (2.f * mx);
  float c0 = (coords[((size_t)(b*3)+0)*NP + n] - m0) * inv + 0.5f;
  float c1 = (coords[((size_t)(b*3)+1)*NP + n] - m1) * inv + 0.5f;
  float c2 = (coords[((size_t)(b*3)+2)*NP + n] - m2) * inv + 0.5f;
  float g0 = fminf(fmaxf(c0 * 32.f, 0.f), 31.f);
  float g1 = fminf(fmaxf(c1 * 32.f, 0.f), 31.f);
  float g2 = fminf(fmaxf(c2 * 32.f, 0.f), 31.f);
  int v0 = (int)rintf(g0), v1 = (int)rintf(g1), v2 = (int)rintf(g2);
  int idx = (v0*32 + v1)*32 + v2 + b*VX;
  if (part == 0) {
    nc[((size_t)(b*3)+0)*NP + n] = g0;
    nc[((size_t)(b*3)+1)*NP + n] = g1;
    nc[((size_t)(b*3)+2)*NP + n] = g2;
    atomicAdd(&cnt[idx], 1.f);
  }
  const float* fp = features + (size_t)(b*64)*NP + n;
  float* sp = sums + (size_t)idx*64;
  for (int i = part*16; i < part*16+16; i++)
    atomicAdd(&sp[i], fp[(size_t)i*NP]);
}

// ---------- 3a. conv weight prep ----------
__global__ void wprep_kernel(const float* __restrict__ wt, unsigned short* __restrict__ wpre)
{
  int t = blockIdx.x*256 + threadIdx.x;  // 27*64*8 = 13824
  if (t >= 27*64*8) return;
  int c16 = t & 7, o = (t >> 3) & 63, tap = t >> 9;
  size_t dst = ((size_t)(tap*64 + o)*8 + (c16 ^ (o & 7))) * 8;
  #pragma unroll
  for (int j = 0; j < 8; j++) {
    int i = c16*8 + j;
    wpre[dst + j] = f2bf(wt[(o*64 + i)*27 + tap]);
  }
}

// ---------- 3b. encoder+point weight prep (q-scales pre-folded) ----------
__global__ void eprep_kernel(const float* __restrict__ qkv_w, const float* __restrict__ proj_w,
                             const float* __restrict__ w1, const float* __restrict__ w2,
                             const float* __restrict__ pt_in_w, const float* __restrict__ q_w,
                             const float* __restrict__ k_w, const float* __restrict__ v_w,
                             unsigned short* __restrict__ dst)
{
  int t = blockIdx.x*256 + threadIdx.x;   // 59392
  if (t >= 59392) return;
  float v;
  if (t < 4096)       v = qkv_w[t] * 0.25f;        // q rows pre-scaled
  else if (t < 12288) v = qkv_w[t];
  else if (t < 16384) v = proj_w[t-12288];
  else if (t < 32768) v = w1[t-16384];
  else if (t < 49152) v = w2[t-32768];
  else {
    int t2 = t - 49152;
    if (t2 < 4096)      v = pt_in_w[t2];
    else if (t2 < 5120) v = q_w[t2-4096] * 0.25f;  // point q pre-scaled
    else if (t2 < 6144) v = k_w[t2-5120];
    else                v = v_w[t2-6144];
  }
  dst[t] = f2bf(v);
}

// ---------- 4. 3x3x3 conv via MFMA implicit GEMM (bf16 output) ----------
__global__ __launch_bounds__(256) void conv_mfma_kernel(
    const float* __restrict__ sums, const float* __restrict__ cnt,
    const unsigned short* __restrict__ wpre,
    const float* __restrict__ bias, unsigned short* __restrict__ gout)
{
  __shared__ uint4 plane[6*34*8];
  __shared__ uint4 wsm[3*64*8];
  const int tid = threadIdx.x;
  const int blk = blockIdx.x;       // B*32*8
  const int yq = blk & 7, z = (blk >> 3) & 31, b = blk >> 8;
  const int y0 = yq * 4;
  const int w  = tid >> 6;
  const int lm = tid & 15;
  const int kg = (tid >> 4) & 3;

  f32x4 acc[2][4];
  #pragma unroll
  for (int mt = 0; mt < 2; mt++)
    #pragma unroll
    for (int nt = 0; nt < 4; nt++)
      #pragma unroll
      for (int r = 0; r < 4; r++) acc[mt][nt][r] = 0.f;

  float bv[4];
  #pragma unroll
  for (int nt = 0; nt < 4; nt++) bv[nt] = bias[nt*16 + lm];

  for (int kd = 0; kd < 3; kd++) {
    const int zz = z + kd - 1;
    if (zz < 0 || zz >= 32) continue;
    __syncthreads();
    for (int e = tid; e < 6*34*8; e += 256) {
      int c16 = e & 7;
      int sx  = (e >> 3) % 34;
      int yl  = e / (34*8);
      int yy = y0 - 1 + yl, x = sx - 1;
      uint4 val = make_uint4(0u,0u,0u,0u);
      if (yy >= 0 && yy < 32 && x >= 0 && x < 32) {
        size_t vox = (size_t)(b*VX) + (zz*32 + yy)*32 + x;
        float rc = 1.f / fmaxf(cnt[vox], 1.f);
        const float* src = sums + vox*64 + c16*8;
        float4 f0 = *(const float4*)(src);
        float4 f1 = *(const float4*)(src + 4);
        val.x = pack2bf(f0.x*rc, f0.y*rc);
        val.y = pack2bf(f0.z*rc, f0.w*rc);
        val.z = pack2bf(f1.x*rc, f1.y*rc);
        val.w = pack2bf(f1.z*rc, f1.w*rc);
      }
      plane[(yl*34 + sx)*8 + (c16 ^ (sx & 7))] = val;
    }
    for (int kh = 0; kh < 3; kh++) {
      __syncthreads();
      const uint4* wsrc = (const uint4*)wpre + (size_t)((kd*3 + kh)*3)*512;
      for (int e = tid; e < 1536; e += 256) wsm[e] = wsrc[e];
      __syncthreads();
      const int yi = w + kh;
      #pragma unroll
      for (int kw = 0; kw < 3; kw++) {
        const int sxa = lm + kw, sxb = sxa + 16;
        const int swz = sxa & 7;
        #pragma unroll
        for (int ch = 0; ch < 2; ch++) {
          const int cb = ch*4 + kg;
          ABu a0, a1, w0, w1, w2, w3;
          a0.u = plane[(yi*34 + sxa)*8 + (cb ^ swz)];
          a1.u = plane[(yi*34 + sxb)*8 + (cb ^ swz)];
          const int wsz = cb ^ (lm & 7);
          w0.u = wsm[(kw*64 +      lm)*8 + wsz];
          w1.u = wsm[(kw*64 + 16 + lm)*8 + wsz];
          w2.u = wsm[(kw*64 + 32 + lm)*8 + wsz];
          w3.u = wsm[(kw*64 + 48 + lm)*8 + wsz];
          acc[0][0] = __builtin_amdgcn_mfma_f32_16x16x32_bf16(a0.v, w0.v, acc[0][0], 0,0,0);
          acc[1][0] = __builtin_amdgcn_mfma_f32_16x16x32_bf16(a1.v, w0.v, acc[1][0], 0,0,0);
          acc[0][1] = __builtin_amdgcn_mfma_f32_16x16x32_bf16(a0.v, w1.v, acc[0][1], 0,0,0);
          acc[1][1] = __builtin_amdgcn_mfma_f32_16x16x32_bf16(a1.v, w1.v, acc[1][1], 0,0,0);
          acc[0][2] = __builtin_amdgcn_mfma_f32_16x16x32_bf16(a0.v, w2.v, acc[0][2], 0,0,0);
          acc[1][2] = __builtin_amdgcn_mfma_f32_16x16x32_bf16(a1.v, w2.v, acc[1][2], 0,0,0);
          acc[0][3] = __builtin_amdgcn_mfma_f32_16x16x32_bf16(a0.v, w3.v, acc[0][3], 0,0,0);
          acc[1][3] = __builtin_amdgcn_mfma_f32_16x16x32_bf16(a1.v, w3.v, acc[1][3], 0,0,0);
        }
      }
    }
  }
  const int y = y0 + w;
  #pragma unroll
  for (int mt = 0; mt < 2; mt++) {
    #pragma unroll
    for (int r = 0; r < 4; r++) {
      const int x = mt*16 + kg*4 + r;
      unsigned short* dst = gout + ((size_t)(b*VX) + (z*32 + y)*32 + x)*64 + lm;
      #pragma unroll
      for (int nt = 0; nt < 4; nt++)
        dst[nt*16] = f2bf(fmaxf(acc[mt][nt][r] + bv[nt], 0.f));
    }
  }
}

// ---------- 5. windowed transformer encoder — MFMA + vectorized glue ----------
__global__ __launch_bounds__(256) void encoder_kernel(
    unsigned short* __restrict__ grid,
    const float* __restrict__ ln1_g, const float* __restrict__ ln1_b,
    const float* __restrict__ qkv_b, const float* __restrict__ proj_b,
    const float* __restrict__ ln2_g, const float* __restrict__ ln2_b,
    const float* __restrict__ b1, const float* __restrict__ b2,
    const unsigned short* __restrict__ encw,
    float* __restrict__ se_sum)
{
  __shared__ unsigned short t_b[64*72];
  __shared__ unsigned short h_b[64*72];
  __shared__ unsigned short q_b[64*72];
  __shared__ unsigned short k_b[64*72];
  __shared__ unsigned short v_b[64*72];
  __shared__ float mean_s[64], rstd_s[64];
  __shared__ float scratch[1024];   // LN2 partials (512) | SE float4 partials (1024)

  const unsigned short* wqb = encw;            // [192][64]
  const unsigned short* wpb = encw + 12288;    // [64][64]
  const unsigned short* w1b = encw + 16384;    // [256][64]
  const unsigned short* w2b = encw + 32768;    // [64][256]

  const int tid = threadIdx.x;
  const int w = tid >> 6;
  const int lane = tid & 63;
  const int cl = lane & 15;
  const int quad = lane >> 4;
  const int win = blockIdx.x;
  const int b = win >> 9, wn = win & 511;
  const int zb = wn >> 6, yb = (wn >> 3) & 7, xb = wn & 7;
  const size_t gb = (size_t)b * VX * 64;

  // load window (uint4)
  for (int e = tid; e < 512; e += 256) {
    int tok = e >> 3, cg8 = e & 7;
    int zl = tok >> 4, yl = (tok >> 2) & 3, xl = tok & 3;
    int vox = ((zb*4+zl)*32 + (yb*4+yl))*32 + (xb*4+xl);
    *(uint4*)(t_b + tok*72 + cg8*8) = *(const uint4*)(grid + gb + (size_t)vox*64 + cg8*8);
  }
  __syncthreads();
  // LN1 stats (16 ch per thread via 2 x b128)
  {
    int i = tid >> 2, part = tid & 3;
    ABu r0, r1;
    r0.u = *(const uint4*)(t_b + i*72 + part*16);
    r1.u = *(const uint4*)(t_b + i*72 + part*16 + 8);
    float sum = 0.f, sq = 0.f;
    const unsigned* u0 = (const unsigned*)&r0;
    const unsigned* u1 = (const unsigned*)&r1;
    #pragma unroll
    for (int j = 0; j < 4; j++) {
      float2 a = bfp2f2(u0[j]); float2 c = bfp2f2(u1[j]);
      sum += a.x + a.y + c.x + c.y;
      sq  += a.x*a.x + a.y*a.y + c.x*c.x + c.y*c.y;
    }
    sum += __shfl_xor(sum, 1); sq += __shfl_xor(sq, 1);
    sum += __shfl_xor(sum, 2); sq += __shfl_xor(sq, 2);
    if (part == 0) {
      float m = sum * (1.f/64.f);
      float var = sq * (1.f/64.f) - m*m;
      mean_s[i] = m; rstd_s[i] = rsqrtf(var + 1e-5f);
    }
  }
  __syncthreads();
  // LN1 apply (fixed 4-ch column per thread)
  {
    const int cg = tid & 15, tq = tid >> 4;
    float4 g4 = *(const float4*)(ln1_g + cg*4);
    float4 b4 = *(const float4*)(ln1_b + cg*4);
    #pragma unroll
    for (int k = 0; k < 4; k++) {
      int tok = tq + k*16;
      uint2 tv = *(const uint2*)(t_b + tok*72 + cg*4);
      float2 x01 = bfp2f2(tv.x), x23 = bfp2f2(tv.y);
      float m = mean_s[tok], r = rstd_s[tok];
      float h0 = (x01.x-m)*r*g4.x + b4.x;
      float h1 = (x01.y-m)*r*g4.y + b4.y;
      float h2 = (x23.x-m)*r*g4.z + b4.z;
      float h3 = (x23.y-m)*r*g4.w + b4.w;
      *(uint2*)(h_b + tok*72 + cg*4) = make_uint2(pack2bf(h0,h1), pack2bf(h2,h3));
    }
  }
  __syncthreads();
  // qkv (q weights+bias pre-scaled by 0.25)
  {
    #pragma unroll
    for (int ci = 0; ci < 3; ci++) {
      const int d0 = 48*w + ci*16;
      ABu a0, a1;
      a0.u = *(const uint4*)(wqb + (d0 + cl)*64 + quad*8);
      a1.u = *(const uint4*)(wqb + (d0 + cl)*64 + 32 + quad*8);
      float4 bias4 = *(const float4*)(qkv_b + d0 + quad*4);
      if (d0 < 64) { bias4.x *= 0.25f; bias4.y *= 0.25f; bias4.z *= 0.25f; bias4.w *= 0.25f; }
      #pragma unroll
      for (int tt = 0; tt < 4; tt++) {
        ABu h0, h1;
        h0.u = *(const uint4*)(h_b + (tt*16 + cl)*72 + quad*8);
        h1.u = *(const uint4*)(h_b + (tt*16 + cl)*72 + 32 + quad*8);
        f32x4 d = {0.f,0.f,0.f,0.f};
        d = __builtin_amdgcn_mfma_f32_16x16x32_bf16(a0.v, h0.v, d, 0,0,0);
        d = __builtin_amdgcn_mfma_f32_16x16x32_bf16(a1.v, h1.v, d, 0,0,0);
        if (d0 < 64) {
          *(uint2*)(q_b + (tt*16+cl)*72 + d0 + quad*4) =
            make_uint2(pack2bf(d[0]+bias4.x, d[1]+bias4.y),
                       pack2bf(d[2]+bias4.z, d[3]+bias4.w));
        } else if (d0 < 128) {
          *(uint2*)(k_b + (tt*16+cl)*72 + (d0-64) + quad*4) =
            make_uint2(pack2bf(d[0]+bias4.x, d[1]+bias4.y),
                       pack2bf(d[2]+bias4.z, d[3]+bias4.w));
        } else {
          const float* bp = (const float*)&bias4;
          #pragma unroll
          for (int r = 0; r < 4; r++)
            v_b[((d0-128) + quad*4 + r)*72 + tt*16 + cl] = f2bf(d[r] + bp[r]);
        }
      }
    }
  }
  __syncthreads();
  // attention: wave w owns tok_i rows 16w..16w+15; p overlays h_b; o -> regs
  uint2 pk[4];
  {
    const uint4 z4 = make_uint4(0u,0u,0u,0u);
    #pragma unroll
    for (int h = 0; h < 4; h++) {
      const int hb = h*16;
      ABu bq;
      if (quad < 2) bq.u = *(const uint4*)(q_b + (w*16 + cl)*72 + hb + quad*8);
      else bq.u = z4;
      float sc[4][4];
      #pragma unroll
      for (int tj = 0; tj < 4; tj++) {
        ABu ak;
        if (quad < 2) ak.u = *(const uint4*)(k_b + (tj*16 + cl)*72 + hb + quad*8);
        else ak.u = z4;
        f32x4 d = {0.f,0.f,0.f,0.f};
        d = __builtin_amdgcn_mfma_f32_16x16x32_bf16(ak.v, bq.v, d, 0,0,0);
        #pragma unroll
        for (int r = 0; r < 4; r++) sc[tj][r] = d[r];
      }
      float mx = -1e30f;
      #pragma unroll
      for (int tj = 0; tj < 4; tj++)
        #pragma unroll
        for (int r = 0; r < 4; r++) mx = fmaxf(mx, sc[tj][r]);
      mx = fmaxf(mx, __shfl_xor(mx, 16));
      mx = fmaxf(mx, __shfl_xor(mx, 32));
      float psum = 0.f;
      #pragma unroll
      for (int tj = 0; tj < 4; tj++) {
        float p0 = __expf(sc[tj][0]-mx), p1 = __expf(sc[tj][1]-mx);
        float p2 = __expf(sc[tj][2]-mx), p3 = __expf(sc[tj][3]-mx);
        psum += p0+p1+p2+p3;
        *(uint2*)(h_b + (w*16+cl)*72 + tj*16 + quad*4) =
            make_uint2(pack2bf(p0,p1), pack2bf(p2,p3));
      }
      psum += __shfl_xor(psum, 16);
      psum += __shfl_xor(psum, 32);
      float inv = 1.f / psum;
      f32x4 oacc = {0.f,0.f,0.f,0.f};
      #pragma unroll
      for (int kk = 0; kk < 2; kk++) {
        ABu av, bp;
        av.u = *(const uint4*)(v_b + (hb + cl)*72 + kk*32 + quad*8);
        bp.u = *(const uint4*)(h_b + (w*16 + cl)*72 + kk*32 + quad*8);
        oacc = __builtin_amdgcn_mfma_f32_16x16x32_bf16(av.v, bp.v, oacc, 0,0,0);
      }
      pk[h] = make_uint2(pack2bf(oacc[0]*inv, oacc[1]*inv),
                         pack2bf(oacc[2]*inv, oacc[3]*inv));
    }
  }
  __syncthreads();
  // stage o into k_b [tok][72]
  #pragma unroll
  for (int h = 0; h < 4; h++)
    *(uint2*)(k_b + (w*16+cl)*72 + h*16 + quad*4) = pk[h];
  __syncthreads();
  // proj + residual RMW + fused LN2 partials
  {
    const int c0 = w*16;
    ABu a0, a1;
    a0.u = *(const uint4*)(wpb + (c0 + cl)*64 + quad*8);
    a1.u = *(const uint4*)(wpb + (c0 + cl)*64 + 32 + quad*8);
    float4 pb4 = *(const float4*)(proj_b + c0 + quad*4);
    #pragma unroll
    for (int tt = 0; tt < 4; tt++) {
      ABu o0, o1;
      o0.u = *(const uint4*)(k_b + (tt*16 + cl)*72 + quad*8);
      o1.u = *(const uint4*)(k_b + (tt*16 + cl)*72 + 32 + quad*8);
      f32x4 d = {0.f,0.f,0.f,0.f};
      d = __builtin_amdgcn_mfma_f32_16x16x32_bf16(a0.v, o0.v, d, 0,0,0);
      d = __builtin_amdgcn_mfma_f32_16x16x32_bf16(a1.v, o1.v, d, 0,0,0);
      uint2* tp = (uint2*)(t_b + (tt*16+cl)*72 + c0 + quad*4);
      uint2 told = *tp;
      float2 t01 = bfp2f2(told.x), t23 = bfp2f2(told.y);
      float n0v = t01.x + d[0] + pb4.x;
      float n1v = t01.y + d[1] + pb4.y;
      float n2v = t23.x + d[2] + pb4.z;
      float n3v = t23.y + d[3] + pb4.w;
      *tp = make_uint2(pack2bf(n0v,n1v), pack2bf(n2v,n3v));
      float s = n0v+n1v+n2v+n3v;
      float qq = n0v*n0v + n1v*n1v + n2v*n2v + n3v*n3v;
      s  += __shfl_xor(s, 16);  s  += __shfl_xor(s, 32);
      qq += __shfl_xor(qq, 16); qq += __shfl_xor(qq, 32);
      if (quad == 0) {
        scratch[(tt*16+cl)*4 + w] = s;
        scratch[256 + (tt*16+cl)*4 + w] = qq;
      }
    }
  }
  __syncthreads();
  if (tid < 64) {
    float s  = scratch[tid*4] + scratch[tid*4+1] + scratch[tid*4+2] + scratch[tid*4+3];
    float qq = scratch[256+tid*4] + scratch[256+tid*4+1]
             + scratch[256+tid*4+2] + scratch[256+tid*4+3];
    float m = s * (1.f/64.f);
    float var = qq * (1.f/64.f) - m*m;
    mean_s[tid] = m; rstd_s[tid] = rsqrtf(var + 1e-5f);
  }
  __syncthreads();
  // LN2 apply
  {
    const int cg = tid & 15, tq = tid >> 4;
    float4 g4 = *(const float4*)(ln2_g + cg*4);
    float4 b4 = *(const float4*)(ln2_b + cg*4);
    #pragma unroll
    for (int k = 0; k < 4; k++) {
      int tok = tq + k*16;
      uint2 tv = *(const uint2*)(t_b + tok*72 + cg*4);
      float2 x01 = bfp2f2(tv.x), x23 = bfp2f2(tv.y);
      float m = mean_s[tok], r = rstd_s[tok];
      float h0 = (x01.x-m)*r*g4.x + b4.x;
      float h1 = (x01.y-m)*r*g4.y + b4.y;
      float h2 = (x23.x-m)*r*g4.z + b4.z;
      float h3 = (x23.y-m)*r*g4.w + b4.w;
      *(uint2*)(h_b + tok*72 + cg*4) = make_uint2(pack2bf(h0,h1), pack2bf(h2,h3));
    }
  }
  __syncthreads();
  // MLP chunked over 4 hid-groups of 64; hid chunk overlays q_b
  {
    const int c0 = w*16;
    ABu hb0[4], hb1[4];
    #pragma unroll
    for (int tt = 0; tt < 4; tt++) {
      hb0[tt].u = *(const uint4*)(h_b + (tt*16 + cl)*72 + quad*8);
      hb1[tt].u = *(const uint4*)(h_b + (tt*16 + cl)*72 + 32 + quad*8);
    }
    f32x4 acc2[4];
    #pragma unroll
    for (int tt = 0; tt < 4; tt++)
      #pragma unroll
      for (int r = 0; r < 4; r++) acc2[tt][r] = 0.f;
    for (int ch = 0; ch < 4; ch++) {
      const int m0 = ch*64 + w*16;
      ABu a0, a1;
      a0.u = *(const uint4*)(w1b + (m0 + cl)*64 + quad*8);
      a1.u = *(const uint4*)(w1b + (m0 + cl)*64 + 32 + quad*8);
      float4 b14 = *(const float4*)(b1 + m0 + quad*4);
      const float* bp = (const float*)&b14;
      #pragma unroll
      for (int tt = 0; tt < 4; tt++) {
        f32x4 d = {0.f,0.f,0.f,0.f};
        d = __builtin_amdgcn_mfma_f32_16x16x32_bf16(a0.v, hb0[tt].v, d, 0,0,0);
        d = __builtin_amdgcn_mfma_f32_16x16x32_bf16(a1.v, hb1[tt].v, d, 0,0,0);
        float g[4];
        #pragma unroll
        for (int r = 0; r < 4; r++) {
          float x = d[r] + bp[r];
          float u = 1.5957691f * (x + 0.044715f*x*x*x);
          g[r] = x / (1.f + __expf(-u));
        }
        *(uint2*)(q_b + (tt*16+cl)*72 + w*16 + quad*4) =
            make_uint2(pack2bf(g[0],g[1]), pack2bf(g[2],g[3]));
      }
      __syncthreads();
      ABu a20, a21;
      a20.u = *(const uint4*)(w2b + (c0 + cl)*256 + ch*64 + quad*8);
      a21.u = *(const uint4*)(w2b + (c0 + cl)*256 + ch*64 + 32 + quad*8);
      #pragma unroll
      for (int tt = 0; tt < 4; tt++) {
        ABu bh0, bh1;
        bh0.u = *(const uint4*)(q_b + (tt*16 + cl)*72 + quad*8);
        bh1.u = *(const uint4*)(q_b + (tt*16 + cl)*72 + 32 + quad*8);
        acc2[tt] = __builtin_amdgcn_mfma_f32_16x16x32_bf16(a20.v, bh0.v, acc2[tt], 0,0,0);
        acc2[tt] = __builtin_amdgcn_mfma_f32_16x16x32_bf16(a21.v, bh1.v, acc2[tt], 0,0,0);
      }
      __syncthreads();
    }
    float4 b24 = *(const float4*)(b2 + c0 + quad*4);
    #pragma unroll
    for (int tt = 0; tt < 4; tt++) {
      uint2* tp = (uint2*)(t_b + (tt*16+cl)*72 + c0 + quad*4);
      uint2 told = *tp;
      float2 t01 = bfp2f2(told.x), t23 = bfp2f2(told.y);
      *tp = make_uint2(pack2bf(t01.x + acc2[tt][0] + b24.x, t01.y + acc2[tt][1] + b24.y),
                       pack2bf(t23.x + acc2[tt][2] + b24.z, t23.y + acc2[tt][3] + b24.w));
    }
  }
  __syncthreads();
  // writeback (uint4) + vectorized SE partials
  for (int e = tid; e < 512; e += 256) {
    int tok = e >> 3, cg8 = e & 7;
    int zl = tok >> 4, yl = (tok >> 2) & 3, xl = tok & 3;
    int vox = ((zb*4+zl)*32 + (yb*4+yl))*32 + (xb*4+xl);
    *(uint4*)(grid + gb + (size_t)vox*64 + cg8*8) = *(const uint4*)(t_b + tok*72 + cg8*8);
  }
  {
    const int cg = tid & 15, tq = tid >> 4;
    float4 p = {0.f,0.f,0.f,0.f};
    #pragma unroll
    for (int k = 0; k < 4; k++) {
      int tok = tq + k*16;
      uint2 tv = *(const uint2*)(t_b + tok*72 + cg*4);
      float2 x01 = bfp2f2(tv.x), x23 = bfp2f2(tv.y);
      p.x += x01.x; p.y += x01.y; p.z += x23.x; p.w += x23.y;
    }
    ((float4*)scratch)[cg*16 + tq] = p;
  }
  __syncthreads();
  if (tid < 64) {
    int cg = tid >> 2, j = tid & 3;
    float s = 0.f;
    #pragma unroll
    for (int g = 0; g < 16; g++) s += scratch[(cg*16+g)*4 + j];
    atomicAdd(&se_sum[b*64 + tid], s);
  }
}

// ---------- 6. SE squeeze-excite scale ----------
__global__ void se_kernel(const float* __restrict__ se_sum, const float* __restrict__ w1,
                          const float* __restrict__ w2, float* __restrict__ scale)
{
  __shared__ float mean_s[256];
  __shared__ float z1[32];
  int tid = threadIdx.x;
  mean_s[tid] = se_sum[tid] * (1.f / VX);
  __syncthreads();
  if (tid < 32) {
    int bb = tid >> 3, j = tid & 7;
    float a = 0.f;
    for (int c = 0; c < 64; c++) a += mean_s[bb*64 + c] * w1[j*64 + c];
    z1[tid] = fmaxf(a, 0.f);
  }
  __syncthreads();
  int b = tid >> 6, c = tid & 63;
  float a = 0.f;
  for (int j = 0; j < 8; j++) a += z1[b*8 + j] * w2[c*8 + j];
  scale[tid] = 1.f / (1.f + __expf(-a));
}

// ---------- 7. point branch input — MFMA ----------
__global__ __launch_bounds__(256) void point_in_kernel(
    const float* __restrict__ features, const float* __restrict__ pt_in_b,
    const unsigned short* __restrict__ ptw,   // pt_in@0, q@4096, k@5120, v@6144
    float* __restrict__ x_t, unsigned short* __restrict__ q_bf,
    unsigned short* __restrict__ k_bf, unsigned short* __restrict__ v_tt)
{
  __shared__ unsigned short f_b[64*72];
  __shared__ unsigned short x_b[64*72];
  const int tid = threadIdx.x;
  const int blk = blockIdx.x;      // B*64
  const int b = blk >> 6;
  const int n0 = (blk & 63) * 64;
  const int w = tid >> 6;
  const int lane = tid & 63;
  const int cl = lane & 15;
  const int quad = lane >> 4;

  // stage f^T bf16 (coalesced read along n, transposed scalar LDS write)
  for (int e = tid; e < 4096; e += 256) {
    int c = e >> 6, nl = e & 63;
    f_b[nl*72 + c] = f2bf(features[((size_t)(b*64 + c))*NP + n0 + nl]);
  }
  __syncthreads();
  // x = relu(W @ f^T + b); wave w -> c-tile m0
  const int m0 = w*16;
  {
    ABu a0, a1;
    a0.u = *(const uint4*)(ptw + (m0 + cl)*64 + quad*8);
    a1.u = *(const uint4*)(ptw + (m0 + cl)*64 + 32 + quad*8);
    float4 bi = *(const float4*)(pt_in_b + m0 + quad*4);
    #pragma unroll
    for (int tt = 0; tt < 4; tt++) {
      ABu f0, f1;
      f0.u = *(const uint4*)(f_b + (tt*16 + cl)*72 + quad*8);
      f1.u = *(const uint4*)(f_b + (tt*16 + cl)*72 + 32 + quad*8);
      f32x4 d = {0.f,0.f,0.f,0.f};
      d = __builtin_amdgcn_mfma_f32_16x16x32_bf16(a0.v, f0.v, d, 0,0,0);
      d = __builtin_amdgcn_mfma_f32_16x16x32_bf16(a1.v, f1.v, d, 0,0,0);
      float x0 = fmaxf(d[0]+bi.x, 0.f), x1 = fmaxf(d[1]+bi.y, 0.f);
      float x2 = fmaxf(d[2]+bi.z, 0.f), x3 = fmaxf(d[3]+bi.w, 0.f);
      const int n = tt*16 + cl;
      *(float4*)&x_t[((size_t)(b*NP) + n0 + n)*64 + m0 + quad*4] =
          make_float4(x0, x1, x2, x3);
      *(uint2*)(x_b + n*72 + m0 + quad*4) = make_uint2(pack2bf(x0,x1), pack2bf(x2,x3));
    }
  }
  __syncthreads();
  // v = v_w @ x^T; wave w -> c-tile m0; store [b][c][n]
  {
    const unsigned short* vwb = ptw + 6144;
    ABu a0, a1;
    a0.u = *(const uint4*)(vwb + (m0 + cl)*64 + quad*8);
    a1.u = *(const uint4*)(vwb + (m0 + cl)*64 + 32 + quad*8);
    #pragma unroll
    for (int tt = 0; tt < 4; tt++) {
      ABu x0, x1;
      x0.u = *(const uint4*)(x_b + (tt*16 + cl)*72 + quad*8);
      x1.u = *(const uint4*)(x_b + (tt*16 + cl)*72 + 32 + quad*8);
      f32x4 d = {0.f,0.f,0.f,0.f};
      d = __builtin_amdgcn_mfma_f32_16x16x32_bf16(a0.v, x0.v, d, 0,0,0);
      d = __builtin_amdgcn_mfma_f32_16x16x32_bf16(a1.v, x1.v, d, 0,0,0);
      const int n = n0 + tt*16 + cl;
      #pragma unroll
      for (int r = 0; r < 4; r++)
        v_tt[((size_t)(b*64) + m0 + quad*4 + r)*NP + n] = f2bf(d[r]);
    }
  }
  // q/k (16 dims): waves 0,2 -> q halves; 1,3 -> k halves (q pre-scaled)
  {
    const int which = w & 1, half = w >> 1;
    const unsigned short* wp = ptw + (which ? 5120 : 4096);
    unsigned short* dst = which ? k_bf : q_bf;
    ABu a0, a1;
    a0.u = *(const uint4*)(wp + cl*64 + quad*8);
    a1.u = *(const uint4*)(wp + cl*64 + 32 + quad*8);
    #pragma unroll
    for (int th = 0; th < 2; th++) {
      const int tt = half*2 + th;
      ABu x0, x1;
      x0.u = *(const uint4*)(x_b + (tt*16 + cl)*72 + quad*8);
      x1.u = *(const uint4*)(x_b + (tt*16 + cl)*72 + 32 + quad*8);
      f32x4 d = {0.f,0.f,0.f,0.f};
      d = __builtin_amdgcn_mfma_f32_16x16x32_bf16(a0.v, x0.v, d, 0,0,0);
      d = __builtin_amdgcn_mfma_f32_16x16x32_bf16(a1.v, x1.v, d, 0,0,0);
      const int n = tt*16 + cl;
      *(uint2*)(dst + ((size_t)(b*NP) + n0 + n)*16 + quad*4) =
          make_uint2(pack2bf(d[0],d[1]), pack2bf(d[2],d[3]));
    }
  }
}

// ---------- 8. point attention — MFMA flash, 4-way KV split ----------
__global__ __launch_bounds__(256) void point_attn_kernel(
    const unsigned short* __restrict__ q_bf, const unsigned short* __restrict__ k_bf,
    const unsigned short* __restrict__ v_tt,
    float* __restrict__ opart, float2* __restrict__ mlbuf)
{
  __shared__ unsigned short q_s[64*24];
  __shared__ unsigned short k_sh[2][64*24];
  __shared__ unsigned short v_sh[2][64*72];
  __shared__ unsigned short p_s[64*72];
  const int tid = threadIdx.x;
  const int blk = blockIdx.x;      // B*64*4
  const int b = blk >> 8;
  const int nb = (blk >> 2) & 63;
  const int s = blk & 3;
  const int n0 = nb * 64;
  const int t_beg = s*16, t_end = s*16 + 16;
  const int w = tid >> 6;
  const int lane = tid & 63;
  const int cl = lane & 15;
  const int quad = lane >> 4;
  const uint4 z4 = make_uint4(0u,0u,0u,0u);

  const unsigned* qbu = (const unsigned*)q_bf;
  const unsigned* kbu = (const unsigned*)k_bf;
  const unsigned* vtu = (const unsigned*)v_tt;
  unsigned* q_su = (unsigned*)q_s;

  {
    unsigned* kd = (unsigned*)k_sh[0];
    unsigned* vd = (unsigned*)v_sh[0];
    for (int e = tid; e < 512; e += 256) {
      int tok = e >> 3, du = e & 7;
      q_su[tok*12 + du] = qbu[((size_t)(b*NP) + n0 + tok)*8 + du];
      kd[tok*12 + du]   = kbu[((size_t)(b*NP) + t_beg*64 + tok)*8 + du];
    }
    for (int e = tid; e < 2048; e += 256) {
      int cc = e >> 5, tu = e & 31;
      vd[cc*36 + tu] = vtu[((size_t)(b*64) + cc)*2048 + t_beg*32 + tu];
    }
  }
  float m_run = -1e30f, l_run = 0.f;
  f32x4 acc[4];
  #pragma unroll
  for (int ct = 0; ct < 4; ct++)
    #pragma unroll
    for (int r = 0; r < 4; r++) acc[ct][r] = 0.f;
  __syncthreads();

  ABu bq;
  if (quad < 2) bq.u = *(const uint4*)(q_s + (w*16 + cl)*24 + quad*8);
  else bq.u = z4;

  for (int t = t_beg; t < t_end; t++) {
    const int cur = t & 1;
    unsigned pk[2], pv[8];
    if (t+1 < t_end) {
      const int m1 = (t+1)*64;
      #pragma unroll
      for (int i = 0; i < 2; i++) {
        int e = tid + i*256;
        pk[i] = kbu[((size_t)(b*NP) + m1 + (e>>3))*8 + (e&7)];
      }
      #pragma unroll
      for (int i = 0; i < 8; i++) {
        int e = tid + i*256;
        pv[i] = vtu[((size_t)(b*64) + (e>>5))*2048 + (m1>>1) + (e&31)];
      }
    }
    const unsigned short* ks = k_sh[cur];
    const unsigned short* vs = v_sh[cur];
    float sc[4][4];
    #pragma unroll
    for (int tj = 0; tj < 4; tj++) {
      ABu ak;
      if (quad < 2) ak.u = *(const uint4*)(ks + (tj*16 + cl)*24 + quad*8);
      else ak.u = z4;
      f32x4 d = {0.f,0.f,0.f,0.f};
      d = __builtin_amdgcn_mfma_f32_16x16x32_bf16(ak.v, bq.v, d, 0,0,0);
      #pragma unroll
      for (int r = 0; r < 4; r++) sc[tj][r] = d[r];
    }
    float tmax = -1e30f;
    #pragma unroll
    for (int tj = 0; tj < 4; tj++)
      #pragma unroll
      for (int r = 0; r < 4; r++) tmax = fmaxf(tmax, sc[tj][r]);
    tmax = fmaxf(tmax, __shfl_xor(tmax, 16));
    tmax = fmaxf(tmax, __shfl_xor(tmax, 32));
    float mnew = fmaxf(m_run, tmax);
    float alpha = __expf(m_run - mnew);
    float psum = 0.f;
    #pragma unroll
    for (int tj = 0; tj < 4; tj++) {
      float p0 = __expf(sc[tj][0]-mnew), p1 = __expf(sc[tj][1]-mnew);
      float p2 = __expf(sc[tj][2]-mnew), p3 = __expf(sc[tj][3]-mnew);
      psum += p0+p1+p2+p3;
      *(uint2*)(p_s + (w*16+cl)*72 + tj*16 + quad*4) =
          make_uint2(pack2bf(p0,p1), pack2bf(p2,p3));
    }
    psum += __shfl_xor(psum, 16);
    psum += __shfl_xor(psum, 32);
    l_run = l_run*alpha + psum;
    m_run = mnew;
    #pragma unroll
    for (int ct = 0; ct < 4; ct++)
      #pragma unroll
      for (int r = 0; r < 4; r++) acc[ct][r] *= alpha;
    #pragma unroll
    for (int kk = 0; kk < 2; kk++) {
      ABu bp;
      bp.u = *(const uint4*)(p_s + (w*16 + cl)*72 + kk*32 + quad*8);
      #pragma unroll
      for (int ct = 0; ct < 4; ct++) {
        ABu av;
        av.u = *(const uint4*)(vs + (ct*16 + cl)*72 + kk*32 + quad*8);
        acc[ct] = __builtin_amdgcn_mfma_f32_16x16x32_bf16(av.v, bp.v, acc[ct], 0,0,0);
      }
    }
    __syncthreads();
    if (t+1 < t_end) {
      unsigned* kd = (unsigned*)k_sh[1-cur];
      unsigned* vd = (unsigned*)v_sh[1-cur];
      #pragma unroll
      for (int i = 0; i < 2; i++) {
        int e = tid + i*256;
        kd[(e>>3)*12 + (e&7)] = pk[i];
      }
      #pragma unroll
      for (int i = 0; i < 8; i++) {
        int e = tid + i*256;
        vd[(e>>5)*36 + (e&31)] = pv[i];
      }
    }
    __syncthreads();
  }
  const int tok = n0 + w*16 + cl;
  #pragma unroll
  for (int ct = 0; ct < 4; ct++) {
    float4 o4;
    o4.x = acc[ct][0]; o4.y = acc[ct][1]; o4.z = acc[ct][2]; o4.w = acc[ct][3];
    *(float4*)&opart[(((size_t)(s*BN + b))*NP + tok)*64 + ct*16 + quad*4] = o4;
  }
  if (quad == 0)
    mlbuf[(size_t)(s*BN + b)*NP + tok] = make_float2(m_run, l_run);
}

// ---------- 9. merge + devox + offset transform + fuse ----------
__global__ __launch_bounds__(256) void fuse_kernel(
    const float* __restrict__ x_t, const float* __restrict__ opart,
    const float2* __restrict__ mlbuf,
    const float* __restrict__ trans_w, const float* __restrict__ trans_b,
    const unsigned short* __restrict__ grid, const float* __restrict__ se_scale,
    const float* __restrict__ nc, float* __restrict__ out)
{
  __shared__ float tw_s[64*65];
  __shared__ float d_s[32*65];
  __shared__ float r_s[64*33];
  __shared__ float mw[32][6];
  const int tid = threadIdx.x;
  const int blk = blockIdx.x;     // B*128
  const int b = blk >> 7;
  const int n0 = (blk & 127) * 32;
  for (int e = tid; e < 4096; e += 256) {
    int c = e >> 6, k = e & 63;
    tw_s[c*65 + k] = trans_w[e];
  }
  if (tid < 32) {
    int nl = tid;
    float m[4], l[4];
    #pragma unroll
    for (int s = 0; s < 4; s++) {
      float2 v = mlbuf[(size_t)(s*BN + b)*NP + n0 + nl];
      m[s] = v.x; l[s] = v.y;
    }
    float M = fmaxf(fmaxf(m[0], m[1]), fmaxf(m[2], m[3]));
    float L = 0.f;
    #pragma unroll
    for (int s = 0; s < 4; s++) {
      float ws = __expf(m[s] - M);
      mw[nl][s] = ws;
      L += l[s] * ws;
    }
    mw[nl][4] = 1.f / L;
  }
  __syncthreads();
  for (int e = tid; e < 2048; e += 256) {
    int nl = e >> 6, c = e & 63;
    size_t pbase = ((size_t)(b*NP) + n0 + nl)*64 + c;
    const size_t sstr = (size_t)BN*NP*64;
    float o = opart[pbase]        * mw[nl][0] + opart[pbase +   sstr] * mw[nl][1]
            + opart[pbase+2*sstr] * mw[nl][2] + opart[pbase + 3*sstr] * mw[nl][3];
    o *= mw[nl][4];
    d_s[nl*65 + c] = x_t[pbase] - o;
  }
  __syncthreads();
  const int cl = tid & 63, g = tid >> 6;
  const float ses = se_scale[b*64 + cl];
  const float tb = trans_b[cl];
  for (int t = 0; t < 8; t++) {
    int nl = g*8 + t;
    int n = n0 + nl;
    float off = 0.f;
    for (int k = 0; k < 64; k++) off += tw_s[cl*65 + k] * d_s[nl*65 + k];
    off = fmaxf(off + tb, 0.f);
    float ncx = nc[((size_t)(b*3)+0)*NP + n];
    float ncy = nc[((size_t)(b*3)+1)*NP + n];
    float ncz = nc[((size_t)(b*3)+2)*NP + n];
    float fx0 = floorf(ncx), fy0 = floorf(ncy), fz0 = floorf(ncz);
    int x0 = (int)fx0, y0 = (int)fy0, z0 = (int)fz0;
    float fx = ncx - fx0, fy = ncy - fy0, fz = ncz - fz0;
    float wx[2] = {1.f-fx, fx}, wy[2] = {1.f-fy, fy}, wz[2] = {1.f-fz, fz};
    float vf = 0.f;
    #pragma unroll
    for (int cor = 0; cor < 8; cor++) {
      int dx = cor >> 2, dy = (cor >> 1) & 1, dz = cor & 1;
      int xi = min(x0+dx, 31), yi = min(y0+dy, 31), zi = min(z0+dz, 31);
      float wgt = wx[dx]*wy[dy]*wz[dz];
      vf += wgt * bf2f(grid[((size_t)(b*VX) + (xi*32+yi)*32 + zi)*64 + cl]);
    }
    vf *= ses;
    float xval = x_t[((size_t)(b*NP) + n)*64 + cl];
    r_s[cl*33 + nl] = xval + off + vf;
  }
  __syncthreads();
  for (int e = tid; e < 2048; e += 256) {
    int c = e >> 5, nl = e & 31;
    out[((size_t)(b*64) + c)*NP + n0 + nl] = r_s[c*33 + nl];
  }
}

extern "C" void kernel_launch(void* const* d_in, const int* in_sizes, int n_in,
                              void* d_out, int out_size, void* d_ws, size_t ws_size,
                              hipStream_t stream)
{
  const float* features = (const float*)d_in[0];
  const float* coords   = (const float*)d_in[1];
  const float* conv_w   = (const float*)d_in[2];
  const float* conv_b   = (const float*)d_in[3];
  const float* ln1_g    = (const float*)d_in[4];
  const float* ln1_b    = (const float*)d_in[5];
  const float* qkv_w    = (const float*)d_in[6];
  const float* qkv_b    = (const float*)d_in[7];
  const float* proj_w   = (const float*)d_in[8];
  const float* proj_b   = (const float*)d_in[9];
  const float* ln2_g    = (const float*)d_in[10];
  const float* ln2_b    = (const float*)d_in[11];
  const float* mlp_w1   = (const float*)d_in[12];
  const float* mlp_b1   = (const float*)d_in[13];
  const float* mlp_w2   = (const float*)d_in[14];
  const float* mlp_b2   = (const float*)d_in[15];
  const float* se_w1    = (const float*)d_in[16];
  const float* se_w2    = (const float*)d_in[17];
  const float* pt_in_w  = (const float*)d_in[18];
  const float* pt_in_b  = (const float*)d_in[19];
  const float* q_w      = (const float*)d_in[20];
  const float* k_w      = (const float*)d_in[21];
  const float* v_w      = (const float*)d_in[22];
  const float* v_trans_w= (const float*)d_in[23];
  const float* v_trans_b= (const float*)d_in[24];

  char* ws = (char*)d_ws;
  float* stats    = (float*)(ws + 0);
  float* se_sum   = (float*)(ws + 256);
  float* se_scale = (float*)(ws + 1280);
  float* nc       = (float*)(ws + 4096);
  float* cnt      = (float*)(ws + 200704);
  float* grid0    = (float*)(ws + 724992);               // fp32 sums (zeroed)
  unsigned short* grid1b = (unsigned short*)(ws + 34279424);  // bf16 grid
  float* x_t = (float*)(ws + 724992);
  unsigned short* q_bf = (unsigned short*)(ws + 724992 + 4194304);
  unsigned short* k_bf = (unsigned short*)(ws + 724992 + 5242880);
  unsigned short* v_tt = (unsigned short*)(ws + 724992 + 6291456);
  float*  opart = (float*)(ws + 724992 + 10485760);      // 16 MB (4 splits)
  float2* mlbuf = (float2*)(ws + 724992 + 27787264);     // 512 KB
  unsigned short* wpre = (unsigned short*)d_out;              // 221184 B
  unsigned short* encw = (unsigned short*)((char*)d_out + 221184);  // 118784 B

  hipMemsetAsync(se_sum, 0, 1024, stream);
  hipMemsetAsync(cnt, 0, 524288 + 33554432, stream);

  wprep_kernel<<<54, 256, 0, stream>>>(conv_w, wpre);
  eprep_kernel<<<232, 256, 0, stream>>>(qkv_w, proj_w, mlp_w1, mlp_w2,
      pt_in_w, q_w, k_w, v_w, encw);
  stats_kernel<<<BN, 256, 0, stream>>>(coords, stats);
  scatter_kernel<<<256, 256, 0, stream>>>(features, coords, stats, nc, grid0, cnt);
  conv_mfma_kernel<<<1024, 256, 0, stream>>>(grid0, cnt, wpre, conv_b, grid1b);
  encoder_kernel<<<2048, 256, 0, stream>>>(grid1b, ln1_g, ln1_b, qkv_b, proj_b,
      ln2_g, ln2_b, mlp_b1, mlp_b2, encw, se_sum);
  se_kernel<<<1, 256, 0, stream>>>(se_sum, se_w1, se_w2, se_scale);
  point_in_kernel<<<256, 256, 0, stream>>>(features, pt_in_b, encw + 49152,
      x_t, q_bf, k_bf, v_tt);
  point_attn_kernel<<<1024, 256, 0, stream>>>(q_bf, k_bf, v_tt, opart, mlbuf);
  fuse_kernel<<<512, 256, 0, stream>>>(x_t, opart, mlbuf, v_trans_w, v_trans_b,
      grid1b, se_scale, nc, (float*)d_out);
  hipMemcpyAsync((char*)d_out + (size_t)BN*64*NP*4, coords, (size_t)BN*3*NP*4,
                 hipMemcpyDeviceToDevice, stream);
}